// Round 1
// baseline (8567.107 us; speedup 1.0000x reference)
//
#include <hip/hip_runtime.h>
#include <math.h>

#define B 32
#define T 512
#define D 256
#define H 8
#define DH 32
#define MF 128
#define NLAYER 6
#define FF 1024
#define NM 4
#define BT (B*T)

#define DN 0.4204482076268573f      /* 32^-0.25 */
#define RATIO 0.08838834764831845f  /* 128^-0.5 */
#define KEPS 1e-4f

// ---------------- transpose mel (B,D,T) -> x (B,T,D) ----------------
__global__ void transpose_mel(const float* __restrict__ mel, float* __restrict__ x) {
  __shared__ float tile[32][33];
  int b = blockIdx.z;
  int d0 = blockIdx.y * 32, t0 = blockIdx.x * 32;
  int tx = threadIdx.x, ty = threadIdx.y; // 32 x 8
  #pragma unroll
  for (int i = 0; i < 32; i += 8)
    tile[ty + i][tx] = mel[(b * D + d0 + ty + i) * T + t0 + tx];
  __syncthreads();
  #pragma unroll
  for (int i = 0; i < 32; i += 8)
    x[(b * T + t0 + ty + i) * D + d0 + tx] = tile[tx][ty + i];
}

// ---------------- layernorm: one wave per row of 256 ----------------
__global__ void ln_kernel(const float* __restrict__ x, const float* __restrict__ g,
                          const float* __restrict__ bb, float* __restrict__ y) {
  int row = blockIdx.x;
  int lane = threadIdx.x; // 64
  const float4 v = ((const float4*)(x + (size_t)row * D))[lane];
  float s = v.x + v.y + v.z + v.w;
  #pragma unroll
  for (int off = 32; off; off >>= 1) s += __shfl_down(s, off);
  s = __shfl(s, 0);
  float mu = s * (1.0f / 256.0f);
  float dx = v.x - mu, dy = v.y - mu, dz = v.z - mu, dw = v.w - mu;
  float q = dx * dx + dy * dy + dz * dz + dw * dw;
  #pragma unroll
  for (int off = 32; off; off >>= 1) q += __shfl_down(q, off);
  q = __shfl(q, 0);
  float rstd = rsqrtf(q * (1.0f / 256.0f) + 1e-5f);
  const float4 gg = ((const float4*)g)[lane];
  const float4 be = ((const float4*)bb)[lane];
  float4 o;
  o.x = dx * rstd * gg.x + be.x;
  o.y = dy * rstd * gg.y + be.y;
  o.z = dz * rstd * gg.z + be.z;
  o.w = dw * rstd * gg.w + be.w;
  ((float4*)(y + (size_t)row * D))[lane] = o;
}

// ---------------- generic fp32 GEMM: C[M,N] = A[M,K] @ W[K,N] (+bias,+gelu,+res) ----------------
template<int BIAS, int RES, int GELU_ACT>
__global__ __launch_bounds__(256) void gemm64(const float* __restrict__ A, const float* __restrict__ W,
                         const float* __restrict__ bias, const float* __restrict__ res,
                         float* __restrict__ C, int N, int K) {
  __shared__ float As[16][65];
  __shared__ float Bs[16][65];
  int tid = threadIdx.x;
  int tx = tid & 15, ty = tid >> 4;
  int row0 = blockIdx.y * 64, col0 = blockIdx.x * 64;
  float acc[4][4] = {};
  int ar = tid >> 4, ak = tid & 15;
  int bc = tid & 63, bk = tid >> 6;
  for (int k0 = 0; k0 < K; k0 += 16) {
    #pragma unroll
    for (int i = 0; i < 4; i++)
      As[ak][ar + 16 * i] = A[(size_t)(row0 + ar + 16 * i) * K + k0 + ak];
    #pragma unroll
    for (int i = 0; i < 4; i++)
      Bs[bk + 4 * i][bc] = W[(size_t)(k0 + bk + 4 * i) * N + col0 + bc];
    __syncthreads();
    #pragma unroll
    for (int kk = 0; kk < 16; kk++) {
      float a[4], b[4];
      #pragma unroll
      for (int i = 0; i < 4; i++) a[i] = As[kk][ty * 4 + i];
      #pragma unroll
      for (int j = 0; j < 4; j++) b[j] = Bs[kk][tx * 4 + j];
      #pragma unroll
      for (int i = 0; i < 4; i++)
        #pragma unroll
        for (int j = 0; j < 4; j++) acc[i][j] += a[i] * b[j];
    }
    __syncthreads();
  }
  #pragma unroll
  for (int i = 0; i < 4; i++) {
    int r = row0 + ty * 4 + i;
    #pragma unroll
    for (int j = 0; j < 4; j++) {
      int c = col0 + tx * 4 + j;
      float v = acc[i][j];
      if (BIAS) v += bias[c];
      if (GELU_ACT) {
        float u = v;
        v = 0.5f * u * (1.0f + tanhf(0.7978845608028654f * (u + 0.044715f * u * u * u)));
      }
      if (RES) v += res[(size_t)r * N + c];
      C[(size_t)r * N + c] = v;
    }
  }
}

// ---------------- FAVOR+ query features (per-row max) ----------------
__global__ void favor_q(const float* __restrict__ q, const float* __restrict__ proj,
                        float* __restrict__ qp) {
  int idx = blockIdx.x;            // (b*H+h)*T + t
  int t = idx & (T - 1);
  int bh = idx >> 9;
  int h = bh & 7, b = bh >> 3;
  __shared__ float qrow[32];
  __shared__ float wmax[2];
  int tid = threadIdx.x;           // 128
  if (tid < 32) qrow[tid] = q[((size_t)(b * T + t)) * D + h * DH + tid] * DN;
  __syncthreads();
  float s = 0.f, dg = 0.f;
  const float* pr = proj + tid * DH;
  #pragma unroll
  for (int j = 0; j < DH; j++) { float qv = qrow[j]; s += qv * pr[j]; dg += qv * qv; }
  dg *= 0.5f;
  float mx = s;
  #pragma unroll
  for (int off = 32; off; off >>= 1) mx = fmaxf(mx, __shfl_down(mx, off));
  if ((tid & 63) == 0) wmax[tid >> 6] = mx;
  __syncthreads();
  mx = fmaxf(wmax[0], wmax[1]);
  qp[(size_t)idx * MF + tid] = RATIO * (expf(s - dg - mx) + KEPS);
}

// ---------------- FAVOR+ key features pass1: raw scores + diag + row max ----------------
__global__ void favor_k1(const float* __restrict__ k, const float* __restrict__ proj,
                         float* __restrict__ kxd, float* __restrict__ kdiag,
                         float* __restrict__ krmax) {
  int idx = blockIdx.x;
  int t = idx & (T - 1);
  int bh = idx >> 9;
  int h = bh & 7, b = bh >> 3;
  __shared__ float krow[32];
  __shared__ float wmax[2];
  int tid = threadIdx.x;
  if (tid < 32) krow[tid] = k[((size_t)(b * T + t)) * D + h * DH + tid] * DN;
  __syncthreads();
  float s = 0.f, dg = 0.f;
  const float* pr = proj + tid * DH;
  #pragma unroll
  for (int j = 0; j < DH; j++) { float kv = krow[j]; s += kv * pr[j]; dg += kv * kv; }
  dg *= 0.5f;
  kxd[(size_t)idx * MF + tid] = s;
  float mx = s;
  #pragma unroll
  for (int off = 32; off; off >>= 1) mx = fmaxf(mx, __shfl_down(mx, off));
  if ((tid & 63) == 0) wmax[tid >> 6] = mx;
  __syncthreads();
  if (tid == 0) {
    kdiag[idx] = dg;
    krmax[idx] = fmaxf(wmax[0], wmax[1]);
  }
}

// ---------------- reduce per-(b,h) max over T ----------------
__global__ void kmax_reduce(const float* __restrict__ krmax, float* __restrict__ kmax) {
  int bh = blockIdx.x;
  int tid = threadIdx.x; // 256
  __shared__ float red[256];
  float m = fmaxf(krmax[bh * T + tid], krmax[bh * T + 256 + tid]);
  red[tid] = m;
  __syncthreads();
  for (int s = 128; s; s >>= 1) {
    if (tid < s) red[tid] = fmaxf(red[tid], red[tid + s]);
    __syncthreads();
  }
  if (tid == 0) kmax[bh] = red[0];
}

// ---------------- FAVOR+ key features pass2: exp ----------------
__global__ void favor_k2(float* __restrict__ kp, const float* __restrict__ kdiag,
                         const float* __restrict__ kmax) {
  int i = blockIdx.x * 256 + threadIdx.x;
  int row = i >> 7;
  int bh = i >> 16;
  kp[i] = RATIO * (expf(kp[i] - kdiag[row] - kmax[bh]) + KEPS);
}

// ---------------- ctx = kp^T @ v per (b,h), plus ksum ----------------
__global__ __launch_bounds__(256) void ctx_kernel(const float* __restrict__ kp, const float* __restrict__ v,
                           float* __restrict__ ctx, float* __restrict__ ksum) {
  int bh = blockIdx.x;
  int b = bh >> 3, h = bh & 7;
  __shared__ float kt[32][MF];
  __shared__ float vt[32][33];
  int tid = threadIdx.x;
  int d = tid & 31, mg = tid >> 5; // mg 0..7
  float acc[16] = {};
  float ks = 0.f;
  for (int t0 = 0; t0 < T; t0 += 32) {
    #pragma unroll
    for (int i = 0; i < 16; i++) {
      int lin = i * 256 + tid;
      int tt = lin >> 7, mm = lin & 127;
      kt[tt][mm] = kp[((size_t)bh * T + t0 + tt) * MF + mm];
    }
    #pragma unroll
    for (int i = 0; i < 4; i++) {
      int tt = (tid >> 5) + 8 * i;
      vt[tt][d] = v[((size_t)(b * T) + t0 + tt) * D + h * DH + d];
    }
    __syncthreads();
    for (int tt = 0; tt < 32; tt++) {
      float vv = vt[tt][d];
      #pragma unroll
      for (int i = 0; i < 16; i++) acc[i] += kt[tt][mg + 8 * i] * vv;
    }
    if (tid < MF) {
      #pragma unroll 8
      for (int tt = 0; tt < 32; tt++) ks += kt[tt][tid];
    }
    __syncthreads();
  }
  #pragma unroll
  for (int i = 0; i < 16; i++) ctx[((size_t)bh * MF + mg + 8 * i) * DH + d] = acc[i];
  if (tid < MF) ksum[bh * MF + tid] = ks;
}

// ---------------- o = (qp @ ctx) / (qp @ ksum), write in (B,T,D) layout ----------------
__global__ __launch_bounds__(256) void o_kernel(const float* __restrict__ qp, const float* __restrict__ ctx,
                         const float* __restrict__ ksum, float* __restrict__ o) {
  int bh = blockIdx.x;
  int b = bh >> 3, h = bh & 7;
  __shared__ float ct[MF][DH];
  __shared__ float ksl[MF];
  __shared__ float qt[8][MF];
  int tid = threadIdx.x;
  #pragma unroll
  for (int i = 0; i < 16; i++) {
    int lin = i * 256 + tid;
    ct[lin >> 5][lin & 31] = ctx[(size_t)bh * (MF * DH) + lin];
  }
  if (tid < MF) ksl[tid] = ksum[bh * MF + tid];
  __syncthreads();
  int d = tid & 31, tl = tid >> 5;
  for (int t0 = 0; t0 < T; t0 += 8) {
    #pragma unroll
    for (int i = 0; i < 4; i++) {
      int lin = i * 256 + tid;
      int tt = lin >> 7, mm = lin & 127;
      qt[tt][mm] = qp[((size_t)bh * T + t0 + tt) * MF + mm];
    }
    __syncthreads();
    float ao = 0.f, ad = 0.f;
    for (int mm = 0; mm < MF; mm++) {
      float qv = qt[tl][mm];
      ao += qv * ct[mm][d];
      ad += qv * ksl[mm];
    }
    int t = t0 + tl;
    o[((size_t)(b * T) + t) * D + h * DH + d] = ao / ad;
    __syncthreads();
  }
}

// ---------------- final masks: out (B, NM, T) ----------------
__global__ void mask_kernel(const float* __restrict__ x, const float* __restrict__ Wm,
                            const float* __restrict__ bm, float* __restrict__ out) {
  int row = blockIdx.x * 4 + (threadIdx.x >> 6); // b*T + t
  int lane = threadIdx.x & 63;
  const float4 v = ((const float4*)(x + (size_t)row * D))[lane];
  int b = row >> 9, t = row & 511;
  #pragma unroll
  for (int msk = 0; msk < NM; msk++) {
    const float* wc = Wm + msk;
    float s = v.x * wc[(lane * 4 + 0) * NM] + v.y * wc[(lane * 4 + 1) * NM] +
              v.z * wc[(lane * 4 + 2) * NM] + v.w * wc[(lane * 4 + 3) * NM];
    #pragma unroll
    for (int off = 32; off; off >>= 1) s += __shfl_down(s, off);
    if (lane == 0) out[((size_t)(b * NM) + msk) * T + t] = s + bm[msk];
  }
}

extern "C" void kernel_launch(void* const* d_in, const int* in_sizes, int n_in,
                              void* d_out, int out_size, void* d_ws, size_t ws_size,
                              hipStream_t stream) {
  const float* mel   = (const float*)d_in[0];
  const float* proj  = (const float*)d_in[1];
  const float* ln1_g = (const float*)d_in[2];
  const float* ln1_b = (const float*)d_in[3];
  const float* Wq    = (const float*)d_in[4];
  const float* Wk    = (const float*)d_in[5];
  const float* Wv    = (const float*)d_in[6];
  const float* Wo    = (const float*)d_in[7];
  const float* bo    = (const float*)d_in[8];
  const float* ln2_g = (const float*)d_in[9];
  const float* ln2_b = (const float*)d_in[10];
  const float* W1    = (const float*)d_in[11];
  const float* b1    = (const float*)d_in[12];
  const float* W2    = (const float*)d_in[13];
  const float* b2    = (const float*)d_in[14];
  const float* Wm    = (const float*)d_in[15];
  const float* bm    = (const float*)d_in[16];

  float* ws = (float*)d_ws;
  const size_t SZ_ACT = (size_t)BT * D;       // 4,194,304
  const size_t SZ_FEAT = (size_t)B * H * T * MF; // 16,777,216
  float* x    = ws;
  float* h    = x + SZ_ACT;
  float* q    = h + SZ_ACT;
  float* k    = q + SZ_ACT;
  float* v    = k + SZ_ACT;
  float* qp   = v + SZ_ACT;
  float* kp   = qp + SZ_FEAT;
  float* ctx  = kp + SZ_FEAT;                 // B*H*MF*DH = 1,048,576
  float* ksum = ctx + (size_t)B * H * MF * DH;
  float* kdiag= ksum + (size_t)B * H * MF;    // B*H*T
  float* krmax= kdiag + (size_t)B * H * T;
  float* kmax = krmax + (size_t)B * H * T;    // B*H
  float* o    = q;   // reuse q
  float* ffh  = qp;  // reuse qp

  transpose_mel<<<dim3(T / 32, D / 32, B), dim3(32, 8), 0, stream>>>(mel, x);

  for (int l = 0; l < NLAYER; l++) {
    const float* wq = Wq + (size_t)l * D * D;
    const float* wk = Wk + (size_t)l * D * D;
    const float* wv = Wv + (size_t)l * D * D;
    const float* wo = Wo + (size_t)l * D * D;
    const float* w1 = W1 + (size_t)l * D * FF;
    const float* w2 = W2 + (size_t)l * FF * D;

    ln_kernel<<<BT, 64, 0, stream>>>(x, ln1_g + l * D, ln1_b + l * D, h);
    gemm64<0,0,0><<<dim3(D / 64, BT / 64), 256, 0, stream>>>(h, wq, nullptr, nullptr, q, D, D);
    gemm64<0,0,0><<<dim3(D / 64, BT / 64), 256, 0, stream>>>(h, wk, nullptr, nullptr, k, D, D);
    gemm64<0,0,0><<<dim3(D / 64, BT / 64), 256, 0, stream>>>(h, wv, nullptr, nullptr, v, D, D);

    favor_q<<<B * H * T, 128, 0, stream>>>(q, proj, qp);
    favor_k1<<<B * H * T, 128, 0, stream>>>(k, proj, kp, kdiag, krmax);
    kmax_reduce<<<B * H, 256, 0, stream>>>(krmax, kmax);
    favor_k2<<<(B * H * T * MF) / 256, 256, 0, stream>>>(kp, kdiag, kmax);

    ctx_kernel<<<B * H, 256, 0, stream>>>(kp, v, ctx, ksum);
    o_kernel<<<B * H, 256, 0, stream>>>(qp, ctx, ksum, o);

    gemm64<1,1,0><<<dim3(D / 64, BT / 64), 256, 0, stream>>>(o, wo, bo + l * D, x, x, D, D);

    ln_kernel<<<BT, 64, 0, stream>>>(x, ln2_g + l * D, ln2_b + l * D, h);
    gemm64<1,0,1><<<dim3(FF / 64, BT / 64), 256, 0, stream>>>(h, w1, b1 + (size_t)l * FF, nullptr, ffh, FF, D);
    gemm64<1,1,0><<<dim3(D / 64, BT / 64), 256, 0, stream>>>(ffh, w2, b2 + l * D, x, x, D, FF);
  }

  mask_kernel<<<BT / 4, 256, 0, stream>>>(x, Wm, bm, (float*)d_out);
}

// Round 3
// 1198.494 us; speedup vs baseline: 7.1482x; 7.1482x over previous
//
#include <hip/hip_runtime.h>
#include <math.h>

#define B 32
#define T 512
#define D 256
#define H 8
#define DH 32
#define MF 128
#define NLAYER 6
#define FF 1024
#define NM 4
#define BT (B*T)
#define BH (B*H)

#define DN2H 0.08838834764831845f   /* 0.5 * 32^-0.5 (0.5*dn^2) */
#define DNS  0.4204482076268573f    /* 32^-0.25 */
#define RATIO 0.08838834764831845f  /* 128^-0.5 */
#define KEPS 1e-4f

typedef __attribute__((ext_vector_type(8))) short short8;
typedef __attribute__((ext_vector_type(4))) float f32x4;

__device__ __forceinline__ ushort f2b(float x) {
  union { float f; unsigned u; } c; c.f = x;
  unsigned r = (c.u + 0x7FFFu + ((c.u >> 16) & 1u)) >> 16;
  return (ushort)r;
}
__device__ __forceinline__ float bf2f(ushort u) {
  union { unsigned u; float f; } c; c.u = ((unsigned)u) << 16;
  return c.f;
}

// ---------------- transpose mel (B,D,T) -> x (B,T,D) fp32 ----------------
__global__ void transpose_mel(const float* __restrict__ mel, float* __restrict__ x) {
  __shared__ float tile[32][33];
  int b = blockIdx.z;
  int d0 = blockIdx.y * 32, t0 = blockIdx.x * 32;
  int tx = threadIdx.x, ty = threadIdx.y;
  #pragma unroll
  for (int i = 0; i < 32; i += 8)
    tile[ty + i][tx] = mel[(b * D + d0 + ty + i) * T + t0 + tx];
  __syncthreads();
  #pragma unroll
  for (int i = 0; i < 32; i += 8)
    x[(b * T + t0 + ty + i) * D + d0 + tx] = tile[tx][ty + i];
}

// ---------------- weight transpose+convert: W[K][N] fp32 -> WT[N][K] bf16 ----------------
__global__ void wtrans(const float* __restrict__ W, ushort* __restrict__ WT,
                       int K, int N, size_t lin, size_t lout) {
  __shared__ float tile[32][33];
  int l = blockIdx.z;
  const float* Wl = W + (size_t)l * lin;
  ushort* WTl = WT + (size_t)l * lout;
  int k0 = blockIdx.y * 32, n0 = blockIdx.x * 32;
  int tx = threadIdx.x, ty = threadIdx.y;
  #pragma unroll
  for (int i = 0; i < 32; i += 8)
    tile[ty + i][tx] = Wl[(size_t)(k0 + ty + i) * N + n0 + tx];
  __syncthreads();
  #pragma unroll
  for (int i = 0; i < 32; i += 8)
    WTl[(size_t)(n0 + ty + i) * K + k0 + tx] = f2b(tile[tx][ty + i]);
}

// ---------------- proj convert (prescaled by DN) ----------------
__global__ void proj_conv(const float* __restrict__ proj, ushort* __restrict__ projd) {
  int e = blockIdx.x * 256 + threadIdx.x;
  if (e < MF * DH) projd[e] = f2b(proj[e] * DNS);
}

// ---------------- layernorm: 4 rows per block, bf16 out ----------------
__global__ __launch_bounds__(256) void ln_kernel(const float* __restrict__ x, const float* __restrict__ g,
                          const float* __restrict__ bb, ushort* __restrict__ y) {
  int row = blockIdx.x * 4 + (threadIdx.x >> 6);
  int lane = threadIdx.x & 63;
  const float4 v = ((const float4*)(x + (size_t)row * D))[lane];
  float s = v.x + v.y + v.z + v.w;
  #pragma unroll
  for (int off = 32; off; off >>= 1) s += __shfl_down(s, off);
  s = __shfl(s, 0);
  float mu = s * (1.0f / 256.0f);
  float dx = v.x - mu, dy = v.y - mu, dz = v.z - mu, dw = v.w - mu;
  float q = dx * dx + dy * dy + dz * dz + dw * dw;
  #pragma unroll
  for (int off = 32; off; off >>= 1) q += __shfl_down(q, off);
  q = __shfl(q, 0);
  float rstd = rsqrtf(q * (1.0f / 256.0f) + 1e-5f);
  const float4 gg = ((const float4*)g)[lane];
  const float4 be = ((const float4*)bb)[lane];
  ushort4 o;
  o.x = f2b(dx * rstd * gg.x + be.x);
  o.y = f2b(dy * rstd * gg.y + be.y);
  o.z = f2b(dz * rstd * gg.z + be.z);
  o.w = f2b(dw * rstd * gg.w + be.w);
  ((ushort4*)(y + (size_t)row * D))[lane] = o;
}

// ---------------- bf16 MFMA GEMM: C[M,N] = A[M,K] @ WT[N,K]^T ----------------
// EPI 0: QKV split (q,k natural bf16; v transposed [bh*32+d][T])
// EPI 1: + bias + res -> fp32
// EPI 2: + bias + gelu -> bf16
template<int EPI>
__global__ __launch_bounds__(256) void gemm_bf16(
    const ushort* __restrict__ A, const ushort* __restrict__ BTm,
    const float* __restrict__ bias, const float* __restrict__ res,
    float* __restrict__ outF, ushort* __restrict__ outB,
    ushort* __restrict__ qo, ushort* __restrict__ ko, ushort* __restrict__ vT,
    int N, int K) {
  __shared__ __align__(16) ushort Al[128 * 40];
  __shared__ __align__(16) ushort Bl[128 * 40];
  int tid = threadIdx.x;
  int wave = tid >> 6, lane = tid & 63;
  int wr = wave >> 1, wc = wave & 1;
  int gi = lane >> 4, li = lane & 15;
  int row0 = blockIdx.y * 128, col0 = blockIdx.x * 128;
  f32x4 acc[4][4] = {};
  for (int k0 = 0; k0 < K; k0 += 32) {
    #pragma unroll
    for (int j = 0; j < 2; j++) {
      int c = j * 256 + tid;
      int r = c >> 2, g = c & 3;
      *(uint4*)&Al[r * 40 + g * 8] = *(const uint4*)&A[(size_t)(row0 + r) * K + k0 + g * 8];
      *(uint4*)&Bl[r * 40 + g * 8] = *(const uint4*)&BTm[(size_t)(col0 + r) * K + k0 + g * 8];
    }
    __syncthreads();
    short8 a[4], b[4];
    #pragma unroll
    for (int m = 0; m < 4; m++)
      a[m] = *(const short8*)&Al[(wr * 64 + m * 16 + li) * 40 + gi * 8];
    #pragma unroll
    for (int n = 0; n < 4; n++)
      b[n] = *(const short8*)&Bl[(wc * 64 + n * 16 + li) * 40 + gi * 8];
    #pragma unroll
    for (int m = 0; m < 4; m++)
      #pragma unroll
      for (int n = 0; n < 4; n++)
        acc[m][n] = __builtin_amdgcn_mfma_f32_16x16x32_bf16(a[m], b[n], acc[m][n], 0, 0, 0);
    __syncthreads();
  }
  #pragma unroll
  for (int m = 0; m < 4; m++) {
    int rbase = row0 + wr * 64 + m * 16 + gi * 4;
    #pragma unroll
    for (int n = 0; n < 4; n++) {
      int col = col0 + wc * 64 + n * 16 + li;
      f32x4 v = acc[m][n];
      if (EPI == 1) {
        float bs = bias[col];
        #pragma unroll
        for (int r = 0; r < 4; r++) {
          size_t off = (size_t)(rbase + r) * N + col;
          outF[off] = v[r] + bs + res[off];
        }
      } else if (EPI == 2) {
        float bs = bias[col];
        #pragma unroll
        for (int r = 0; r < 4; r++) {
          float u = v[r] + bs;
          float gel = 0.5f * u * (1.0f + tanhf(0.7978845608028654f * (u + 0.044715f * u * u * u)));
          outB[(size_t)(rbase + r) * N + col] = f2b(gel);
        }
      } else {
        if (col < 256) {
          #pragma unroll
          for (int r = 0; r < 4; r++) qo[(size_t)(rbase + r) * 256 + col] = f2b(v[r]);
        } else if (col < 512) {
          #pragma unroll
          for (int r = 0; r < 4; r++) ko[(size_t)(rbase + r) * 256 + col - 256] = f2b(v[r]);
        } else {
          int b_ = rbase >> 9, t = rbase & 511;
          int hh = (col - 512) >> 5, d = (col - 512) & 31;
          ushort4 pk;
          pk.x = f2b(v[0]); pk.y = f2b(v[1]); pk.z = f2b(v[2]); pk.w = f2b(v[3]);
          *(ushort4*)&vT[((size_t)((b_ * 8 + hh) * 32 + d)) * 512 + t] = pk;
        }
      }
    }
  }
}

// ---------------- FAVOR+ feature GEMM: rows = bh*T+t, K=32 ----------------
// IS_Q=1: qp[bh][t][m] = ratio*(exp(s - diag - rowmax)+eps) bf16
// IS_Q=0: kpT[bh][m][t] = raw s bf16; kdiagT/krmaxT[bh][t]
template<int IS_Q>
__global__ __launch_bounds__(256) void favor_gemm(
    const ushort* __restrict__ X, const ushort* __restrict__ projd,
    ushort* __restrict__ outQ, ushort* __restrict__ outKT,
    float* __restrict__ kdiagT, float* __restrict__ krmaxT) {
  __shared__ __align__(16) ushort Al[128 * 40];
  __shared__ __align__(16) ushort Bl[128 * 40];
  __shared__ float diag_s[128];
  int tid = threadIdx.x;
  int wave = tid >> 6, lane = tid & 63;
  int gi = lane >> 4, li = lane & 15;
  int row0 = blockIdx.x * 128;   // bh*512 + t
  int bh = row0 >> 9;
  int t0 = row0 & 511;
  int b = bh >> 3, h = bh & 7;
  const ushort* Xb = X + (size_t)(b * 512) * 256 + h * 32;
  #pragma unroll
  for (int j = 0; j < 2; j++) {
    int c = j * 256 + tid;
    int r = c >> 2, g = c & 3;
    *(uint4*)&Al[r * 40 + g * 8] = *(const uint4*)&Xb[(size_t)(t0 + r) * 256 + g * 8];
    *(uint4*)&Bl[r * 40 + g * 8] = *(const uint4*)&projd[r * 32 + g * 8];
  }
  __syncthreads();
  short8 a[2];
  f32x4 acc[2][8] = {};
  #pragma unroll
  for (int m = 0; m < 2; m++) {
    a[m] = *(const short8*)&Al[(wave * 32 + m * 16 + li) * 40 + gi * 8];
    float s = 0.f;
    #pragma unroll
    for (int i = 0; i < 8; i++) {
      float xv = bf2f((ushort)a[m][i]);
      s += xv * xv;
    }
    s += __shfl_xor(s, 16);
    s += __shfl_xor(s, 32);
    if (gi == 0) diag_s[wave * 32 + m * 16 + li] = DN2H * s;
  }
  short8 bfr[8];
  #pragma unroll
  for (int n = 0; n < 8; n++)
    bfr[n] = *(const short8*)&Bl[(n * 16 + li) * 40 + gi * 8];
  #pragma unroll
  for (int m = 0; m < 2; m++)
    #pragma unroll
    for (int n = 0; n < 8; n++)
      acc[m][n] = __builtin_amdgcn_mfma_f32_16x16x32_bf16(a[m], bfr[n], acc[m][n], 0, 0, 0);

  #pragma unroll
  for (int m = 0; m < 2; m++) {
    float mx[4], dgv[4];
    #pragma unroll
    for (int r = 0; r < 4; r++) {
      float mv = -1e30f;
      #pragma unroll
      for (int n = 0; n < 8; n++) mv = fmaxf(mv, acc[m][n][r]);
      #pragma unroll
      for (int msk = 1; msk <= 8; msk <<= 1) mv = fmaxf(mv, __shfl_xor(mv, msk));
      mx[r] = mv;
      dgv[r] = diag_s[wave * 32 + m * 16 + gi * 4 + r];
    }
    int tb = t0 + wave * 32 + m * 16 + gi * 4;
    if (IS_Q) {
      #pragma unroll
      for (int n = 0; n < 8; n++)
        #pragma unroll
        for (int r = 0; r < 4; r++)
          outQ[((size_t)bh * 512 + tb + r) * 128 + n * 16 + li] =
              f2b(RATIO * (expf(acc[m][n][r] - dgv[r] - mx[r]) + KEPS));
    } else {
      #pragma unroll
      for (int n = 0; n < 8; n++) {
        ushort4 pk;
        pk.x = f2b(acc[m][n][0]); pk.y = f2b(acc[m][n][1]);
        pk.z = f2b(acc[m][n][2]); pk.w = f2b(acc[m][n][3]);
        *(ushort4*)&outKT[((size_t)bh * 128 + n * 16 + li) * 512 + tb] = pk;
      }
      if (li == 0) {
        #pragma unroll
        for (int r = 0; r < 4; r++) {
          kdiagT[(size_t)bh * 512 + tb + r] = dgv[r];
          krmaxT[(size_t)bh * 512 + tb + r] = mx[r];
        }
      }
    }
  }
}

// ---------------- per-bh max over T ----------------
__global__ void kmax_reduce(const float* __restrict__ krmaxT, float* __restrict__ kmax) {
  int bh = blockIdx.x;
  int tid = threadIdx.x;
  __shared__ float red[256];
  red[tid] = fmaxf(krmaxT[bh * 512 + tid], krmaxT[bh * 512 + 256 + tid]);
  __syncthreads();
  for (int s = 128; s; s >>= 1) {
    if (tid < s) red[tid] = fmaxf(red[tid], red[tid + s]);
    __syncthreads();
  }
  if (tid == 0) kmax[bh] = red[0];
}

// ---------------- kp finish: kp = ratio*(exp(s - diag - kmax)+eps), in place ----------------
__global__ void kp_finish(ushort* __restrict__ kpT, const float* __restrict__ kdiagT,
                          const float* __restrict__ kmax) {
  size_t e = ((size_t)blockIdx.x * 256 + threadIdx.x) * 8;
  int row = (int)(e >> 9);
  int bh = row >> 7;
  int t = (int)(e & 511);
  uint4 raw = *(const uint4*)&kpT[e];
  ushort* rs = (ushort*)&raw;
  float km = kmax[bh];
  const float* kd = kdiagT + (size_t)bh * 512 + t;
  ushort out[8];
  #pragma unroll
  for (int i = 0; i < 8; i++)
    out[i] = f2b(RATIO * (expf(bf2f(rs[i]) - kd[i] - km) + KEPS));
  *(uint4*)&kpT[e] = *(uint4*)out;
}

// ---------------- ctx: [128 feat x 32 dh] = kpT[128,512] @ vT[32,512]^T per bh ----------------
// writes Bmat rows 0..31 (ctx transposed: Bmat[bh][d][m])
__global__ __launch_bounds__(256) void ctx_gemm(const ushort* __restrict__ kpT,
                                                const ushort* __restrict__ vT,
                                                ushort* __restrict__ Bmat) {
  __shared__ __align__(16) ushort Akl[128 * 40];
  __shared__ __align__(16) ushort Bvl[32 * 40];
  int bh = blockIdx.x;
  int tid = threadIdx.x;
  int wave = tid >> 6, lane = tid & 63;
  int gi = lane >> 4, li = lane & 15;
  const ushort* Ab = kpT + (size_t)bh * 128 * 512;
  const ushort* Bb = vT + (size_t)bh * 32 * 512;
  f32x4 acc[2][2] = {};
  for (int ks = 0; ks < 16; ks++) {
    int kt = ks * 32;
    #pragma unroll
    for (int j = 0; j < 2; j++) {
      int c = j * 256 + tid;
      int r = c >> 2, g = c & 3;
      *(uint4*)&Akl[r * 40 + g * 8] = *(const uint4*)&Ab[(size_t)r * 512 + kt + g * 8];
    }
    if (tid < 128) {
      int r = tid >> 2, g = tid & 3;
      *(uint4*)&Bvl[r * 40 + g * 8] = *(const uint4*)&Bb[(size_t)r * 512 + kt + g * 8];
    }
    __syncthreads();
    short8 a[2], bb[2];
    #pragma unroll
    for (int m = 0; m < 2; m++)
      a[m] = *(const short8*)&Akl[(wave * 32 + m * 16 + li) * 40 + gi * 8];
    #pragma unroll
    for (int n = 0; n < 2; n++)
      bb[n] = *(const short8*)&Bvl[(n * 16 + li) * 40 + gi * 8];
    #pragma unroll
    for (int m = 0; m < 2; m++)
      #pragma unroll
      for (int n = 0; n < 2; n++)
        acc[m][n] = __builtin_amdgcn_mfma_f32_16x16x32_bf16(a[m], bb[n], acc[m][n], 0, 0, 0);
    __syncthreads();
  }
  #pragma unroll
  for (int m = 0; m < 2; m++)
    #pragma unroll
    for (int n = 0; n < 2; n++) {
      int d = n * 16 + li;
      int mg = wave * 32 + m * 16 + gi * 4;
      ushort4 pk;
      pk.x = f2b(acc[m][n][0]); pk.y = f2b(acc[m][n][1]);
      pk.z = f2b(acc[m][n][2]); pk.w = f2b(acc[m][n][3]);
      *(ushort4*)&Bmat[((size_t)bh * 48 + d) * 128 + mg] = pk;
    }
}

// ---------------- ksum -> Bmat row 32; zero rows 33..47 ----------------
__global__ __launch_bounds__(256) void ksum_kernel(const ushort* __restrict__ kpT,
                                                   ushort* __restrict__ Bmat) {
  int bh = blockIdx.x;
  int tid = threadIdx.x;
  int wave = tid >> 6, lane = tid & 63;
  for (int i = 0; i < 32; i++) {
    int m = wave * 32 + i;
    uint4 raw = *(const uint4*)&kpT[((size_t)bh * 128 + m) * 512 + lane * 8];
    ushort* rs = (ushort*)&raw;
    float s = 0.f;
    #pragma unroll
    for (int j = 0; j < 8; j++) s += bf2f(rs[j]);
    #pragma unroll
    for (int off = 32; off; off >>= 1) s += __shfl_down(s, off);
    if (lane == 0) Bmat[((size_t)bh * 48 + 32) * 128 + m] = f2b(s);
  }
  for (int e = tid; e < 15 * 128; e += 256)
    Bmat[((size_t)bh * 48 + 33) * 128 + e] = 0;
}

// ---------------- o = qp @ [ctxT;ksum]^T, divide by denom col, write bf16 [bt][256] ----------------
__global__ __launch_bounds__(256) void o_gemm(const ushort* __restrict__ qp,
                                              const ushort* __restrict__ Bmat,
                                              ushort* __restrict__ o) {
  __shared__ __align__(16) ushort Aql[64 * 136];
  __shared__ __align__(16) ushort Bml[48 * 136];
  int bh = blockIdx.y;
  int t0 = blockIdx.x * 64;
  int tid = threadIdx.x;
  int wave = tid >> 6, lane = tid & 63;
  int gi = lane >> 4, li = lane & 15;
  #pragma unroll
  for (int j = 0; j < 4; j++) {
    int c = j * 256 + tid;
    int r = c >> 4, g = c & 15;
    *(uint4*)&Aql[r * 136 + g * 8] = *(const uint4*)&qp[((size_t)bh * 512 + t0 + r) * 128 + g * 8];
  }
  #pragma unroll
  for (int j = 0; j < 3; j++) {
    int c = j * 256 + tid;
    int r = c >> 4, g = c & 15;
    *(uint4*)&Bml[r * 136 + g * 8] = *(const uint4*)&Bmat[((size_t)bh * 48 + r) * 128 + g * 8];
  }
  __syncthreads();
  f32x4 acc[3] = {};
  #pragma unroll
  for (int ks = 0; ks < 4; ks++) {
    short8 a = *(const short8*)&Aql[(wave * 16 + li) * 136 + ks * 32 + gi * 8];
    #pragma unroll
    for (int n = 0; n < 3; n++) {
      short8 bb = *(const short8*)&Bml[(n * 16 + li) * 136 + ks * 32 + gi * 8];
      acc[n] = __builtin_amdgcn_mfma_f32_16x16x32_bf16(a, bb, acc[n], 0, 0, 0);
    }
  }
  int b = bh >> 3, h = bh & 7;
  int t = t0 + wave * 16 + gi * 4;
  float den[4];
  #pragma unroll
  for (int r = 0; r < 4; r++) den[r] = __shfl(acc[2][r], lane & 48);
  #pragma unroll
  for (int n = 0; n < 2; n++)
    #pragma unroll
    for (int r = 0; r < 4; r++)
      o[((size_t)(b * 512) + t + r) * 256 + h * 32 + n * 16 + li] = f2b(acc[n][r] / den[r]);
}

// ---------------- final masks: out (B, NM, T) fp32 ----------------
__global__ void mask_kernel(const float* __restrict__ x, const float* __restrict__ Wm,
                            const float* __restrict__ bm, float* __restrict__ out) {
  int row = blockIdx.x * 4 + (threadIdx.x >> 6);
  int lane = threadIdx.x & 63;
  const float4 v = ((const float4*)(x + (size_t)row * D))[lane];
  int b = row >> 9, t = row & 511;
  #pragma unroll
  for (int msk = 0; msk < NM; msk++) {
    const float* wc = Wm + msk;
    float s = v.x * wc[(lane * 4 + 0) * NM] + v.y * wc[(lane * 4 + 1) * NM] +
              v.z * wc[(lane * 4 + 2) * NM] + v.w * wc[(lane * 4 + 3) * NM];
    #pragma unroll
    for (int off = 32; off; off >>= 1) s += __shfl_down(s, off);
    if (lane == 0) out[((size_t)(b * NM) + msk) * T + t] = s + bm[msk];
  }
}

extern "C" void kernel_launch(void* const* d_in, const int* in_sizes, int n_in,
                              void* d_out, int out_size, void* d_ws, size_t ws_size,
                              hipStream_t stream) {
  const float* mel   = (const float*)d_in[0];
  const float* proj  = (const float*)d_in[1];
  const float* ln1_g = (const float*)d_in[2];
  const float* ln1_b = (const float*)d_in[3];
  const float* Wq    = (const float*)d_in[4];
  const float* Wk    = (const float*)d_in[5];
  const float* Wv    = (const float*)d_in[6];
  const float* Wo    = (const float*)d_in[7];
  const float* bo    = (const float*)d_in[8];
  const float* ln2_g = (const float*)d_in[9];
  const float* ln2_b = (const float*)d_in[10];
  const float* W1    = (const float*)d_in[11];
  const float* b1    = (const float*)d_in[12];
  const float* W2    = (const float*)d_in[13];
  const float* b2    = (const float*)d_in[14];
  const float* Wm    = (const float*)d_in[15];
  const float* bm    = (const float*)d_in[16];

  // ---- workspace layout ----
  float* x      = (float*)d_ws;                        // BT*D
  float* kdiagT = x + (size_t)BT * D;                  // BH*T
  float* krmaxT = kdiagT + (size_t)BH * T;             // BH*T
  float* kmax   = krmaxT + (size_t)BH * T;             // BH
  ushort* us    = (ushort*)(kmax + 256);
  ushort* h     = us;                   us += (size_t)BT * D;
  ushort* qb    = us;                   us += (size_t)BT * D;
  ushort* kb    = us;                   us += (size_t)BT * D;
  ushort* vT    = us;                   us += (size_t)BT * D;
  ushort* ob    = us;                   us += (size_t)BT * D;
  ushort* qp    = us;                   us += (size_t)BH * T * MF;
  ushort* kpT   = us;                   us += (size_t)BH * T * MF;
  ushort* ffh   = us;                   us += (size_t)BT * FF;
  ushort* Bmat  = us;                   us += (size_t)BH * 48 * MF;
  ushort* qkvT  = us;                   us += (size_t)NLAYER * 768 * 256;
  ushort* woT   = us;                   us += (size_t)NLAYER * 256 * 256;
  ushort* w1T   = us;                   us += (size_t)NLAYER * 1024 * 256;
  ushort* w2T   = us;                   us += (size_t)NLAYER * 256 * 1024;
  ushort* projd = us;                   us += (size_t)MF * DH;

  // ---- prep: transposed bf16 weights ----
  wtrans<<<dim3(8, 8, NLAYER), dim3(32, 8), 0, stream>>>(Wq, qkvT, 256, 256, 65536, 768 * 256);
  wtrans<<<dim3(8, 8, NLAYER), dim3(32, 8), 0, stream>>>(Wk, qkvT + 256 * 256, 256, 256, 65536, 768 * 256);
  wtrans<<<dim3(8, 8, NLAYER), dim3(32, 8), 0, stream>>>(Wv, qkvT + 512 * 256, 256, 256, 65536, 768 * 256);
  wtrans<<<dim3(8, 8, NLAYER), dim3(32, 8), 0, stream>>>(Wo, woT, 256, 256, 65536, 65536);
  wtrans<<<dim3(32, 8, NLAYER), dim3(32, 8), 0, stream>>>(W1, w1T, 256, 1024, 262144, 262144);
  wtrans<<<dim3(8, 32, NLAYER), dim3(32, 8), 0, stream>>>(W2, w2T, 1024, 256, 262144, 262144);
  proj_conv<<<16, 256, 0, stream>>>(proj, projd);

  transpose_mel<<<dim3(T / 32, D / 32, B), dim3(32, 8), 0, stream>>>(mel, x);

  for (int l = 0; l < NLAYER; l++) {
    const ushort* qkvTl = qkvT + (size_t)l * 768 * 256;
    ln_kernel<<<BT / 4, 256, 0, stream>>>(x, ln1_g + l * D, ln1_b + l * D, h);
    gemm_bf16<0><<<dim3(6, 128), 256, 0, stream>>>(h, qkvTl, nullptr, nullptr,
        nullptr, nullptr, qb, kb, vT, 768, 256);
    favor_gemm<1><<<1024, 256, 0, stream>>>(qb, projd, qp, nullptr, nullptr, nullptr);
    favor_gemm<0><<<1024, 256, 0, stream>>>(kb, projd, nullptr, kpT, kdiagT, krmaxT);
    kmax_reduce<<<BH, 256, 0, stream>>>(krmaxT, kmax);
    kp_finish<<<(BH * T * MF) / 2048, 256, 0, stream>>>(kpT, kdiagT, kmax);
    ctx_gemm<<<BH, 256, 0, stream>>>(kpT, vT, Bmat);
    ksum_kernel<<<BH, 256, 0, stream>>>(kpT, Bmat);
    o_gemm<<<dim3(8, BH), 256, 0, stream>>>(qp, Bmat, ob);
    gemm_bf16<1><<<dim3(2, 128), 256, 0, stream>>>(ob, woT + (size_t)l * 256 * 256,
        bo + l * D, x, x, nullptr, nullptr, nullptr, nullptr, 256, 256);
    ln_kernel<<<BT / 4, 256, 0, stream>>>(x, ln2_g + l * D, ln2_b + l * D, h);
    gemm_bf16<2><<<dim3(8, 128), 256, 0, stream>>>(h, w1T + (size_t)l * 1024 * 256,
        b1 + (size_t)l * FF, nullptr, nullptr, ffh, nullptr, nullptr, nullptr, 1024, 256);
    gemm_bf16<1><<<dim3(2, 128), 256, 0, stream>>>(ffh, w2T + (size_t)l * 256 * 1024,
        b2 + l * D, x, x, nullptr, nullptr, nullptr, nullptr, 256, 1024);
  }

  mask_kernel<<<BT / 4, 256, 0, stream>>>(x, Wm, bm, (float*)d_out);
}

// Round 4
// 1050.189 us; speedup vs baseline: 8.1577x; 1.1412x over previous
//
#include <hip/hip_runtime.h>
#include <math.h>

#define B 32
#define T 512
#define D 256
#define H 8
#define DH 32
#define MF 128
#define NLAYER 6
#define FF 1024
#define NM 4
#define BT (B*T)
#define BH (B*H)

#define DN2H 0.08838834764831845f   /* 0.5 * 32^-0.5 (0.5*dn^2) */
#define DNS  0.4204482076268573f    /* 32^-0.25 */
#define RATIO 0.08838834764831845f  /* 128^-0.5 */
#define KEPS 1e-4f

typedef __attribute__((ext_vector_type(8))) short short8;
typedef __attribute__((ext_vector_type(4))) float f32x4;

__device__ __forceinline__ ushort f2b(float x) {
  union { float f; unsigned u; } c; c.f = x;
  unsigned r = (c.u + 0x7FFFu + ((c.u >> 16) & 1u)) >> 16;
  return (ushort)r;
}
__device__ __forceinline__ float bf2f(ushort u) {
  union { unsigned u; float f; } c; c.u = ((unsigned)u) << 16;
  return c.f;
}
__device__ __forceinline__ void gload16(const ushort* g, ushort* l) {
  __builtin_amdgcn_global_load_lds((const __attribute__((address_space(1))) void*)g,
                                   (__attribute__((address_space(3))) void*)l, 16, 0, 0);
}

// ---------------- transpose mel (B,D,T) -> x (B,T,D) fp32 ----------------
__global__ void transpose_mel(const float* __restrict__ mel, float* __restrict__ x) {
  __shared__ float tile[32][33];
  int b = blockIdx.z;
  int d0 = blockIdx.y * 32, t0 = blockIdx.x * 32;
  int tx = threadIdx.x, ty = threadIdx.y;
  #pragma unroll
  for (int i = 0; i < 32; i += 8)
    tile[ty + i][tx] = mel[(b * D + d0 + ty + i) * T + t0 + tx];
  __syncthreads();
  #pragma unroll
  for (int i = 0; i < 32; i += 8)
    x[(b * T + t0 + ty + i) * D + d0 + tx] = tile[tx][ty + i];
}

// ---------------- weight transpose+convert: W[K][N] fp32 -> WT[N][K] bf16 ----------------
__global__ void wtrans(const float* __restrict__ W, ushort* __restrict__ WT,
                       int K, int N, size_t lin, size_t lout) {
  __shared__ float tile[32][33];
  int l = blockIdx.z;
  const float* Wl = W + (size_t)l * lin;
  ushort* WTl = WT + (size_t)l * lout;
  int k0 = blockIdx.y * 32, n0 = blockIdx.x * 32;
  int tx = threadIdx.x, ty = threadIdx.y;
  #pragma unroll
  for (int i = 0; i < 32; i += 8)
    tile[ty + i][tx] = Wl[(size_t)(k0 + ty + i) * N + n0 + tx];
  __syncthreads();
  #pragma unroll
  for (int i = 0; i < 32; i += 8)
    WTl[(size_t)(n0 + ty + i) * K + k0 + tx] = f2b(tile[tx][ty + i]);
}

// ---------------- proj convert (prescaled by DN) ----------------
__global__ void proj_conv(const float* __restrict__ proj, ushort* __restrict__ projd) {
  int e = blockIdx.x * 256 + threadIdx.x;
  if (e < MF * DH) projd[e] = f2b(proj[e] * DNS);
}

// ---------------- vT constant rows init: row 32 = 1.0, rows 33..63 = 0 ----------------
__global__ void vinit(ushort* __restrict__ vT) {
  int bh = blockIdx.x;
  int tid = threadIdx.x;
  for (int r = 32; r < 64; r++) {
    ushort val = (r == 32) ? (ushort)0x3F80 : (ushort)0;
    for (int e = tid; e < 512; e += 256)
      vT[((size_t)bh * 64 + r) * 512 + e] = val;
  }
}

// ---------------- layernorm: 4 rows per block, bf16 out ----------------
__global__ __launch_bounds__(256) void ln_kernel(const float* __restrict__ x, const float* __restrict__ g,
                          const float* __restrict__ bb, ushort* __restrict__ y) {
  int row = blockIdx.x * 4 + (threadIdx.x >> 6);
  int lane = threadIdx.x & 63;
  const float4 v = ((const float4*)(x + (size_t)row * D))[lane];
  float s = v.x + v.y + v.z + v.w;
  #pragma unroll
  for (int off = 32; off; off >>= 1) s += __shfl_down(s, off);
  s = __shfl(s, 0);
  float mu = s * (1.0f / 256.0f);
  float dx = v.x - mu, dy = v.y - mu, dz = v.z - mu, dw = v.w - mu;
  float q = dx * dx + dy * dy + dz * dz + dw * dw;
  #pragma unroll
  for (int off = 32; off; off >>= 1) q += __shfl_down(q, off);
  q = __shfl(q, 0);
  float rstd = rsqrtf(q * (1.0f / 256.0f) + 1e-5f);
  const float4 gg = ((const float4*)g)[lane];
  const float4 be = ((const float4*)bb)[lane];
  ushort4 o;
  o.x = f2b(dx * rstd * gg.x + be.x);
  o.y = f2b(dy * rstd * gg.y + be.y);
  o.z = f2b(dz * rstd * gg.z + be.z);
  o.w = f2b(dw * rstd * gg.w + be.w);
  ((ushort4*)(y + (size_t)row * D))[lane] = o;
}

// ---------------- bf16 MFMA GEMM with global_load_lds staging ----------------
// C[M,N] = A[M,K] @ WT[N,K]^T ; tile BM x 128, BK=32, linear LDS [rows][32]
// EPI 0: QKV split (q,k natural bf16; v transposed [bh*64+d][T])
// EPI 1: + bias + res -> fp32
// EPI 2: + bias + gelu -> bf16
template<int EPI, int BM>
__global__ __launch_bounds__(256) void gemm_bf16(
    const ushort* __restrict__ A, const ushort* __restrict__ BTm,
    const float* __restrict__ bias, const float* __restrict__ res,
    float* __restrict__ outF, ushort* __restrict__ outB,
    ushort* __restrict__ qo, ushort* __restrict__ ko, ushort* __restrict__ vT,
    int N, int K) {
  constexpr int MFR = BM / 32;   // m-frags per wave
  __shared__ __align__(16) ushort Al[BM * 32];
  __shared__ __align__(16) ushort Bl[128 * 32];
  int tid = threadIdx.x;
  int wave = tid >> 6, lane = tid & 63;
  int wr = wave >> 1, wc = wave & 1;
  int gi = lane >> 4, li = lane & 15;
  int lrow = lane >> 2, lkb = (lane & 3) * 8;
  int row0 = blockIdx.y * BM, col0 = blockIdx.x * 128;
  f32x4 acc[MFR][4] = {};
  for (int k0 = 0; k0 < K; k0 += 32) {
    #pragma unroll
    for (int i = 0; i < BM / 64; i++) {
      int chunk = wave * (BM / 64) + i;
      int row = chunk * 16 + lrow;
      gload16(&A[(size_t)(row0 + row) * K + k0 + lkb], &Al[chunk * 512]);
    }
    #pragma unroll
    for (int i = 0; i < 2; i++) {
      int chunk = wave * 2 + i;
      int row = chunk * 16 + lrow;
      gload16(&BTm[(size_t)(col0 + row) * K + k0 + lkb], &Bl[chunk * 512]);
    }
    __syncthreads();
    short8 a[MFR], b[4];
    #pragma unroll
    for (int m = 0; m < MFR; m++)
      a[m] = *(const short8*)&Al[(wr * (MFR * 16) + m * 16 + li) * 32 + gi * 8];
    #pragma unroll
    for (int n = 0; n < 4; n++)
      b[n] = *(const short8*)&Bl[(wc * 64 + n * 16 + li) * 32 + gi * 8];
    #pragma unroll
    for (int m = 0; m < MFR; m++)
      #pragma unroll
      for (int n = 0; n < 4; n++)
        acc[m][n] = __builtin_amdgcn_mfma_f32_16x16x32_bf16(a[m], b[n], acc[m][n], 0, 0, 0);
    __syncthreads();
  }
  #pragma unroll
  for (int m = 0; m < MFR; m++) {
    int rbase = row0 + wr * (MFR * 16) + m * 16 + gi * 4;
    #pragma unroll
    for (int n = 0; n < 4; n++) {
      int col = col0 + wc * 64 + n * 16 + li;
      f32x4 v = acc[m][n];
      if (EPI == 1) {
        float bs = bias[col];
        #pragma unroll
        for (int r = 0; r < 4; r++) {
          size_t off = (size_t)(rbase + r) * N + col;
          outF[off] = v[r] + bs + res[off];
        }
      } else if (EPI == 2) {
        float bs = bias[col];
        #pragma unroll
        for (int r = 0; r < 4; r++) {
          float u = v[r] + bs;
          float gel = 0.5f * u * (1.0f + tanhf(0.7978845608028654f * (u + 0.044715f * u * u * u)));
          outB[(size_t)(rbase + r) * N + col] = f2b(gel);
        }
      } else {
        if (col < 256) {
          #pragma unroll
          for (int r = 0; r < 4; r++) qo[(size_t)(rbase + r) * 256 + col] = f2b(v[r]);
        } else if (col < 512) {
          #pragma unroll
          for (int r = 0; r < 4; r++) ko[(size_t)(rbase + r) * 256 + col - 256] = f2b(v[r]);
        } else {
          int b_ = rbase >> 9, t = rbase & 511;
          int hh = (col - 512) >> 5, d = (col - 512) & 31;
          ushort4 pk;
          pk.x = f2b(v[0]); pk.y = f2b(v[1]); pk.z = f2b(v[2]); pk.w = f2b(v[3]);
          *(ushort4*)&vT[((size_t)((b_ * 8 + hh) * 64 + d)) * 512 + t] = pk;
        }
      }
    }
  }
}

// ---------------- FAVOR+ feature GEMM: rows = bh*T+t, K=32 ----------------
template<int IS_Q>
__global__ __launch_bounds__(256) void favor_gemm(
    const ushort* __restrict__ X, const ushort* __restrict__ projd,
    ushort* __restrict__ outQ, ushort* __restrict__ outKT,
    float* __restrict__ kdiagT, float* __restrict__ krmaxT) {
  __shared__ __align__(16) ushort Al[128 * 32];
  __shared__ __align__(16) ushort Bl[128 * 32];
  __shared__ float diag_s[128];
  int tid = threadIdx.x;
  int wave = tid >> 6, lane = tid & 63;
  int gi = lane >> 4, li = lane & 15;
  int lrow = lane >> 2, lkb = (lane & 3) * 8;
  int row0 = blockIdx.x * 128;   // bh*512 + t
  int bh = row0 >> 9;
  int t0 = row0 & 511;
  int b = bh >> 3, h = bh & 7;
  const ushort* Xb = X + (size_t)(b * 512) * 256 + h * 32;
  #pragma unroll
  for (int i = 0; i < 2; i++) {
    int chunk = wave * 2 + i;
    int row = chunk * 16 + lrow;
    gload16(&Xb[(size_t)(t0 + row) * 256 + lkb], &Al[chunk * 512]);
    gload16(&projd[row * 32 + lkb], &Bl[chunk * 512]);
  }
  __syncthreads();
  short8 a[2];
  f32x4 acc[2][8] = {};
  #pragma unroll
  for (int m = 0; m < 2; m++) {
    a[m] = *(const short8*)&Al[(wave * 32 + m * 16 + li) * 32 + gi * 8];
    float s = 0.f;
    #pragma unroll
    for (int i = 0; i < 8; i++) {
      float xv = bf2f((ushort)a[m][i]);
      s += xv * xv;
    }
    s += __shfl_xor(s, 16);
    s += __shfl_xor(s, 32);
    if (gi == 0) diag_s[wave * 32 + m * 16 + li] = DN2H * s;
  }
  short8 bfr[8];
  #pragma unroll
  for (int n = 0; n < 8; n++)
    bfr[n] = *(const short8*)&Bl[(n * 16 + li) * 32 + gi * 8];
  #pragma unroll
  for (int m = 0; m < 2; m++)
    #pragma unroll
    for (int n = 0; n < 8; n++)
      acc[m][n] = __builtin_amdgcn_mfma_f32_16x16x32_bf16(a[m], bfr[n], acc[m][n], 0, 0, 0);
  __syncthreads();

  #pragma unroll
  for (int m = 0; m < 2; m++) {
    float mx[4], dgv[4];
    #pragma unroll
    for (int r = 0; r < 4; r++) {
      float mv = -1e30f;
      #pragma unroll
      for (int n = 0; n < 8; n++) mv = fmaxf(mv, acc[m][n][r]);
      #pragma unroll
      for (int msk = 1; msk <= 8; msk <<= 1) mv = fmaxf(mv, __shfl_xor(mv, msk));
      mx[r] = mv;
      dgv[r] = diag_s[wave * 32 + m * 16 + gi * 4 + r];
    }
    int tb = t0 + wave * 32 + m * 16 + gi * 4;
    if (IS_Q) {
      #pragma unroll
      for (int n = 0; n < 8; n++)
        #pragma unroll
        for (int r = 0; r < 4; r++)
          outQ[((size_t)bh * 512 + tb + r) * 128 + n * 16 + li] =
              f2b(RATIO * (expf(acc[m][n][r] - dgv[r] - mx[r]) + KEPS));
    } else {
      #pragma unroll
      for (int n = 0; n < 8; n++) {
        ushort4 pk;
        pk.x = f2b(acc[m][n][0]); pk.y = f2b(acc[m][n][1]);
        pk.z = f2b(acc[m][n][2]); pk.w = f2b(acc[m][n][3]);
        *(ushort4*)&outKT[((size_t)bh * 128 + n * 16 + li) * 512 + tb] = pk;
      }
      if (li == 0) {
        #pragma unroll
        for (int r = 0; r < 4; r++) {
          kdiagT[(size_t)bh * 512 + tb + r] = dgv[r];
          krmaxT[(size_t)bh * 512 + tb + r] = mx[r];
        }
      }
    }
  }
}

// ---------------- per-bh max over T ----------------
__global__ void kmax_reduce(const float* __restrict__ krmaxT, float* __restrict__ kmax) {
  int bh = blockIdx.x;
  int tid = threadIdx.x;
  __shared__ float red[256];
  red[tid] = fmaxf(krmaxT[bh * 512 + tid], krmaxT[bh * 512 + 256 + tid]);
  __syncthreads();
  for (int s = 128; s; s >>= 1) {
    if (tid < s) red[tid] = fmaxf(red[tid], red[tid + s]);
    __syncthreads();
  }
  if (tid == 0) kmax[bh] = red[0];
}

// ---------------- kp finish: kp = ratio*(exp(s - diag - kmax)+eps), in place ----------------
__global__ void kp_finish(ushort* __restrict__ kpT, const float* __restrict__ kdiagT,
                          const float* __restrict__ kmax) {
  size_t e = ((size_t)blockIdx.x * 256 + threadIdx.x) * 8;
  int row = (int)(e >> 9);
  int bh = row >> 7;
  int t = (int)(e & 511);
  uint4 raw = *(const uint4*)&kpT[e];
  ushort* rs = (ushort*)&raw;
  float km = kmax[bh];
  const float* kd = kdiagT + (size_t)bh * 512 + t;
  ushort out[8];
  #pragma unroll
  for (int i = 0; i < 8; i++)
    out[i] = f2b(RATIO * (expf(bf2f(rs[i]) - kd[i] - km) + KEPS));
  *(uint4*)&kpT[e] = *(uint4*)out;
}

// ---------------- ctx: kpT[128,512] @ vT64[64,512]^T -> Bmat[48][128] (ksum fused via ones-row) ----------------
__global__ __launch_bounds__(256) void ctx_gemm(const ushort* __restrict__ kpT,
                                                const ushort* __restrict__ vT,
                                                ushort* __restrict__ Bmat) {
  __shared__ __align__(16) ushort Akl[128 * 32];
  __shared__ __align__(16) ushort Bvl[64 * 32];
  int bh = blockIdx.x;
  int tid = threadIdx.x;
  int wave = tid >> 6, lane = tid & 63;
  int gi = lane >> 4, li = lane & 15;
  int lrow = lane >> 2, lkb = (lane & 3) * 8;
  const ushort* Ab = kpT + (size_t)bh * 128 * 512;
  const ushort* Bb = vT + (size_t)bh * 64 * 512;
  f32x4 acc[2][3] = {};
  for (int ks = 0; ks < 16; ks++) {
    int kt = ks * 32;
    #pragma unroll
    for (int i = 0; i < 2; i++) {
      int chunk = wave * 2 + i;
      int row = chunk * 16 + lrow;
      gload16(&Ab[(size_t)row * 512 + kt + lkb], &Akl[chunk * 512]);
    }
    {
      int row = wave * 16 + lrow;
      gload16(&Bb[(size_t)row * 512 + kt + lkb], &Bvl[wave * 512]);
    }
    __syncthreads();
    short8 a[2], bb[3];
    #pragma unroll
    for (int m = 0; m < 2; m++)
      a[m] = *(const short8*)&Akl[(wave * 32 + m * 16 + li) * 32 + gi * 8];
    #pragma unroll
    for (int n = 0; n < 3; n++)
      bb[n] = *(const short8*)&Bvl[(n * 16 + li) * 32 + gi * 8];
    #pragma unroll
    for (int m = 0; m < 2; m++)
      #pragma unroll
      for (int n = 0; n < 3; n++)
        acc[m][n] = __builtin_amdgcn_mfma_f32_16x16x32_bf16(a[m], bb[n], acc[m][n], 0, 0, 0);
    __syncthreads();
  }
  #pragma unroll
  for (int m = 0; m < 2; m++)
    #pragma unroll
    for (int n = 0; n < 3; n++) {
      int dd = n * 16 + li;
      int mg = wave * 32 + m * 16 + gi * 4;
      ushort4 pk;
      pk.x = f2b(acc[m][n][0]); pk.y = f2b(acc[m][n][1]);
      pk.z = f2b(acc[m][n][2]); pk.w = f2b(acc[m][n][3]);
      *(ushort4*)&Bmat[((size_t)bh * 48 + dd) * 128 + mg] = pk;
    }
}

// ---------------- o = qp @ [ctxT;ksum]^T, divide by denom col, write bf16 [bt][256] ----------------
__global__ __launch_bounds__(256) void o_gemm(const ushort* __restrict__ qp,
                                              const ushort* __restrict__ Bmat,
                                              ushort* __restrict__ o) {
  __shared__ __align__(16) ushort Aql[64 * 136];
  __shared__ __align__(16) ushort Bml[48 * 136];
  int bh = blockIdx.y;
  int t0 = blockIdx.x * 64;
  int tid = threadIdx.x;
  int wave = tid >> 6, lane = tid & 63;
  int gi = lane >> 4, li = lane & 15;
  #pragma unroll
  for (int j = 0; j < 4; j++) {
    int c = j * 256 + tid;
    int r = c >> 4, g = c & 15;
    *(uint4*)&Aql[r * 136 + g * 8] = *(const uint4*)&qp[((size_t)bh * 512 + t0 + r) * 128 + g * 8];
  }
  #pragma unroll
  for (int j = 0; j < 3; j++) {
    int c = j * 256 + tid;
    int r = c >> 4, g = c & 15;
    *(uint4*)&Bml[r * 136 + g * 8] = *(const uint4*)&Bmat[((size_t)bh * 48 + r) * 128 + g * 8];
  }
  __syncthreads();
  f32x4 acc[3] = {};
  #pragma unroll
  for (int ks = 0; ks < 4; ks++) {
    short8 a = *(const short8*)&Aql[(wave * 16 + li) * 136 + ks * 32 + gi * 8];
    #pragma unroll
    for (int n = 0; n < 3; n++) {
      short8 bb = *(const short8*)&Bml[(n * 16 + li) * 136 + ks * 32 + gi * 8];
      acc[n] = __builtin_amdgcn_mfma_f32_16x16x32_bf16(a, bb, acc[n], 0, 0, 0);
    }
  }
  int b = bh >> 3, h = bh & 7;
  int t = t0 + wave * 16 + gi * 4;
  float den[4];
  #pragma unroll
  for (int r = 0; r < 4; r++) den[r] = __shfl(acc[2][r], lane & 48);
  #pragma unroll
  for (int n = 0; n < 2; n++)
    #pragma unroll
    for (int r = 0; r < 4; r++)
      o[((size_t)(b * 512) + t + r) * 256 + h * 32 + n * 16 + li] = f2b(acc[n][r] / den[r]);
}

// ---------------- final masks: out (B, NM, T) fp32 ----------------
__global__ void mask_kernel(const float* __restrict__ x, const float* __restrict__ Wm,
                            const float* __restrict__ bm, float* __restrict__ out) {
  int row = blockIdx.x * 4 + (threadIdx.x >> 6);
  int lane = threadIdx.x & 63;
  const float4 v = ((const float4*)(x + (size_t)row * D))[lane];
  int b = row >> 9, t = row & 511;
  #pragma unroll
  for (int msk = 0; msk < NM; msk++) {
    const float* wc = Wm + msk;
    float s = v.x * wc[(lane * 4 + 0) * NM] + v.y * wc[(lane * 4 + 1) * NM] +
              v.z * wc[(lane * 4 + 2) * NM] + v.w * wc[(lane * 4 + 3) * NM];
    #pragma unroll
    for (int off = 32; off; off >>= 1) s += __shfl_down(s, off);
    if (lane == 0) out[((size_t)(b * NM) + msk) * T + t] = s + bm[msk];
  }
}

extern "C" void kernel_launch(void* const* d_in, const int* in_sizes, int n_in,
                              void* d_out, int out_size, void* d_ws, size_t ws_size,
                              hipStream_t stream) {
  const float* mel   = (const float*)d_in[0];
  const float* proj  = (const float*)d_in[1];
  const float* ln1_g = (const float*)d_in[2];
  const float* ln1_b = (const float*)d_in[3];
  const float* Wq    = (const float*)d_in[4];
  const float* Wk    = (const float*)d_in[5];
  const float* Wv    = (const float*)d_in[6];
  const float* Wo    = (const float*)d_in[7];
  const float* bo    = (const float*)d_in[8];
  const float* ln2_g = (const float*)d_in[9];
  const float* ln2_b = (const float*)d_in[10];
  const float* W1    = (const float*)d_in[11];
  const float* b1    = (const float*)d_in[12];
  const float* W2    = (const float*)d_in[13];
  const float* b2    = (const float*)d_in[14];
  const float* Wm    = (const float*)d_in[15];
  const float* bm    = (const float*)d_in[16];

  // ---- workspace layout ----
  float* x      = (float*)d_ws;                        // BT*D
  float* kdiagT = x + (size_t)BT * D;                  // BH*T
  float* krmaxT = kdiagT + (size_t)BH * T;             // BH*T
  float* kmax   = krmaxT + (size_t)BH * T;             // BH
  ushort* us    = (ushort*)(kmax + 256);
  ushort* h     = us;                   us += (size_t)BT * D;
  ushort* qb    = us;                   us += (size_t)BT * D;
  ushort* kb    = us;                   us += (size_t)BT * D;
  ushort* vT    = us;                   us += (size_t)BH * 64 * T;
  ushort* ob    = us;                   us += (size_t)BT * D;
  ushort* qp    = us;                   us += (size_t)BH * T * MF;
  ushort* kpT   = us;                   us += (size_t)BH * T * MF;
  ushort* ffh   = us;                   us += (size_t)BT * FF;
  ushort* Bmat  = us;                   us += (size_t)BH * 48 * MF;
  ushort* qkvT  = us;                   us += (size_t)NLAYER * 768 * 256;
  ushort* woT   = us;                   us += (size_t)NLAYER * 256 * 256;
  ushort* w1T   = us;                   us += (size_t)NLAYER * 1024 * 256;
  ushort* w2T   = us;                   us += (size_t)NLAYER * 256 * 1024;
  ushort* projd = us;                   us += (size_t)MF * DH;

  // ---- prep: transposed bf16 weights + constants ----
  wtrans<<<dim3(8, 8, NLAYER), dim3(32, 8), 0, stream>>>(Wq, qkvT, 256, 256, 65536, 768 * 256);
  wtrans<<<dim3(8, 8, NLAYER), dim3(32, 8), 0, stream>>>(Wk, qkvT + 256 * 256, 256, 256, 65536, 768 * 256);
  wtrans<<<dim3(8, 8, NLAYER), dim3(32, 8), 0, stream>>>(Wv, qkvT + 512 * 256, 256, 256, 65536, 768 * 256);
  wtrans<<<dim3(8, 8, NLAYER), dim3(32, 8), 0, stream>>>(Wo, woT, 256, 256, 65536, 65536);
  wtrans<<<dim3(32, 8, NLAYER), dim3(32, 8), 0, stream>>>(W1, w1T, 256, 1024, 262144, 262144);
  wtrans<<<dim3(8, 32, NLAYER), dim3(32, 8), 0, stream>>>(W2, w2T, 1024, 256, 262144, 262144);
  proj_conv<<<16, 256, 0, stream>>>(proj, projd);
  vinit<<<BH, 256, 0, stream>>>(vT);

  transpose_mel<<<dim3(T / 32, D / 32, B), dim3(32, 8), 0, stream>>>(mel, x);

  for (int l = 0; l < NLAYER; l++) {
    const ushort* qkvTl = qkvT + (size_t)l * 768 * 256;
    ln_kernel<<<BT / 4, 256, 0, stream>>>(x, ln1_g + l * D, ln1_b + l * D, h);
    gemm_bf16<0, 128><<<dim3(6, 128), 256, 0, stream>>>(h, qkvTl, nullptr, nullptr,
        nullptr, nullptr, qb, kb, vT, 768, 256);
    favor_gemm<1><<<1024, 256, 0, stream>>>(qb, projd, qp, nullptr, nullptr, nullptr);
    favor_gemm<0><<<1024, 256, 0, stream>>>(kb, projd, nullptr, kpT, kdiagT, krmaxT);
    kmax_reduce<<<BH, 256, 0, stream>>>(krmaxT, kmax);
    kp_finish<<<(BH * T * MF) / 2048, 256, 0, stream>>>(kpT, kdiagT, kmax);
    ctx_gemm<<<BH, 256, 0, stream>>>(kpT, vT, Bmat);
    o_gemm<<<dim3(8, BH), 256, 0, stream>>>(qp, Bmat, ob);
    gemm_bf16<1, 64><<<dim3(2, 256), 256, 0, stream>>>(ob, woT + (size_t)l * 256 * 256,
        bo + l * D, x, x, nullptr, nullptr, nullptr, nullptr, 256, 256);
    ln_kernel<<<BT / 4, 256, 0, stream>>>(x, ln2_g + l * D, ln2_b + l * D, h);
    gemm_bf16<2, 128><<<dim3(8, 128), 256, 0, stream>>>(h, w1T + (size_t)l * 1024 * 256,
        b1 + (size_t)l * FF, nullptr, nullptr, ffh, nullptr, nullptr, nullptr, 1024, 256);
    gemm_bf16<1, 64><<<dim3(2, 256), 256, 0, stream>>>(ffh, w2T + (size_t)l * 256 * 1024,
        b2 + l * D, x, x, nullptr, nullptr, nullptr, nullptr, 256, 1024);
  }

  mask_kernel<<<BT / 4, 256, 0, stream>>>(x, Wm, bm, (float*)d_out);
}

// Round 5
// 965.039 us; speedup vs baseline: 8.8775x; 1.0882x over previous
//
#include <hip/hip_runtime.h>
#include <math.h>

#define B 32
#define T 512
#define D 256
#define H 8
#define DH 32
#define MF 128
#define NLAYER 6
#define FF 1024
#define NM 4
#define BT (B*T)
#define BH (B*H)

#define DN2H 0.08838834764831845f   /* 0.5 * 32^-0.5 (0.5*dn^2) */
#define DNS  0.4204482076268573f    /* 32^-0.25 */
#define RATIO 0.08838834764831845f  /* 128^-0.5 */
#define KEPS 1e-4f

typedef __attribute__((ext_vector_type(8))) short short8;
typedef __attribute__((ext_vector_type(4))) float f32x4;

__device__ __forceinline__ ushort f2b(float x) {
  union { float f; unsigned u; } c; c.f = x;
  unsigned r = (c.u + 0x7FFFu + ((c.u >> 16) & 1u)) >> 16;
  return (ushort)r;
}
__device__ __forceinline__ float bf2f(ushort u) {
  union { unsigned u; float f; } c; c.u = ((unsigned)u) << 16;
  return c.f;
}
__device__ __forceinline__ void gload16(const ushort* g, ushort* l) {
  __builtin_amdgcn_global_load_lds((const __attribute__((address_space(1))) void*)g,
                                   (__attribute__((address_space(3))) void*)l, 16, 0, 0);
}

// ---------------- transpose mel (B,D,T) -> x (B,T,D) fp32 ----------------
__global__ void transpose_mel(const float* __restrict__ mel, float* __restrict__ x) {
  __shared__ float tile[32][33];
  int b = blockIdx.z;
  int d0 = blockIdx.y * 32, t0 = blockIdx.x * 32;
  int tx = threadIdx.x, ty = threadIdx.y;
  #pragma unroll
  for (int i = 0; i < 32; i += 8)
    tile[ty + i][tx] = mel[(b * D + d0 + ty + i) * T + t0 + tx];
  __syncthreads();
  #pragma unroll
  for (int i = 0; i < 32; i += 8)
    x[(b * T + t0 + ty + i) * D + d0 + tx] = tile[tx][ty + i];
}

// ---------------- weight transpose+convert: W[K][N] fp32 -> WT[N][K] bf16 ----------------
__global__ void wtrans(const float* __restrict__ W, ushort* __restrict__ WT,
                       int K, int N, size_t lin, size_t lout) {
  __shared__ float tile[32][33];
  int l = blockIdx.z;
  const float* Wl = W + (size_t)l * lin;
  ushort* WTl = WT + (size_t)l * lout;
  int k0 = blockIdx.y * 32, n0 = blockIdx.x * 32;
  int tx = threadIdx.x, ty = threadIdx.y;
  #pragma unroll
  for (int i = 0; i < 32; i += 8)
    tile[ty + i][tx] = Wl[(size_t)(k0 + ty + i) * N + n0 + tx];
  __syncthreads();
  #pragma unroll
  for (int i = 0; i < 32; i += 8)
    WTl[(size_t)(n0 + ty + i) * K + k0 + tx] = f2b(tile[tx][ty + i]);
}

// ---------------- proj convert (prescaled by DN) ----------------
__global__ void proj_conv(const float* __restrict__ proj, ushort* __restrict__ projd) {
  int e = blockIdx.x * 256 + threadIdx.x;
  if (e < MF * DH) projd[e] = f2b(proj[e] * DNS);
}

// ---------------- vT constant rows init: row 32 = 1.0, rows 33..63 = 0 ----------------
__global__ void vinit(ushort* __restrict__ vT) {
  int bh = blockIdx.x;
  int tid = threadIdx.x;
  for (int r = 32; r < 64; r++) {
    ushort val = (r == 32) ? (ushort)0x3F80 : (ushort)0;
    for (int e = tid; e < 512; e += 256)
      vT[((size_t)bh * 64 + r) * 512 + e] = val;
  }
}

// ---------------- layernorm: 4 rows per block, bf16 out ----------------
__global__ __launch_bounds__(256) void ln_kernel(const float* __restrict__ x, const float* __restrict__ g,
                          const float* __restrict__ bb, ushort* __restrict__ y) {
  int row = blockIdx.x * 4 + (threadIdx.x >> 6);
  int lane = threadIdx.x & 63;
  const float4 v = ((const float4*)(x + (size_t)row * D))[lane];
  float s = v.x + v.y + v.z + v.w;
  #pragma unroll
  for (int off = 32; off; off >>= 1) s += __shfl_down(s, off);
  s = __shfl(s, 0);
  float mu = s * (1.0f / 256.0f);
  float dx = v.x - mu, dy = v.y - mu, dz = v.z - mu, dw = v.w - mu;
  float q = dx * dx + dy * dy + dz * dz + dw * dw;
  #pragma unroll
  for (int off = 32; off; off >>= 1) q += __shfl_down(q, off);
  q = __shfl(q, 0);
  float rstd = rsqrtf(q * (1.0f / 256.0f) + 1e-5f);
  const float4 gg = ((const float4*)g)[lane];
  const float4 be = ((const float4*)bb)[lane];
  ushort4 o;
  o.x = f2b(dx * rstd * gg.x + be.x);
  o.y = f2b(dy * rstd * gg.y + be.y);
  o.z = f2b(dz * rstd * gg.z + be.z);
  o.w = f2b(dw * rstd * gg.w + be.w);
  ((ushort4*)(y + (size_t)row * D))[lane] = o;
}

// ---------------- bf16 MFMA GEMM with global_load_lds staging ----------------
// C[M,N] = A[M,K] @ WT[N,K]^T ; tile BM x 128, BK=32, linear LDS [rows][32]
// EPI 0: QKV split (q,k natural bf16; v transposed [bh*64+d][T])
// EPI 1: + bias + res -> fp32
// EPI 2: + bias + gelu -> bf16
template<int EPI, int BM>
__global__ __launch_bounds__(256) void gemm_bf16(
    const ushort* __restrict__ A, const ushort* __restrict__ BTm,
    const float* __restrict__ bias, const float* __restrict__ res,
    float* __restrict__ outF, ushort* __restrict__ outB,
    ushort* __restrict__ qo, ushort* __restrict__ ko, ushort* __restrict__ vT,
    int N, int K) {
  constexpr int MFR = BM / 32;   // m-frags per wave
  __shared__ __align__(16) ushort Al[BM * 32];
  __shared__ __align__(16) ushort Bl[128 * 32];
  int tid = threadIdx.x;
  int wave = tid >> 6, lane = tid & 63;
  int wr = wave >> 1, wc = wave & 1;
  int gi = lane >> 4, li = lane & 15;
  int lrow = lane >> 2, lkb = (lane & 3) * 8;
  int row0 = blockIdx.y * BM, col0 = blockIdx.x * 128;
  f32x4 acc[MFR][4] = {};
  for (int k0 = 0; k0 < K; k0 += 32) {
    #pragma unroll
    for (int i = 0; i < BM / 64; i++) {
      int chunk = wave * (BM / 64) + i;
      int row = chunk * 16 + lrow;
      gload16(&A[(size_t)(row0 + row) * K + k0 + lkb], &Al[chunk * 512]);
    }
    #pragma unroll
    for (int i = 0; i < 2; i++) {
      int chunk = wave * 2 + i;
      int row = chunk * 16 + lrow;
      gload16(&BTm[(size_t)(col0 + row) * K + k0 + lkb], &Bl[chunk * 512]);
    }
    __syncthreads();
    short8 a[MFR], b[4];
    #pragma unroll
    for (int m = 0; m < MFR; m++)
      a[m] = *(const short8*)&Al[(wr * (MFR * 16) + m * 16 + li) * 32 + gi * 8];
    #pragma unroll
    for (int n = 0; n < 4; n++)
      b[n] = *(const short8*)&Bl[(wc * 64 + n * 16 + li) * 32 + gi * 8];
    #pragma unroll
    for (int m = 0; m < MFR; m++)
      #pragma unroll
      for (int n = 0; n < 4; n++)
        acc[m][n] = __builtin_amdgcn_mfma_f32_16x16x32_bf16(a[m], b[n], acc[m][n], 0, 0, 0);
    __syncthreads();
  }
  #pragma unroll
  for (int m = 0; m < MFR; m++) {
    int rbase = row0 + wr * (MFR * 16) + m * 16 + gi * 4;
    #pragma unroll
    for (int n = 0; n < 4; n++) {
      int col = col0 + wc * 64 + n * 16 + li;
      f32x4 v = acc[m][n];
      if (EPI == 1) {
        float bs = bias[col];
        #pragma unroll
        for (int r = 0; r < 4; r++) {
          size_t off = (size_t)(rbase + r) * N + col;
          outF[off] = v[r] + bs + res[off];
        }
      } else if (EPI == 2) {
        float bs = bias[col];
        #pragma unroll
        for (int r = 0; r < 4; r++) {
          float u = v[r] + bs;
          float p = u + 0.044715f * u * u * u;
          float gel = u / (1.0f + __expf(-1.5957691216057308f * p));
          outB[(size_t)(rbase + r) * N + col] = f2b(gel);
        }
      } else {
        if (col < 256) {
          #pragma unroll
          for (int r = 0; r < 4; r++) qo[(size_t)(rbase + r) * 256 + col] = f2b(v[r]);
        } else if (col < 512) {
          #pragma unroll
          for (int r = 0; r < 4; r++) ko[(size_t)(rbase + r) * 256 + col - 256] = f2b(v[r]);
        } else {
          int b_ = rbase >> 9, t = rbase & 511;
          int hh = (col - 512) >> 5, d = (col - 512) & 31;
          ushort4 pk;
          pk.x = f2b(v[0]); pk.y = f2b(v[1]); pk.z = f2b(v[2]); pk.w = f2b(v[3]);
          *(ushort4*)&vT[((size_t)((b_ * 8 + hh) * 64 + d)) * 512 + t] = pk;
        }
      }
    }
  }
}

// ---------------- FAVOR+ feature GEMM: rows = bh*T+t, K=32 ----------------
template<int IS_Q>
__global__ __launch_bounds__(256) void favor_gemm(
    const ushort* __restrict__ X, const ushort* __restrict__ projd,
    ushort* __restrict__ outQ, ushort* __restrict__ outKT,
    float* __restrict__ kdiagT, float* __restrict__ krmaxT) {
  __shared__ __align__(16) ushort Al[128 * 32];
  __shared__ __align__(16) ushort Bl[128 * 32];
  __shared__ float diag_s[128];
  int tid = threadIdx.x;
  int wave = tid >> 6, lane = tid & 63;
  int gi = lane >> 4, li = lane & 15;
  int lrow = lane >> 2, lkb = (lane & 3) * 8;
  int row0 = blockIdx.x * 128;   // bh*512 + t
  int bh = row0 >> 9;
  int t0 = row0 & 511;
  int b = bh >> 3, h = bh & 7;
  const ushort* Xb = X + (size_t)(b * 512) * 256 + h * 32;
  #pragma unroll
  for (int i = 0; i < 2; i++) {
    int chunk = wave * 2 + i;
    int row = chunk * 16 + lrow;
    gload16(&Xb[(size_t)(t0 + row) * 256 + lkb], &Al[chunk * 512]);
    gload16(&projd[row * 32 + lkb], &Bl[chunk * 512]);
  }
  __syncthreads();
  short8 a[2];
  f32x4 acc[2][8] = {};
  #pragma unroll
  for (int m = 0; m < 2; m++) {
    a[m] = *(const short8*)&Al[(wave * 32 + m * 16 + li) * 32 + gi * 8];
    float s = 0.f;
    #pragma unroll
    for (int i = 0; i < 8; i++) {
      float xv = bf2f((ushort)a[m][i]);
      s += xv * xv;
    }
    s += __shfl_xor(s, 16);
    s += __shfl_xor(s, 32);
    if (gi == 0) diag_s[wave * 32 + m * 16 + li] = DN2H * s;
  }
  short8 bfr[8];
  #pragma unroll
  for (int n = 0; n < 8; n++)
    bfr[n] = *(const short8*)&Bl[(n * 16 + li) * 32 + gi * 8];
  #pragma unroll
  for (int m = 0; m < 2; m++)
    #pragma unroll
    for (int n = 0; n < 8; n++)
      acc[m][n] = __builtin_amdgcn_mfma_f32_16x16x32_bf16(a[m], bfr[n], acc[m][n], 0, 0, 0);
  __syncthreads();

  #pragma unroll
  for (int m = 0; m < 2; m++) {
    float mx[4], dgv[4];
    #pragma unroll
    for (int r = 0; r < 4; r++) {
      float mv = -1e30f;
      #pragma unroll
      for (int n = 0; n < 8; n++) mv = fmaxf(mv, acc[m][n][r]);
      #pragma unroll
      for (int msk = 1; msk <= 8; msk <<= 1) mv = fmaxf(mv, __shfl_xor(mv, msk));
      mx[r] = mv;
      dgv[r] = diag_s[wave * 32 + m * 16 + gi * 4 + r];
    }
    int tb = t0 + wave * 32 + m * 16 + gi * 4;
    if (IS_Q) {
      #pragma unroll
      for (int n = 0; n < 8; n++)
        #pragma unroll
        for (int r = 0; r < 4; r++)
          outQ[((size_t)bh * 512 + tb + r) * 128 + n * 16 + li] =
              f2b(RATIO * (__expf(acc[m][n][r] - dgv[r] - mx[r]) + KEPS));
    } else {
      #pragma unroll
      for (int n = 0; n < 8; n++) {
        ushort4 pk;
        pk.x = f2b(acc[m][n][0]); pk.y = f2b(acc[m][n][1]);
        pk.z = f2b(acc[m][n][2]); pk.w = f2b(acc[m][n][3]);
        *(ushort4*)&outKT[((size_t)bh * 128 + n * 16 + li) * 512 + tb] = pk;
      }
      if (li == 0) {
        #pragma unroll
        for (int r = 0; r < 4; r++) {
          kdiagT[(size_t)bh * 512 + tb + r] = dgv[r];
          krmaxT[(size_t)bh * 512 + tb + r] = mx[r];
        }
      }
    }
  }
}

// ---------------- per-bh max over T ----------------
__global__ void kmax_reduce(const float* __restrict__ krmaxT, float* __restrict__ kmax) {
  int bh = blockIdx.x;
  int tid = threadIdx.x;
  __shared__ float red[256];
  red[tid] = fmaxf(krmaxT[bh * 512 + tid], krmaxT[bh * 512 + 256 + tid]);
  __syncthreads();
  for (int s = 128; s; s >>= 1) {
    if (tid < s) red[tid] = fmaxf(red[tid], red[tid + s]);
    __syncthreads();
  }
  if (tid == 0) kmax[bh] = red[0];
}

// ---------------- ctx: exp-fused kpT[128,512] @ vT64[64,512]^T -> Bmat[48][128] ----------------
// A-staging is reg-staged: kp = ratio*(exp(s)*fx[t] + eps), fx[t]=exp(-kdiag[t]-kmax)
__global__ __launch_bounds__(256) void ctx_gemm(const ushort* __restrict__ kpT,
                                                const ushort* __restrict__ vT,
                                                const float* __restrict__ kdiagT,
                                                const float* __restrict__ kmax,
                                                ushort* __restrict__ Bmat) {
  __shared__ __align__(16) ushort Akl[128 * 32];
  __shared__ __align__(16) ushort Bvl[64 * 32];
  __shared__ float fx_s[512];
  int bh = blockIdx.x;
  int tid = threadIdx.x;
  int wave = tid >> 6, lane = tid & 63;
  int gi = lane >> 4, li = lane & 15;
  int lrow = lane >> 2, lkb = (lane & 3) * 8;
  const ushort* Ab = kpT + (size_t)bh * 128 * 512;
  const ushort* Bb = vT + (size_t)bh * 64 * 512;
  float km = kmax[bh];
  fx_s[tid] = __expf(-kdiagT[(size_t)bh * 512 + tid] - km);
  fx_s[tid + 256] = __expf(-kdiagT[(size_t)bh * 512 + tid + 256] - km);
  __syncthreads();
  f32x4 acc[2][3] = {};
  for (int ks = 0; ks < 16; ks++) {
    int kt = ks * 32;
    #pragma unroll
    for (int i = 0; i < 2; i++) {
      int chunk = wave * 2 + i;
      int row = chunk * 16 + lrow;
      uint4 raw = *(const uint4*)&Ab[(size_t)row * 512 + kt + lkb];
      ushort* rs = (ushort*)&raw;
      const float* fx = &fx_s[kt + lkb];
      ushort o8[8];
      #pragma unroll
      for (int j = 0; j < 8; j++)
        o8[j] = f2b(RATIO * (__expf(bf2f(rs[j])) * fx[j] + KEPS));
      *(uint4*)&Akl[chunk * 512 + lrow * 32 + lkb] = *(uint4*)o8;
    }
    {
      int row = wave * 16 + lrow;
      gload16(&Bb[(size_t)row * 512 + kt + lkb], &Bvl[wave * 512]);
    }
    __syncthreads();
    short8 a[2], bb[3];
    #pragma unroll
    for (int m = 0; m < 2; m++)
      a[m] = *(const short8*)&Akl[(wave * 32 + m * 16 + li) * 32 + gi * 8];
    #pragma unroll
    for (int n = 0; n < 3; n++)
      bb[n] = *(const short8*)&Bvl[(n * 16 + li) * 32 + gi * 8];
    #pragma unroll
    for (int m = 0; m < 2; m++)
      #pragma unroll
      for (int n = 0; n < 3; n++)
        acc[m][n] = __builtin_amdgcn_mfma_f32_16x16x32_bf16(a[m], bb[n], acc[m][n], 0, 0, 0);
    __syncthreads();
  }
  #pragma unroll
  for (int m = 0; m < 2; m++)
    #pragma unroll
    for (int n = 0; n < 3; n++) {
      int dd = n * 16 + li;
      int mg = wave * 32 + m * 16 + gi * 4;
      ushort4 pk;
      pk.x = f2b(acc[m][n][0]); pk.y = f2b(acc[m][n][1]);
      pk.z = f2b(acc[m][n][2]); pk.w = f2b(acc[m][n][3]);
      *(ushort4*)&Bmat[((size_t)bh * 48 + dd) * 128 + mg] = pk;
    }
}

// ---------------- o = qp @ [ctxT;ksum]^T, divide by denom col, write bf16 [bt][256] ----------------
__global__ __launch_bounds__(256) void o_gemm(const ushort* __restrict__ qp,
                                              const ushort* __restrict__ Bmat,
                                              ushort* __restrict__ o) {
  __shared__ __align__(16) ushort Aql[64 * 136];
  __shared__ __align__(16) ushort Bml[48 * 136];
  int bh = blockIdx.y;
  int t0 = blockIdx.x * 64;
  int tid = threadIdx.x;
  int wave = tid >> 6, lane = tid & 63;
  int gi = lane >> 4, li = lane & 15;
  #pragma unroll
  for (int j = 0; j < 4; j++) {
    int c = j * 256 + tid;
    int r = c >> 4, g = c & 15;
    *(uint4*)&Aql[r * 136 + g * 8] = *(const uint4*)&qp[((size_t)bh * 512 + t0 + r) * 128 + g * 8];
  }
  #pragma unroll
  for (int j = 0; j < 3; j++) {
    int c = j * 256 + tid;
    int r = c >> 4, g = c & 15;
    *(uint4*)&Bml[r * 136 + g * 8] = *(const uint4*)&Bmat[((size_t)bh * 48 + r) * 128 + g * 8];
  }
  __syncthreads();
  f32x4 acc[3] = {};
  #pragma unroll
  for (int ks = 0; ks < 4; ks++) {
    short8 a = *(const short8*)&Aql[(wave * 16 + li) * 136 + ks * 32 + gi * 8];
    #pragma unroll
    for (int n = 0; n < 3; n++) {
      short8 bb = *(const short8*)&Bml[(n * 16 + li) * 136 + ks * 32 + gi * 8];
      acc[n] = __builtin_amdgcn_mfma_f32_16x16x32_bf16(a, bb, acc[n], 0, 0, 0);
    }
  }
  int b = bh >> 3, h = bh & 7;
  int t = t0 + wave * 16 + gi * 4;
  float den[4];
  #pragma unroll
  for (int r = 0; r < 4; r++) den[r] = __shfl(acc[2][r], lane & 48);
  #pragma unroll
  for (int n = 0; n < 2; n++)
    #pragma unroll
    for (int r = 0; r < 4; r++)
      o[((size_t)(b * 512) + t + r) * 256 + h * 32 + n * 16 + li] = f2b(acc[n][r] / den[r]);
}

// ---------------- final masks: out (B, NM, T) fp32 ----------------
__global__ void mask_kernel(const float* __restrict__ x, const float* __restrict__ Wm,
                            const float* __restrict__ bm, float* __restrict__ out) {
  int row = blockIdx.x * 4 + (threadIdx.x >> 6);
  int lane = threadIdx.x & 63;
  const float4 v = ((const float4*)(x + (size_t)row * D))[lane];
  int b = row >> 9, t = row & 511;
  #pragma unroll
  for (int msk = 0; msk < NM; msk++) {
    const float* wc = Wm + msk;
    float s = v.x * wc[(lane * 4 + 0) * NM] + v.y * wc[(lane * 4 + 1) * NM] +
              v.z * wc[(lane * 4 + 2) * NM] + v.w * wc[(lane * 4 + 3) * NM];
    #pragma unroll
    for (int off = 32; off; off >>= 1) s += __shfl_down(s, off);
    if (lane == 0) out[((size_t)(b * NM) + msk) * T + t] = s + bm[msk];
  }
}

extern "C" void kernel_launch(void* const* d_in, const int* in_sizes, int n_in,
                              void* d_out, int out_size, void* d_ws, size_t ws_size,
                              hipStream_t stream) {
  const float* mel   = (const float*)d_in[0];
  const float* proj  = (const float*)d_in[1];
  const float* ln1_g = (const float*)d_in[2];
  const float* ln1_b = (const float*)d_in[3];
  const float* Wq    = (const float*)d_in[4];
  const float* Wk    = (const float*)d_in[5];
  const float* Wv    = (const float*)d_in[6];
  const float* Wo    = (const float*)d_in[7];
  const float* bo    = (const float*)d_in[8];
  const float* ln2_g = (const float*)d_in[9];
  const float* ln2_b = (const float*)d_in[10];
  const float* W1    = (const float*)d_in[11];
  const float* b1    = (const float*)d_in[12];
  const float* W2    = (const float*)d_in[13];
  const float* b2    = (const float*)d_in[14];
  const float* Wm    = (const float*)d_in[15];
  const float* bm    = (const float*)d_in[16];

  // ---- workspace layout ----
  float* x      = (float*)d_ws;                        // BT*D
  float* kdiagT = x + (size_t)BT * D;                  // BH*T
  float* krmaxT = kdiagT + (size_t)BH * T;             // BH*T
  float* kmax   = krmaxT + (size_t)BH * T;             // BH
  ushort* us    = (ushort*)(kmax + 256);
  ushort* h     = us;                   us += (size_t)BT * D;
  ushort* qb    = us;                   us += (size_t)BT * D;
  ushort* kb    = us;                   us += (size_t)BT * D;
  ushort* vT    = us;                   us += (size_t)BH * 64 * T;
  ushort* ob    = us;                   us += (size_t)BT * D;
  ushort* qp    = us;                   us += (size_t)BH * T * MF;
  ushort* kpT   = us;                   us += (size_t)BH * T * MF;
  ushort* ffh   = us;                   us += (size_t)BT * FF;
  ushort* Bmat  = us;                   us += (size_t)BH * 48 * MF;
  ushort* qkvT  = us;                   us += (size_t)NLAYER * 768 * 256;
  ushort* woT   = us;                   us += (size_t)NLAYER * 256 * 256;
  ushort* w1T   = us;                   us += (size_t)NLAYER * 1024 * 256;
  ushort* w2T   = us;                   us += (size_t)NLAYER * 256 * 1024;
  ushort* projd = us;                   us += (size_t)MF * DH;

  // ---- prep: transposed bf16 weights + constants ----
  wtrans<<<dim3(8, 8, NLAYER), dim3(32, 8), 0, stream>>>(Wq, qkvT, 256, 256, 65536, 768 * 256);
  wtrans<<<dim3(8, 8, NLAYER), dim3(32, 8), 0, stream>>>(Wk, qkvT + 256 * 256, 256, 256, 65536, 768 * 256);
  wtrans<<<dim3(8, 8, NLAYER), dim3(32, 8), 0, stream>>>(Wv, qkvT + 512 * 256, 256, 256, 65536, 768 * 256);
  wtrans<<<dim3(8, 8, NLAYER), dim3(32, 8), 0, stream>>>(Wo, woT, 256, 256, 65536, 65536);
  wtrans<<<dim3(32, 8, NLAYER), dim3(32, 8), 0, stream>>>(W1, w1T, 256, 1024, 262144, 262144);
  wtrans<<<dim3(8, 32, NLAYER), dim3(32, 8), 0, stream>>>(W2, w2T, 1024, 256, 262144, 262144);
  proj_conv<<<16, 256, 0, stream>>>(proj, projd);
  vinit<<<BH, 256, 0, stream>>>(vT);

  transpose_mel<<<dim3(T / 32, D / 32, B), dim3(32, 8), 0, stream>>>(mel, x);

  for (int l = 0; l < NLAYER; l++) {
    const ushort* qkvTl = qkvT + (size_t)l * 768 * 256;
    ln_kernel<<<BT / 4, 256, 0, stream>>>(x, ln1_g + l * D, ln1_b + l * D, h);
    gemm_bf16<0, 128><<<dim3(6, 128), 256, 0, stream>>>(h, qkvTl, nullptr, nullptr,
        nullptr, nullptr, qb, kb, vT, 768, 256);
    favor_gemm<1><<<1024, 256, 0, stream>>>(qb, projd, qp, nullptr, nullptr, nullptr);
    favor_gemm<0><<<1024, 256, 0, stream>>>(kb, projd, nullptr, kpT, kdiagT, krmaxT);
    kmax_reduce<<<BH, 256, 0, stream>>>(krmaxT, kmax);
    ctx_gemm<<<BH, 256, 0, stream>>>(kpT, vT, kdiagT, kmax, Bmat);
    o_gemm<<<dim3(8, BH), 256, 0, stream>>>(qp, Bmat, ob);
    gemm_bf16<1, 64><<<dim3(2, 256), 256, 0, stream>>>(ob, woT + (size_t)l * 256 * 256,
        bo + l * D, x, x, nullptr, nullptr, nullptr, nullptr, 256, 256);
    ln_kernel<<<BT / 4, 256, 0, stream>>>(x, ln2_g + l * D, ln2_b + l * D, h);
    gemm_bf16<2, 128><<<dim3(8, 128), 256, 0, stream>>>(h, w1T + (size_t)l * 1024 * 256,
        b1 + (size_t)l * FF, nullptr, nullptr, ffh, nullptr, nullptr, nullptr, 1024, 256);
    gemm_bf16<1, 64><<<dim3(2, 256), 256, 0, stream>>>(ffh, w2T + (size_t)l * 256 * 1024,
        b2 + l * D, x, x, nullptr, nullptr, nullptr, nullptr, 256, 1024);
  }

  mask_kernel<<<BT / 4, 256, 0, stream>>>(x, Wm, bm, (float*)d_out);
}

// Round 6
// 946.411 us; speedup vs baseline: 9.0522x; 1.0197x over previous
//
#include <hip/hip_runtime.h>
#include <math.h>

#define B 32
#define T 512
#define D 256
#define H 8
#define DH 32
#define MF 128
#define NLAYER 6
#define FF 1024
#define NM 4
#define BT (B*T)
#define BH (B*H)

#define DN2H 0.08838834764831845f   /* 0.5 * 32^-0.5 (0.5*dn^2) */
#define DNS  0.4204482076268573f    /* 32^-0.25 */
#define RATIO 0.08838834764831845f  /* 128^-0.5 */
#define KEPS 1e-4f

typedef __attribute__((ext_vector_type(8))) short short8;
typedef __attribute__((ext_vector_type(4))) float f32x4;

#define MFMA(a, b, c) __builtin_amdgcn_mfma_f32_16x16x32_bf16(a, b, c, 0, 0, 0)

__device__ __forceinline__ ushort f2b(float x) {
  union { float f; unsigned u; } c; c.f = x;
  unsigned r = (c.u + 0x7FFFu + ((c.u >> 16) & 1u)) >> 16;
  return (ushort)r;
}
__device__ __forceinline__ float bf2f(ushort u) {
  union { unsigned u; float f; } c; c.u = ((unsigned)u) << 16;
  return c.f;
}
__device__ __forceinline__ void gload16(const ushort* g, ushort* l) {
  __builtin_amdgcn_global_load_lds((const __attribute__((address_space(1))) void*)g,
                                   (__attribute__((address_space(3))) void*)l, 16, 0, 0);
}

// ---------------- transpose mel (B,D,T) -> x (B,T,D) fp32 ----------------
__global__ void transpose_mel(const float* __restrict__ mel, float* __restrict__ x) {
  __shared__ float tile[32][33];
  int b = blockIdx.z;
  int d0 = blockIdx.y * 32, t0 = blockIdx.x * 32;
  int tx = threadIdx.x, ty = threadIdx.y;
  #pragma unroll
  for (int i = 0; i < 32; i += 8)
    tile[ty + i][tx] = mel[(b * D + d0 + ty + i) * T + t0 + tx];
  __syncthreads();
  #pragma unroll
  for (int i = 0; i < 32; i += 8)
    x[(b * T + t0 + ty + i) * D + d0 + tx] = tile[tx][ty + i];
}

// ---------------- weight transpose+convert: W[K][N] fp32 -> WT[N][K] bf16 ----------------
__global__ void wtrans(const float* __restrict__ W, ushort* __restrict__ WT,
                       int K, int N, size_t lin, size_t lout) {
  __shared__ float tile[32][33];
  int l = blockIdx.z;
  const float* Wl = W + (size_t)l * lin;
  ushort* WTl = WT + (size_t)l * lout;
  int k0 = blockIdx.y * 32, n0 = blockIdx.x * 32;
  int tx = threadIdx.x, ty = threadIdx.y;
  #pragma unroll
  for (int i = 0; i < 32; i += 8)
    tile[ty + i][tx] = Wl[(size_t)(k0 + ty + i) * N + n0 + tx];
  __syncthreads();
  #pragma unroll
  for (int i = 0; i < 32; i += 8)
    WTl[(size_t)(n0 + ty + i) * K + k0 + tx] = f2b(tile[tx][ty + i]);
}

// ---------------- proj convert (prescaled by DN) ----------------
__global__ void proj_conv(const float* __restrict__ proj, ushort* __restrict__ projd) {
  int e = blockIdx.x * 256 + threadIdx.x;
  if (e < MF * DH) projd[e] = f2b(proj[e] * DNS);
}

// ---------------- layernorm (layer-0 entry only) ----------------
__global__ __launch_bounds__(256) void ln_kernel(const float* __restrict__ x, const float* __restrict__ g,
                          const float* __restrict__ bb, ushort* __restrict__ y) {
  int row = blockIdx.x * 4 + (threadIdx.x >> 6);
  int lane = threadIdx.x & 63;
  const float4 v = ((const float4*)(x + (size_t)row * D))[lane];
  float s = v.x + v.y + v.z + v.w;
  #pragma unroll
  for (int off = 32; off; off >>= 1) s += __shfl_down(s, off);
  s = __shfl(s, 0);
  float mu = s * (1.0f / 256.0f);
  float dx = v.x - mu, dy = v.y - mu, dz = v.z - mu, dw = v.w - mu;
  float q = dx * dx + dy * dy + dz * dz + dw * dw;
  #pragma unroll
  for (int off = 32; off; off >>= 1) q += __shfl_down(q, off);
  q = __shfl(q, 0);
  float rstd = rsqrtf(q * (1.0f / 256.0f) + 1e-5f);
  const float4 gg = ((const float4*)g)[lane];
  const float4 be = ((const float4*)bb)[lane];
  ushort4 o;
  o.x = f2b(dx * rstd * gg.x + be.x);
  o.y = f2b(dy * rstd * gg.y + be.y);
  o.z = f2b(dz * rstd * gg.z + be.z);
  o.w = f2b(dw * rstd * gg.w + be.w);
  ((ushort4*)(y + (size_t)row * D))[lane] = o;
}

// ---------------- bf16 MFMA GEMM with global_load_lds staging ----------------
// EPI 0: QKV split (q,k natural bf16; v transposed [bh*32+d][T])
// EPI 2: + bias + fast-gelu -> bf16
template<int EPI, int BM>
__global__ __launch_bounds__(256) void gemm_bf16(
    const ushort* __restrict__ A, const ushort* __restrict__ BTm,
    const float* __restrict__ bias,
    ushort* __restrict__ outB,
    ushort* __restrict__ qo, ushort* __restrict__ ko, ushort* __restrict__ vT,
    int N, int K) {
  constexpr int MFR = BM / 32;
  __shared__ __align__(16) ushort Al[BM * 32];
  __shared__ __align__(16) ushort Bl[128 * 32];
  int tid = threadIdx.x;
  int wave = tid >> 6, lane = tid & 63;
  int wr = wave >> 1, wc = wave & 1;
  int gi = lane >> 4, li = lane & 15;
  int lrow = lane >> 2, lkb = (lane & 3) * 8;
  int row0 = blockIdx.y * BM, col0 = blockIdx.x * 128;
  f32x4 acc[MFR][4] = {};
  for (int k0 = 0; k0 < K; k0 += 32) {
    #pragma unroll
    for (int i = 0; i < BM / 64; i++) {
      int chunk = wave * (BM / 64) + i;
      int row = chunk * 16 + lrow;
      gload16(&A[(size_t)(row0 + row) * K + k0 + lkb], &Al[chunk * 512]);
    }
    #pragma unroll
    for (int i = 0; i < 2; i++) {
      int chunk = wave * 2 + i;
      int row = chunk * 16 + lrow;
      gload16(&BTm[(size_t)(col0 + row) * K + k0 + lkb], &Bl[chunk * 512]);
    }
    __syncthreads();
    short8 a[MFR], b[4];
    #pragma unroll
    for (int m = 0; m < MFR; m++)
      a[m] = *(const short8*)&Al[(wr * (MFR * 16) + m * 16 + li) * 32 + gi * 8];
    #pragma unroll
    for (int n = 0; n < 4; n++)
      b[n] = *(const short8*)&Bl[(wc * 64 + n * 16 + li) * 32 + gi * 8];
    #pragma unroll
    for (int m = 0; m < MFR; m++)
      #pragma unroll
      for (int n = 0; n < 4; n++)
        acc[m][n] = MFMA(a[m], b[n], acc[m][n]);
    __syncthreads();
  }
  #pragma unroll
  for (int m = 0; m < MFR; m++) {
    int rbase = row0 + wr * (MFR * 16) + m * 16 + gi * 4;
    #pragma unroll
    for (int n = 0; n < 4; n++) {
      int col = col0 + wc * 64 + n * 16 + li;
      f32x4 v = acc[m][n];
      if (EPI == 2) {
        float bs = bias[col];
        #pragma unroll
        for (int r = 0; r < 4; r++) {
          float u = v[r] + bs;
          float p = u + 0.044715f * u * u * u;
          float gel = u / (1.0f + __expf(-1.5957691216057308f * p));
          outB[(size_t)(rbase + r) * N + col] = f2b(gel);
        }
      } else {
        if (col < 256) {
          #pragma unroll
          for (int r = 0; r < 4; r++) qo[(size_t)(rbase + r) * 256 + col] = f2b(v[r]);
        } else if (col < 512) {
          #pragma unroll
          for (int r = 0; r < 4; r++) ko[(size_t)(rbase + r) * 256 + col - 256] = f2b(v[r]);
        } else {
          int b_ = rbase >> 9, t = rbase & 511;
          int hh = (col - 512) >> 5, d = (col - 512) & 31;
          ushort4 pk;
          pk.x = f2b(v[0]); pk.y = f2b(v[1]); pk.z = f2b(v[2]); pk.w = f2b(v[3]);
          *(ushort4*)&vT[((size_t)((b_ * 8 + hh) * 32 + d)) * 512 + t] = pk;
        }
      }
    }
  }
}

// ---------------- fused k-features + ctx per (b,h) ----------------
// pass1: S = proj@k^T (MFMA), global max; pass2: recompute S, exp, ctx MFMA + ksum.
// Writes Bmat[48][128]: rows 0..31 ctx^T, 32 ksum, 33..47 zero.
__global__ __launch_bounds__(256) void ctx_fused(
    const ushort* __restrict__ kb, const ushort* __restrict__ projd,
    const ushort* __restrict__ vT, ushort* __restrict__ Bmat) {
  __shared__ __align__(16) ushort Kl[512 * 32];
  __shared__ __align__(16) ushort Pl[128 * 32];
  __shared__ __align__(16) ushort Sl[2][128 * 40];
  __shared__ __align__(16) ushort Bvl[2][32 * 32];
  __shared__ float dg_s[512];
  __shared__ float red_s[256];
  int bh = blockIdx.x;
  int b = bh >> 3, h = bh & 7;
  int tid = threadIdx.x, wave = tid >> 6, lane = tid & 63;
  int gi = lane >> 4, li = lane & 15;
  int lrow = lane >> 2, lkb = (lane & 3) * 8;
  const ushort* Kg = kb + (size_t)(b * 512) * 256 + h * 32;
  const ushort* Vg = vT + (size_t)bh * 32 * 512;
  #pragma unroll
  for (int i = 0; i < 8; i++) {
    int chunk = wave * 8 + i;
    gload16(&Kg[(size_t)(chunk * 16 + lrow) * 256 + lkb], &Kl[chunk * 512]);
  }
  #pragma unroll
  for (int i = 0; i < 2; i++) {
    int chunk = wave * 2 + i;
    gload16(&projd[(chunk * 16 + lrow) * 32 + lkb], &Pl[chunk * 512]);
  }
  __syncthreads();
  #pragma unroll
  for (int i = 0; i < 2; i++) {
    int t = tid * 2 + i;
    const ushort* kr = &Kl[t * 32];
    float s = 0.f;
    #pragma unroll
    for (int j = 0; j < 32; j++) { float v = bf2f(kr[j]); s += v * v; }
    dg_s[t] = DN2H * s;
  }
  short8 bp0 = *(const short8*)&Pl[(wave * 32 + li) * 32 + gi * 8];
  short8 bp1 = *(const short8*)&Pl[(wave * 32 + 16 + li) * 32 + gi * 8];
  // ---- pass 1: global max of raw scores ----
  float smax = -1e30f;
  for (int c = 0; c < 16; c++) {
    int t0c = c * 32;
    short8 a0 = *(const short8*)&Kl[(t0c + li) * 32 + gi * 8];
    short8 a1 = *(const short8*)&Kl[(t0c + 16 + li) * 32 + gi * 8];
    f32x4 s00 = {}, s01 = {}, s10 = {}, s11 = {};
    s00 = MFMA(a0, bp0, s00); s01 = MFMA(a0, bp1, s01);
    s10 = MFMA(a1, bp0, s10); s11 = MFMA(a1, bp1, s11);
    #pragma unroll
    for (int r = 0; r < 4; r++)
      smax = fmaxf(smax, fmaxf(fmaxf(s00[r], s01[r]), fmaxf(s10[r], s11[r])));
  }
  red_s[tid] = smax;
  __syncthreads();
  for (int s = 128; s; s >>= 1) {
    if (tid < s) red_s[tid] = fmaxf(red_s[tid], red_s[tid + s]);
    __syncthreads();
  }
  float km = red_s[0];
  // ---- pass 2: exp + ctx ----
  f32x4 cacc[2][2] = {};
  float ks0 = 0.f, ks1 = 0.f;
  int cur = 0;
  for (int c = 0; c < 16; c++, cur ^= 1) {
    int t0c = c * 32;
    if (wave < 2)
      gload16(&Vg[(size_t)(wave * 16 + lrow) * 512 + t0c + lkb], &Bvl[cur][wave * 512]);
    short8 a0 = *(const short8*)&Kl[(t0c + li) * 32 + gi * 8];
    short8 a1 = *(const short8*)&Kl[(t0c + 16 + li) * 32 + gi * 8];
    f32x4 s00 = {}, s01 = {}, s10 = {}, s11 = {};
    s00 = MFMA(a0, bp0, s00); s01 = MFMA(a0, bp1, s01);
    s10 = MFMA(a1, bp0, s10); s11 = MFMA(a1, bp1, s11);
    ushort4 w00, w01, w10, w11;
    #pragma unroll
    for (int r = 0; r < 4; r++) {
      float d0 = dg_s[t0c + gi * 4 + r];
      float d1 = dg_s[t0c + 16 + gi * 4 + r];
      float k00 = RATIO * (__expf(s00[r] - d0 - km) + KEPS);
      float k01 = RATIO * (__expf(s01[r] - d0 - km) + KEPS);
      float k10 = RATIO * (__expf(s10[r] - d1 - km) + KEPS);
      float k11 = RATIO * (__expf(s11[r] - d1 - km) + KEPS);
      ks0 += k00 + k10; ks1 += k01 + k11;
      ((ushort*)&w00)[r] = f2b(k00); ((ushort*)&w01)[r] = f2b(k01);
      ((ushort*)&w10)[r] = f2b(k10); ((ushort*)&w11)[r] = f2b(k11);
    }
    *(ushort4*)&Sl[cur][(wave * 32 + li) * 40 + gi * 4]           = w00;
    *(ushort4*)&Sl[cur][(wave * 32 + 16 + li) * 40 + gi * 4]      = w01;
    *(ushort4*)&Sl[cur][(wave * 32 + li) * 40 + 16 + gi * 4]      = w10;
    *(ushort4*)&Sl[cur][(wave * 32 + 16 + li) * 40 + 16 + gi * 4] = w11;
    __syncthreads();
    short8 ca0 = *(const short8*)&Sl[cur][(wave * 32 + li) * 40 + gi * 8];
    short8 ca1 = *(const short8*)&Sl[cur][(wave * 32 + 16 + li) * 40 + gi * 8];
    short8 cb0 = *(const short8*)&Bvl[cur][li * 32 + gi * 8];
    short8 cb1 = *(const short8*)&Bvl[cur][(16 + li) * 32 + gi * 8];
    cacc[0][0] = MFMA(ca0, cb0, cacc[0][0]);
    cacc[0][1] = MFMA(ca0, cb1, cacc[0][1]);
    cacc[1][0] = MFMA(ca1, cb0, cacc[1][0]);
    cacc[1][1] = MFMA(ca1, cb1, cacc[1][1]);
  }
  ks0 += __shfl_xor(ks0, 16); ks0 += __shfl_xor(ks0, 32);
  ks1 += __shfl_xor(ks1, 16); ks1 += __shfl_xor(ks1, 32);
  if (gi == 0) {
    Bmat[((size_t)bh * 48 + 32) * 128 + wave * 32 + li] = f2b(ks0);
    Bmat[((size_t)bh * 48 + 32) * 128 + wave * 32 + 16 + li] = f2b(ks1);
  }
  #pragma unroll
  for (int m = 0; m < 2; m++)
    #pragma unroll
    for (int n = 0; n < 2; n++) {
      int dd = n * 16 + li;
      int mg = wave * 32 + m * 16 + gi * 4;
      ushort4 pk;
      pk.x = f2b(cacc[m][n][0]); pk.y = f2b(cacc[m][n][1]);
      pk.z = f2b(cacc[m][n][2]); pk.w = f2b(cacc[m][n][3]);
      *(ushort4*)&Bmat[((size_t)bh * 48 + dd) * 128 + mg] = pk;
    }
  for (int e = tid; e < 15 * 128; e += 256)
    Bmat[((size_t)bh * 48 + 33) * 128 + e] = 0;
}

// ---------------- fused q-features + o per (64 t, bh) ----------------
__global__ __launch_bounds__(256) void favq_o(
    const ushort* __restrict__ qb, const ushort* __restrict__ projd,
    const ushort* __restrict__ Bmat, ushort* __restrict__ ob) {
  __shared__ __align__(16) ushort Ql[64 * 32];
  __shared__ __align__(16) ushort Pl[128 * 32];
  __shared__ __align__(16) ushort Sl[64 * 136];
  __shared__ __align__(16) ushort Bml[48 * 136];
  __shared__ float dgq[64];
  int bh = blockIdx.y;
  int t0 = blockIdx.x * 64;
  int b = bh >> 3, h = bh & 7;
  int tid = threadIdx.x, wave = tid >> 6, lane = tid & 63;
  int gi = lane >> 4, li = lane & 15;
  int lrow = lane >> 2, lkb = (lane & 3) * 8;
  const ushort* Qg = qb + (size_t)(b * 512) * 256 + h * 32;
  gload16(&Qg[(size_t)(t0 + wave * 16 + lrow) * 256 + lkb], &Ql[wave * 512]);
  #pragma unroll
  for (int i = 0; i < 2; i++) {
    int chunk = wave * 2 + i;
    gload16(&projd[(chunk * 16 + lrow) * 32 + lkb], &Pl[chunk * 512]);
  }
  #pragma unroll
  for (int j = 0; j < 3; j++) {
    int c = j * 256 + tid;
    int r = c >> 4, g = c & 15;
    *(uint4*)&Bml[r * 136 + g * 8] = *(const uint4*)&Bmat[(size_t)bh * 48 * 128 + r * 128 + g * 8];
  }
  __syncthreads();
  if (tid < 64) {
    const ushort* qr = &Ql[tid * 32];
    float s = 0.f;
    #pragma unroll
    for (int j = 0; j < 32; j++) { float v = bf2f(qr[j]); s += v * v; }
    dgq[tid] = DN2H * s;
  }
  short8 bq = *(const short8*)&Ql[(wave * 16 + li) * 32 + gi * 8];
  f32x4 sacc[8] = {};
  #pragma unroll
  for (int m = 0; m < 8; m++) {
    short8 a = *(const short8*)&Pl[(m * 16 + li) * 32 + gi * 8];
    sacc[m] = MFMA(a, bq, sacc[m]);
  }
  __syncthreads();   // dgq visible
  float mx = -1e30f;
  #pragma unroll
  for (int m = 0; m < 8; m++)
    #pragma unroll
    for (int r = 0; r < 4; r++) mx = fmaxf(mx, sacc[m][r]);
  mx = fmaxf(mx, __shfl_xor(mx, 16));
  mx = fmaxf(mx, __shfl_xor(mx, 32));
  float dg = dgq[wave * 16 + li];
  #pragma unroll
  for (int m = 0; m < 8; m++) {
    ushort4 o4;
    #pragma unroll
    for (int r = 0; r < 4; r++)
      ((ushort*)&o4)[r] = f2b(RATIO * (__expf(sacc[m][r] - dg - mx) + KEPS));
    *(ushort4*)&Sl[(wave * 16 + li) * 136 + m * 16 + gi * 4] = o4;
  }
  __syncthreads();
  f32x4 oacc[3] = {};
  #pragma unroll
  for (int ks = 0; ks < 4; ks++) {
    short8 a = *(const short8*)&Sl[(wave * 16 + li) * 136 + ks * 32 + gi * 8];
    #pragma unroll
    for (int n = 0; n < 3; n++) {
      short8 bb = *(const short8*)&Bml[(n * 16 + li) * 136 + ks * 32 + gi * 8];
      oacc[n] = MFMA(a, bb, oacc[n]);
    }
  }
  int t = t0 + wave * 16 + gi * 4;
  float den[4];
  #pragma unroll
  for (int r = 0; r < 4; r++) den[r] = __shfl(oacc[2][r], lane & 48);
  #pragma unroll
  for (int n = 0; n < 2; n++)
    #pragma unroll
    for (int r = 0; r < 4; r++)
      ob[((size_t)(b * 512) + t + r) * 256 + h * 32 + n * 16 + li] = f2b(oacc[n][r] / den[r]);
}

// ---------------- GEMM (full 256-col rows) + bias + residual + {LN -> h | mask -> out} ----------------
template<int MODE>  // 0: write x fp32 + h = LN(x); 1: final masks to mout
__global__ __launch_bounds__(256) void gemm_ln(
    const ushort* __restrict__ A, const ushort* __restrict__ BTm,
    const float* __restrict__ bias, const float* __restrict__ res,
    float* __restrict__ x, const float* __restrict__ g, const float* __restrict__ bvec,
    ushort* __restrict__ hout,
    const float* __restrict__ Wm, const float* __restrict__ bm, float* __restrict__ mout,
    int K) {
  __shared__ __align__(16) ushort Al[64 * 32];
  __shared__ __align__(16) ushort Bl[256 * 32];
  int tid = threadIdx.x, wave = tid >> 6, lane = tid & 63;
  int gi = lane >> 4, li = lane & 15;
  int lrow = lane >> 2, lkb = (lane & 3) * 8;
  int row0 = blockIdx.x * 64;
  f32x4 acc[16] = {};
  for (int k0 = 0; k0 < K; k0 += 32) {
    gload16(&A[(size_t)(row0 + wave * 16 + lrow) * K + k0 + lkb], &Al[wave * 512]);
    #pragma unroll
    for (int i = 0; i < 4; i++) {
      int chunk = wave * 4 + i;
      gload16(&BTm[(size_t)(chunk * 16 + lrow) * K + k0 + lkb], &Bl[chunk * 512]);
    }
    __syncthreads();
    short8 a = *(const short8*)&Al[(wave * 16 + li) * 32 + gi * 8];
    #pragma unroll
    for (int n = 0; n < 16; n++) {
      short8 b = *(const short8*)&Bl[(n * 16 + li) * 32 + gi * 8];
      acc[n] = MFMA(a, b, acc[n]);
    }
    __syncthreads();
  }
  #pragma unroll
  for (int r = 0; r < 4; r++) {
    int row = row0 + wave * 16 + gi * 4 + r;
    float xv[16];
    float s1 = 0.f, s2 = 0.f;
    #pragma unroll
    for (int n = 0; n < 16; n++) {
      int col = n * 16 + li;
      float vv = acc[n][r] + bias[col] + res[(size_t)row * 256 + col];
      xv[n] = vv; s1 += vv; s2 += vv * vv;
    }
    if (MODE == 0) {
      #pragma unroll
      for (int off = 1; off <= 8; off <<= 1) { s1 += __shfl_xor(s1, off); s2 += __shfl_xor(s2, off); }
      float mu = s1 * (1.f / 256.f);
      float rstd = rsqrtf(s2 * (1.f / 256.f) - mu * mu + 1e-5f);
      #pragma unroll
      for (int n = 0; n < 16; n++) {
        int col = n * 16 + li;
        x[(size_t)row * 256 + col] = xv[n];
        hout[(size_t)row * 256 + col] = f2b((xv[n] - mu) * rstd * g[col] + bvec[col]);
      }
    } else {
      int bb_ = row >> 9, t = row & 511;
      #pragma unroll
      for (int msk = 0; msk < NM; msk++) {
        float sm = 0.f;
        #pragma unroll
        for (int n = 0; n < 16; n++) sm += xv[n] * Wm[(n * 16 + li) * NM + msk];
        #pragma unroll
        for (int off = 1; off <= 8; off <<= 1) sm += __shfl_xor(sm, off);
        if (li == 0) mout[((size_t)(bb_ * NM) + msk) * 512 + t] = sm + bm[msk];
      }
    }
  }
}

extern "C" void kernel_launch(void* const* d_in, const int* in_sizes, int n_in,
                              void* d_out, int out_size, void* d_ws, size_t ws_size,
                              hipStream_t stream) {
  const float* mel   = (const float*)d_in[0];
  const float* proj  = (const float*)d_in[1];
  const float* ln1_g = (const float*)d_in[2];
  const float* ln1_b = (const float*)d_in[3];
  const float* Wq    = (const float*)d_in[4];
  const float* Wk    = (const float*)d_in[5];
  const float* Wv    = (const float*)d_in[6];
  const float* Wo    = (const float*)d_in[7];
  const float* bo    = (const float*)d_in[8];
  const float* ln2_g = (const float*)d_in[9];
  const float* ln2_b = (const float*)d_in[10];
  const float* W1    = (const float*)d_in[11];
  const float* b1    = (const float*)d_in[12];
  const float* W2    = (const float*)d_in[13];
  const float* b2    = (const float*)d_in[14];
  const float* Wm    = (const float*)d_in[15];
  const float* bm    = (const float*)d_in[16];

  // ---- workspace layout ----
  float* x      = (float*)d_ws;                        // BT*D fp32
  ushort* us    = (ushort*)(x + (size_t)BT * D);
  ushort* h     = us;                   us += (size_t)BT * D;
  ushort* qb    = us;                   us += (size_t)BT * D;
  ushort* kb    = us;                   us += (size_t)BT * D;
  ushort* vT    = us;                   us += (size_t)BH * 32 * T;
  ushort* ob    = us;                   us += (size_t)BT * D;
  ushort* ffh   = us;                   us += (size_t)BT * FF;
  ushort* Bmat  = us;                   us += (size_t)BH * 48 * MF;
  ushort* qkvT  = us;                   us += (size_t)NLAYER * 768 * 256;
  ushort* woT   = us;                   us += (size_t)NLAYER * 256 * 256;
  ushort* w1T   = us;                   us += (size_t)NLAYER * 1024 * 256;
  ushort* w2T   = us;                   us += (size_t)NLAYER * 256 * 1024;
  ushort* projd = us;                   us += (size_t)MF * DH;

  // ---- prep: transposed bf16 weights ----
  wtrans<<<dim3(8, 8, NLAYER), dim3(32, 8), 0, stream>>>(Wq, qkvT, 256, 256, 65536, 768 * 256);
  wtrans<<<dim3(8, 8, NLAYER), dim3(32, 8), 0, stream>>>(Wk, qkvT + 256 * 256, 256, 256, 65536, 768 * 256);
  wtrans<<<dim3(8, 8, NLAYER), dim3(32, 8), 0, stream>>>(Wv, qkvT + 512 * 256, 256, 256, 65536, 768 * 256);
  wtrans<<<dim3(8, 8, NLAYER), dim3(32, 8), 0, stream>>>(Wo, woT, 256, 256, 65536, 65536);
  wtrans<<<dim3(32, 8, NLAYER), dim3(32, 8), 0, stream>>>(W1, w1T, 256, 1024, 262144, 262144);
  wtrans<<<dim3(8, 32, NLAYER), dim3(32, 8), 0, stream>>>(W2, w2T, 1024, 256, 262144, 262144);
  proj_conv<<<16, 256, 0, stream>>>(proj, projd);

  transpose_mel<<<dim3(T / 32, D / 32, B), dim3(32, 8), 0, stream>>>(mel, x);
  ln_kernel<<<BT / 4, 256, 0, stream>>>(x, ln1_g, ln1_b, h);

  for (int l = 0; l < NLAYER; l++) {
    gemm_bf16<0, 128><<<dim3(6, 128), 256, 0, stream>>>(h, qkvT + (size_t)l * 768 * 256,
        nullptr, nullptr, qb, kb, vT, 768, 256);
    ctx_fused<<<BH, 256, 0, stream>>>(kb, projd, vT, Bmat);
    favq_o<<<dim3(8, BH), 256, 0, stream>>>(qb, projd, Bmat, ob);
    gemm_ln<0><<<256, 256, 0, stream>>>(ob, woT + (size_t)l * 256 * 256,
        bo + l * D, x, x, ln2_g + l * D, ln2_b + l * D, h,
        nullptr, nullptr, nullptr, 256);
    gemm_bf16<2, 128><<<dim3(8, 128), 256, 0, stream>>>(h, w1T + (size_t)l * 1024 * 256,
        b1 + (size_t)l * FF, ffh, nullptr, nullptr, nullptr, 1024, 256);
    if (l < NLAYER - 1) {
      gemm_ln<0><<<256, 256, 0, stream>>>(ffh, w2T + (size_t)l * 256 * 1024,
          b2 + l * D, x, x, ln1_g + (l + 1) * D, ln1_b + (l + 1) * D, h,
          nullptr, nullptr, nullptr, 1024);
    } else {
      gemm_ln<1><<<256, 256, 0, stream>>>(ffh, w2T + (size_t)l * 256 * 1024,
          b2 + l * D, x, x, nullptr, nullptr, nullptr,
          Wm, bm, (float*)d_out, 1024);
    }
  }
}

// Round 7
// 855.631 us; speedup vs baseline: 10.0126x; 1.1061x over previous
//
#include <hip/hip_runtime.h>
#include <math.h>

#define B 32
#define T 512
#define D 256
#define H 8
#define DH 32
#define MF 128
#define NLAYER 6
#define FF 1024
#define NM 4
#define BT (B*T)
#define BH (B*H)

#define DN2H 0.08838834764831845f   /* 0.5 * 32^-0.5 (0.5*dn^2) */
#define DNS  0.4204482076268573f    /* 32^-0.25 */
#define RATIO 0.08838834764831845f  /* 128^-0.5 */
#define KEPS 1e-4f

typedef __attribute__((ext_vector_type(8))) short short8;
typedef __attribute__((ext_vector_type(4))) float f32x4;

#define MFMA(a, b, c) __builtin_amdgcn_mfma_f32_16x16x32_bf16(a, b, c, 0, 0, 0)

// swizzled 16B-group (in elements offset) a staging lane fetches from global
#define SWZG(l) (((((l) & 3) + (((l) >> 3) & 3)) & 3) * 8)
// LDS element offset of logical 16B-group gi for row-in-chunk li (inverse swizzle)
#define RS(li, gi) (((((gi) - ((li) >> 1)) & 3)) * 8)

__device__ __forceinline__ ushort f2b(float x) {
  union { float f; unsigned u; } c; c.f = x;
  unsigned r = (c.u + 0x7FFFu + ((c.u >> 16) & 1u)) >> 16;
  return (ushort)r;
}
__device__ __forceinline__ float bf2f(ushort u) {
  union { unsigned u; float f; } c; c.u = ((unsigned)u) << 16;
  return c.f;
}
__device__ __forceinline__ void gload16(const ushort* g, ushort* l) {
  __builtin_amdgcn_global_load_lds((const __attribute__((address_space(1))) void*)g,
                                   (__attribute__((address_space(3))) void*)l, 16, 0, 0);
}

// ---------------- transpose mel (B,D,T) -> x (B,T,D) fp32 ----------------
__global__ void transpose_mel(const float* __restrict__ mel, float* __restrict__ x) {
  __shared__ float tile[32][33];
  int b = blockIdx.z;
  int d0 = blockIdx.y * 32, t0 = blockIdx.x * 32;
  int tx = threadIdx.x, ty = threadIdx.y;
  #pragma unroll
  for (int i = 0; i < 32; i += 8)
    tile[ty + i][tx] = mel[(b * D + d0 + ty + i) * T + t0 + tx];
  __syncthreads();
  #pragma unroll
  for (int i = 0; i < 32; i += 8)
    x[(b * T + t0 + ty + i) * D + d0 + tx] = tile[tx][ty + i];
}

// ---------------- weight transpose+convert: W[K][N] fp32 -> WT[N][K] bf16 ----------------
__global__ void wtrans(const float* __restrict__ W, ushort* __restrict__ WT,
                       int K, int N, size_t lin, size_t lout) {
  __shared__ float tile[32][33];
  int l = blockIdx.z;
  const float* Wl = W + (size_t)l * lin;
  ushort* WTl = WT + (size_t)l * lout;
  int k0 = blockIdx.y * 32, n0 = blockIdx.x * 32;
  int tx = threadIdx.x, ty = threadIdx.y;
  #pragma unroll
  for (int i = 0; i < 32; i += 8)
    tile[ty + i][tx] = Wl[(size_t)(k0 + ty + i) * N + n0 + tx];
  __syncthreads();
  #pragma unroll
  for (int i = 0; i < 32; i += 8)
    WTl[(size_t)(n0 + ty + i) * K + k0 + tx] = f2b(tile[tx][ty + i]);
}

// ---------------- proj convert (prescaled by DN) ----------------
__global__ void proj_conv(const float* __restrict__ proj, ushort* __restrict__ projd) {
  int e = blockIdx.x * 256 + threadIdx.x;
  if (e < MF * DH) projd[e] = f2b(proj[e] * DNS);
}

// ---------------- layernorm (layer-0 entry only) ----------------
__global__ __launch_bounds__(256) void ln_kernel(const float* __restrict__ x, const float* __restrict__ g,
                          const float* __restrict__ bb, ushort* __restrict__ y) {
  int row = blockIdx.x * 4 + (threadIdx.x >> 6);
  int lane = threadIdx.x & 63;
  const float4 v = ((const float4*)(x + (size_t)row * D))[lane];
  float s = v.x + v.y + v.z + v.w;
  #pragma unroll
  for (int off = 32; off; off >>= 1) s += __shfl_down(s, off);
  s = __shfl(s, 0);
  float mu = s * (1.0f / 256.0f);
  float dx = v.x - mu, dy = v.y - mu, dz = v.z - mu, dw = v.w - mu;
  float q = dx * dx + dy * dy + dz * dz + dw * dw;
  #pragma unroll
  for (int off = 32; off; off >>= 1) q += __shfl_down(q, off);
  q = __shfl(q, 0);
  float rstd = rsqrtf(q * (1.0f / 256.0f) + 1e-5f);
  const float4 gg = ((const float4*)g)[lane];
  const float4 be = ((const float4*)bb)[lane];
  ushort4 o;
  o.x = f2b(dx * rstd * gg.x + be.x);
  o.y = f2b(dy * rstd * gg.y + be.y);
  o.z = f2b(dz * rstd * gg.z + be.z);
  o.w = f2b(dw * rstd * gg.w + be.w);
  ((ushort4*)(y + (size_t)row * D))[lane] = o;
}

// ---------------- bf16 MFMA GEMM, swizzled gload_lds staging ----------------
// EPI 0: QKV split (q,k natural bf16; v transposed [bh*32+d][T])
// EPI 2: + bias + fast-gelu -> bf16
template<int EPI, int BM>
__global__ __launch_bounds__(256) void gemm_bf16(
    const ushort* __restrict__ A, const ushort* __restrict__ BTm,
    const float* __restrict__ bias,
    ushort* __restrict__ outB,
    ushort* __restrict__ qo, ushort* __restrict__ ko, ushort* __restrict__ vT,
    int N, int K) {
  constexpr int MFR = BM / 32;
  __shared__ __align__(16) ushort Al[BM * 32];
  __shared__ __align__(16) ushort Bl[128 * 32];
  int tid = threadIdx.x;
  int wave = tid >> 6, lane = tid & 63;
  int wr = wave >> 1, wc = wave & 1;
  int gi = lane >> 4, li = lane & 15;
  int lrow = lane >> 2, lkb = SWZG(lane);
  int row0 = blockIdx.y * BM, col0 = blockIdx.x * 128;
  f32x4 acc[MFR][4] = {};
  for (int k0 = 0; k0 < K; k0 += 32) {
    #pragma unroll
    for (int i = 0; i < BM / 64; i++) {
      int chunk = wave * (BM / 64) + i;
      int row = chunk * 16 + lrow;
      gload16(&A[(size_t)(row0 + row) * K + k0 + lkb], &Al[chunk * 512]);
    }
    #pragma unroll
    for (int i = 0; i < 2; i++) {
      int chunk = wave * 2 + i;
      int row = chunk * 16 + lrow;
      gload16(&BTm[(size_t)(col0 + row) * K + k0 + lkb], &Bl[chunk * 512]);
    }
    __syncthreads();
    short8 a[MFR], b[4];
    #pragma unroll
    for (int m = 0; m < MFR; m++)
      a[m] = *(const short8*)&Al[(wr * (MFR * 16) + m * 16 + li) * 32 + RS(li, gi)];
    #pragma unroll
    for (int n = 0; n < 4; n++)
      b[n] = *(const short8*)&Bl[(wc * 64 + n * 16 + li) * 32 + RS(li, gi)];
    #pragma unroll
    for (int m = 0; m < MFR; m++)
      #pragma unroll
      for (int n = 0; n < 4; n++)
        acc[m][n] = MFMA(a[m], b[n], acc[m][n]);
    __syncthreads();
  }
  #pragma unroll
  for (int m = 0; m < MFR; m++) {
    int rbase = row0 + wr * (MFR * 16) + m * 16 + gi * 4;
    #pragma unroll
    for (int n = 0; n < 4; n++) {
      int col = col0 + wc * 64 + n * 16 + li;
      f32x4 v = acc[m][n];
      if (EPI == 2) {
        float bs = bias[col];
        #pragma unroll
        for (int r = 0; r < 4; r++) {
          float u = v[r] + bs;
          float p = u + 0.044715f * u * u * u;
          float gel = u / (1.0f + __expf(-1.5957691216057308f * p));
          outB[(size_t)(rbase + r) * N + col] = f2b(gel);
        }
      } else {
        if (col < 256) {
          #pragma unroll
          for (int r = 0; r < 4; r++) qo[(size_t)(rbase + r) * 256 + col] = f2b(v[r]);
        } else if (col < 512) {
          #pragma unroll
          for (int r = 0; r < 4; r++) ko[(size_t)(rbase + r) * 256 + col - 256] = f2b(v[r]);
        } else {
          int b_ = rbase >> 9, t = rbase & 511;
          int hh = (col - 512) >> 5, d = (col - 512) & 31;
          ushort4 pk;
          pk.x = f2b(v[0]); pk.y = f2b(v[1]); pk.z = f2b(v[2]); pk.w = f2b(v[3]);
          *(ushort4*)&vT[((size_t)((b_ * 8 + hh) * 32 + d)) * 512 + t] = pk;
        }
      }
    }
  }
}

// ---------------- fused k-features + ctx per (b,h) (unchanged) ----------------
__global__ __launch_bounds__(256) void ctx_fused(
    const ushort* __restrict__ kb, const ushort* __restrict__ projd,
    const ushort* __restrict__ vT, ushort* __restrict__ Bmat) {
  __shared__ __align__(16) ushort Kl[512 * 32];
  __shared__ __align__(16) ushort Pl[128 * 32];
  __shared__ __align__(16) ushort Sl[2][128 * 40];
  __shared__ __align__(16) ushort Bvl[2][32 * 32];
  __shared__ float dg_s[512];
  __shared__ float red_s[256];
  int bh = blockIdx.x;
  int b = bh >> 3, h = bh & 7;
  int tid = threadIdx.x, wave = tid >> 6, lane = tid & 63;
  int gi = lane >> 4, li = lane & 15;
  int lrow = lane >> 2, lkb = (lane & 3) * 8;
  const ushort* Kg = kb + (size_t)(b * 512) * 256 + h * 32;
  const ushort* Vg = vT + (size_t)bh * 32 * 512;
  #pragma unroll
  for (int i = 0; i < 8; i++) {
    int chunk = wave * 8 + i;
    gload16(&Kg[(size_t)(chunk * 16 + lrow) * 256 + lkb], &Kl[chunk * 512]);
  }
  #pragma unroll
  for (int i = 0; i < 2; i++) {
    int chunk = wave * 2 + i;
    gload16(&projd[(chunk * 16 + lrow) * 32 + lkb], &Pl[chunk * 512]);
  }
  __syncthreads();
  #pragma unroll
  for (int i = 0; i < 2; i++) {
    int t = tid * 2 + i;
    const ushort* kr = &Kl[t * 32];
    float s = 0.f;
    #pragma unroll
    for (int j = 0; j < 32; j++) { float v = bf2f(kr[j]); s += v * v; }
    dg_s[t] = DN2H * s;
  }
  short8 bp0 = *(const short8*)&Pl[(wave * 32 + li) * 32 + gi * 8];
  short8 bp1 = *(const short8*)&Pl[(wave * 32 + 16 + li) * 32 + gi * 8];
  float smax = -1e30f;
  for (int c = 0; c < 16; c++) {
    int t0c = c * 32;
    short8 a0 = *(const short8*)&Kl[(t0c + li) * 32 + gi * 8];
    short8 a1 = *(const short8*)&Kl[(t0c + 16 + li) * 32 + gi * 8];
    f32x4 s00 = {}, s01 = {}, s10 = {}, s11 = {};
    s00 = MFMA(a0, bp0, s00); s01 = MFMA(a0, bp1, s01);
    s10 = MFMA(a1, bp0, s10); s11 = MFMA(a1, bp1, s11);
    #pragma unroll
    for (int r = 0; r < 4; r++)
      smax = fmaxf(smax, fmaxf(fmaxf(s00[r], s01[r]), fmaxf(s10[r], s11[r])));
  }
  red_s[tid] = smax;
  __syncthreads();
  for (int s = 128; s; s >>= 1) {
    if (tid < s) red_s[tid] = fmaxf(red_s[tid], red_s[tid + s]);
    __syncthreads();
  }
  float km = red_s[0];
  f32x4 cacc[2][2] = {};
  float ks0 = 0.f, ks1 = 0.f;
  int cur = 0;
  for (int c = 0; c < 16; c++, cur ^= 1) {
    int t0c = c * 32;
    if (wave < 2)
      gload16(&Vg[(size_t)(wave * 16 + lrow) * 512 + t0c + lkb], &Bvl[cur][wave * 512]);
    short8 a0 = *(const short8*)&Kl[(t0c + li) * 32 + gi * 8];
    short8 a1 = *(const short8*)&Kl[(t0c + 16 + li) * 32 + gi * 8];
    f32x4 s00 = {}, s01 = {}, s10 = {}, s11 = {};
    s00 = MFMA(a0, bp0, s00); s01 = MFMA(a0, bp1, s01);
    s10 = MFMA(a1, bp0, s10); s11 = MFMA(a1, bp1, s11);
    ushort4 w00, w01, w10, w11;
    #pragma unroll
    for (int r = 0; r < 4; r++) {
      float d0 = dg_s[t0c + gi * 4 + r];
      float d1 = dg_s[t0c + 16 + gi * 4 + r];
      float k00 = RATIO * (__expf(s00[r] - d0 - km) + KEPS);
      float k01 = RATIO * (__expf(s01[r] - d0 - km) + KEPS);
      float k10 = RATIO * (__expf(s10[r] - d1 - km) + KEPS);
      float k11 = RATIO * (__expf(s11[r] - d1 - km) + KEPS);
      ks0 += k00 + k10; ks1 += k01 + k11;
      ((ushort*)&w00)[r] = f2b(k00); ((ushort*)&w01)[r] = f2b(k01);
      ((ushort*)&w10)[r] = f2b(k10); ((ushort*)&w11)[r] = f2b(k11);
    }
    *(ushort4*)&Sl[cur][(wave * 32 + li) * 40 + gi * 4]           = w00;
    *(ushort4*)&Sl[cur][(wave * 32 + 16 + li) * 40 + gi * 4]      = w01;
    *(ushort4*)&Sl[cur][(wave * 32 + li) * 40 + 16 + gi * 4]      = w10;
    *(ushort4*)&Sl[cur][(wave * 32 + 16 + li) * 40 + 16 + gi * 4] = w11;
    __syncthreads();
    short8 ca0 = *(const short8*)&Sl[cur][(wave * 32 + li) * 40 + gi * 8];
    short8 ca1 = *(const short8*)&Sl[cur][(wave * 32 + 16 + li) * 40 + gi * 8];
    short8 cb0 = *(const short8*)&Bvl[cur][li * 32 + gi * 8];
    short8 cb1 = *(const short8*)&Bvl[cur][(16 + li) * 32 + gi * 8];
    cacc[0][0] = MFMA(ca0, cb0, cacc[0][0]);
    cacc[0][1] = MFMA(ca0, cb1, cacc[0][1]);
    cacc[1][0] = MFMA(ca1, cb0, cacc[1][0]);
    cacc[1][1] = MFMA(ca1, cb1, cacc[1][1]);
  }
  ks0 += __shfl_xor(ks0, 16); ks0 += __shfl_xor(ks0, 32);
  ks1 += __shfl_xor(ks1, 16); ks1 += __shfl_xor(ks1, 32);
  if (gi == 0) {
    Bmat[((size_t)bh * 48 + 32) * 128 + wave * 32 + li] = f2b(ks0);
    Bmat[((size_t)bh * 48 + 32) * 128 + wave * 32 + 16 + li] = f2b(ks1);
  }
  #pragma unroll
  for (int m = 0; m < 2; m++)
    #pragma unroll
    for (int n = 0; n < 2; n++) {
      int dd = n * 16 + li;
      int mg = wave * 32 + m * 16 + gi * 4;
      ushort4 pk;
      pk.x = f2b(cacc[m][n][0]); pk.y = f2b(cacc[m][n][1]);
      pk.z = f2b(cacc[m][n][2]); pk.w = f2b(cacc[m][n][3]);
      *(ushort4*)&Bmat[((size_t)bh * 48 + dd) * 128 + mg] = pk;
    }
  for (int e = tid; e < 15 * 128; e += 256)
    Bmat[((size_t)bh * 48 + 33) * 128 + e] = 0;
}

// ---------------- fused q-features + o per (64 t, bh) (unchanged) ----------------
__global__ __launch_bounds__(256) void favq_o(
    const ushort* __restrict__ qb, const ushort* __restrict__ projd,
    const ushort* __restrict__ Bmat, ushort* __restrict__ ob) {
  __shared__ __align__(16) ushort Ql[64 * 32];
  __shared__ __align__(16) ushort Pl[128 * 32];
  __shared__ __align__(16) ushort Sl[64 * 136];
  __shared__ __align__(16) ushort Bml[48 * 136];
  __shared__ float dgq[64];
  int bh = blockIdx.y;
  int t0 = blockIdx.x * 64;
  int b = bh >> 3, h = bh & 7;
  int tid = threadIdx.x, wave = tid >> 6, lane = tid & 63;
  int gi = lane >> 4, li = lane & 15;
  int lrow = lane >> 2, lkb = (lane & 3) * 8;
  const ushort* Qg = qb + (size_t)(b * 512) * 256 + h * 32;
  gload16(&Qg[(size_t)(t0 + wave * 16 + lrow) * 256 + lkb], &Ql[wave * 512]);
  #pragma unroll
  for (int i = 0; i < 2; i++) {
    int chunk = wave * 2 + i;
    gload16(&projd[(chunk * 16 + lrow) * 32 + lkb], &Pl[chunk * 512]);
  }
  #pragma unroll
  for (int j = 0; j < 3; j++) {
    int c = j * 256 + tid;
    int r = c >> 4, g = c & 15;
    *(uint4*)&Bml[r * 136 + g * 8] = *(const uint4*)&Bmat[(size_t)bh * 48 * 128 + r * 128 + g * 8];
  }
  __syncthreads();
  if (tid < 64) {
    const ushort* qr = &Ql[tid * 32];
    float s = 0.f;
    #pragma unroll
    for (int j = 0; j < 32; j++) { float v = bf2f(qr[j]); s += v * v; }
    dgq[tid] = DN2H * s;
  }
  short8 bq = *(const short8*)&Ql[(wave * 16 + li) * 32 + gi * 8];
  f32x4 sacc[8] = {};
  #pragma unroll
  for (int m = 0; m < 8; m++) {
    short8 a = *(const short8*)&Pl[(m * 16 + li) * 32 + gi * 8];
    sacc[m] = MFMA(a, bq, sacc[m]);
  }
  __syncthreads();
  float mx = -1e30f;
  #pragma unroll
  for (int m = 0; m < 8; m++)
    #pragma unroll
    for (int r = 0; r < 4; r++) mx = fmaxf(mx, sacc[m][r]);
  mx = fmaxf(mx, __shfl_xor(mx, 16));
  mx = fmaxf(mx, __shfl_xor(mx, 32));
  float dg = dgq[wave * 16 + li];
  #pragma unroll
  for (int m = 0; m < 8; m++) {
    ushort4 o4;
    #pragma unroll
    for (int r = 0; r < 4; r++)
      ((ushort*)&o4)[r] = f2b(RATIO * (__expf(sacc[m][r] - dg - mx) + KEPS));
    *(ushort4*)&Sl[(wave * 16 + li) * 136 + m * 16 + gi * 4] = o4;
  }
  __syncthreads();
  f32x4 oacc[3] = {};
  #pragma unroll
  for (int ks = 0; ks < 4; ks++) {
    short8 a = *(const short8*)&Sl[(wave * 16 + li) * 136 + ks * 32 + gi * 8];
    #pragma unroll
    for (int n = 0; n < 3; n++) {
      short8 bb = *(const short8*)&Bml[(n * 16 + li) * 136 + ks * 32 + gi * 8];
      oacc[n] = MFMA(a, bb, oacc[n]);
    }
  }
  int t = t0 + wave * 16 + gi * 4;
  float den[4];
  #pragma unroll
  for (int r = 0; r < 4; r++) den[r] = __shfl(oacc[2][r], lane & 48);
  #pragma unroll
  for (int n = 0; n < 2; n++)
    #pragma unroll
    for (int r = 0; r < 4; r++)
      ob[((size_t)(b * 512) + t + r) * 256 + h * 32 + n * 16 + li] = f2b(oacc[n][r] / den[r]);
}

// ---------------- GEMM 64x256 + bias + residual + {LN -> h | mask -> out} ----------------
// 4 waves, wave tile 64 rows x 64 cols (4m x 4n frags), swizzled staging.
template<int MODE>  // 0: write x fp32 + h = LN(x); 1: final masks to mout
__global__ __launch_bounds__(256) void gemm_ln2(
    const ushort* __restrict__ A, const ushort* __restrict__ BTm,
    const float* __restrict__ bias, const float* __restrict__ res,
    float* __restrict__ x, const float* __restrict__ g, const float* __restrict__ bvec,
    ushort* __restrict__ hout,
    const float* __restrict__ Wm, const float* __restrict__ bm, float* __restrict__ mout,
    int K) {
  __shared__ __align__(16) ushort Al[64 * 32];
  __shared__ __align__(16) ushort Bl[256 * 32];
  __shared__ float rs1[4 * 64];
  __shared__ float rs2[4 * 64];
  __shared__ float pmS[4 * 256];
  int tid = threadIdx.x, wave = tid >> 6, lane = tid & 63;
  int gi = lane >> 4, li = lane & 15;
  int lrow = lane >> 2, lkb = SWZG(lane);
  int row0 = blockIdx.x * 64;
  int wc = wave;
  f32x4 acc[4][4] = {};
  for (int k0 = 0; k0 < K; k0 += 32) {
    gload16(&A[(size_t)(row0 + wave * 16 + lrow) * K + k0 + lkb], &Al[wave * 512]);
    #pragma unroll
    for (int i = 0; i < 4; i++) {
      int chunk = wave * 4 + i;
      gload16(&BTm[(size_t)(chunk * 16 + lrow) * K + k0 + lkb], &Bl[chunk * 512]);
    }
    __syncthreads();
    short8 a[4], b[4];
    #pragma unroll
    for (int m = 0; m < 4; m++)
      a[m] = *(const short8*)&Al[(m * 16 + li) * 32 + RS(li, gi)];
    #pragma unroll
    for (int n = 0; n < 4; n++)
      b[n] = *(const short8*)&Bl[(wc * 64 + n * 16 + li) * 32 + RS(li, gi)];
    #pragma unroll
    for (int m = 0; m < 4; m++)
      #pragma unroll
      for (int n = 0; n < 4; n++)
        acc[m][n] = MFMA(a[m], b[n], acc[m][n]);
    __syncthreads();
  }
  // phase 1: add bias+res into acc; per-row partial sums -> LDS
  #pragma unroll
  for (int m = 0; m < 4; m++) {
    #pragma unroll
    for (int r = 0; r < 4; r++) {
      int row = row0 + m * 16 + gi * 4 + r;
      int ridx = m * 16 + gi * 4 + r;
      float s1 = 0.f, s2 = 0.f;
      #pragma unroll
      for (int n = 0; n < 4; n++) {
        int col = wc * 64 + n * 16 + li;
        float val = acc[m][n][r] + bias[col] + res[(size_t)row * 256 + col];
        acc[m][n][r] = val;
        s1 += val; s2 += val * val;
      }
      if (MODE == 0) {
        #pragma unroll
        for (int off = 1; off <= 8; off <<= 1) { s1 += __shfl_xor(s1, off); s2 += __shfl_xor(s2, off); }
        if (li == 0) { rs1[wave * 64 + ridx] = s1; rs2[wave * 64 + ridx] = s2; }
      } else {
        #pragma unroll
        for (int msk = 0; msk < NM; msk++) {
          float sm = 0.f;
          #pragma unroll
          for (int n = 0; n < 4; n++) {
            int col = wc * 64 + n * 16 + li;
            sm += acc[m][n][r] * Wm[col * NM + msk];
          }
          #pragma unroll
          for (int off = 1; off <= 8; off <<= 1) sm += __shfl_xor(sm, off);
          if (li == 0) pmS[wave * 256 + ridx * 4 + msk] = sm;
        }
      }
    }
  }
  __syncthreads();
  if (MODE == 0) {
    float g4[4], bv4[4];
    #pragma unroll
    for (int n = 0; n < 4; n++) {
      int col = wc * 64 + n * 16 + li;
      g4[n] = g[col]; bv4[n] = bvec[col];
    }
    #pragma unroll
    for (int m = 0; m < 4; m++) {
      #pragma unroll
      for (int r = 0; r < 4; r++) {
        int row = row0 + m * 16 + gi * 4 + r;
        int ridx = m * 16 + gi * 4 + r;
        float t1 = rs1[ridx] + rs1[64 + ridx] + rs1[128 + ridx] + rs1[192 + ridx];
        float t2 = rs2[ridx] + rs2[64 + ridx] + rs2[128 + ridx] + rs2[192 + ridx];
        float mu = t1 * (1.f / 256.f);
        float rstd = rsqrtf(t2 * (1.f / 256.f) - mu * mu + 1e-5f);
        #pragma unroll
        for (int n = 0; n < 4; n++) {
          int col = wc * 64 + n * 16 + li;
          float val = acc[m][n][r];
          x[(size_t)row * 256 + col] = val;
          hout[(size_t)row * 256 + col] = f2b((val - mu) * rstd * g4[n] + bv4[n]);
        }
      }
    }
  } else {
    int ridx = tid >> 2, msk = tid & 3;
    float tot = pmS[ridx * 4 + msk] + pmS[256 + ridx * 4 + msk] +
                pmS[512 + ridx * 4 + msk] + pmS[768 + ridx * 4 + msk];
    int grow = row0 + ridx;
    int bb_ = grow >> 9, t = grow & 511;
    mout[((size_t)(bb_ * NM) + msk) * 512 + t] = tot + bm[msk];
  }
}

extern "C" void kernel_launch(void* const* d_in, const int* in_sizes, int n_in,
                              void* d_out, int out_size, void* d_ws, size_t ws_size,
                              hipStream_t stream) {
  const float* mel   = (const float*)d_in[0];
  const float* proj  = (const float*)d_in[1];
  const float* ln1_g = (const float*)d_in[2];
  const float* ln1_b = (const float*)d_in[3];
  const float* Wq    = (const float*)d_in[4];
  const float* Wk    = (const float*)d_in[5];
  const float* Wv    = (const float*)d_in[6];
  const float* Wo    = (const float*)d_in[7];
  const float* bo    = (const float*)d_in[8];
  const float* ln2_g = (const float*)d_in[9];
  const float* ln2_b = (const float*)d_in[10];
  const float* W1    = (const float*)d_in[11];
  const float* b1    = (const float*)d_in[12];
  const float* W2    = (const float*)d_in[13];
  const float* b2    = (const float*)d_in[14];
  const float* Wm    = (const float*)d_in[15];
  const float* bm    = (const float*)d_in[16];

  // ---- workspace layout ----
  float* x      = (float*)d_ws;                        // BT*D fp32
  ushort* us    = (ushort*)(x + (size_t)BT * D);
  ushort* h     = us;                   us += (size_t)BT * D;
  ushort* qb    = us;                   us += (size_t)BT * D;
  ushort* kb    = us;                   us += (size_t)BT * D;
  ushort* vT    = us;                   us += (size_t)BH * 32 * T;
  ushort* ob    = us;                   us += (size_t)BT * D;
  ushort* ffh   = us;                   us += (size_t)BT * FF;
  ushort* Bmat  = us;                   us += (size_t)BH * 48 * MF;
  ushort* qkvT  = us;                   us += (size_t)NLAYER * 768 * 256;
  ushort* woT   = us;                   us += (size_t)NLAYER * 256 * 256;
  ushort* w1T   = us;                   us += (size_t)NLAYER * 1024 * 256;
  ushort* w2T   = us;                   us += (size_t)NLAYER * 256 * 1024;
  ushort* projd = us;                   us += (size_t)MF * DH;

  // ---- prep: transposed bf16 weights ----
  wtrans<<<dim3(8, 8, NLAYER), dim3(32, 8), 0, stream>>>(Wq, qkvT, 256, 256, 65536, 768 * 256);
  wtrans<<<dim3(8, 8, NLAYER), dim3(32, 8), 0, stream>>>(Wk, qkvT + 256 * 256, 256, 256, 65536, 768 * 256);
  wtrans<<<dim3(8, 8, NLAYER), dim3(32, 8), 0, stream>>>(Wv, qkvT + 512 * 256, 256, 256, 65536, 768 * 256);
  wtrans<<<dim3(8, 8, NLAYER), dim3(32, 8), 0, stream>>>(Wo, woT, 256, 256, 65536, 65536);
  wtrans<<<dim3(32, 8, NLAYER), dim3(32, 8), 0, stream>>>(W1, w1T, 256, 1024, 262144, 262144);
  wtrans<<<dim3(8, 32, NLAYER), dim3(32, 8), 0, stream>>>(W2, w2T, 1024, 256, 262144, 262144);
  proj_conv<<<16, 256, 0, stream>>>(proj, projd);

  transpose_mel<<<dim3(T / 32, D / 32, B), dim3(32, 8), 0, stream>>>(mel, x);
  ln_kernel<<<BT / 4, 256, 0, stream>>>(x, ln1_g, ln1_b, h);

  for (int l = 0; l < NLAYER; l++) {
    gemm_bf16<0, 128><<<dim3(6, 128), 256, 0, stream>>>(h, qkvT + (size_t)l * 768 * 256,
        nullptr, nullptr, qb, kb, vT, 768, 256);
    ctx_fused<<<BH, 256, 0, stream>>>(kb, projd, vT, Bmat);
    favq_o<<<dim3(8, BH), 256, 0, stream>>>(qb, projd, Bmat, ob);
    gemm_ln2<0><<<256, 256, 0, stream>>>(ob, woT + (size_t)l * 256 * 256,
        bo + l * D, x, x, ln2_g + l * D, ln2_b + l * D, h,
        nullptr, nullptr, nullptr, 256);
    gemm_bf16<2, 128><<<dim3(8, 128), 256, 0, stream>>>(h, w1T + (size_t)l * 1024 * 256,
        b1 + (size_t)l * FF, ffh, nullptr, nullptr, nullptr, 1024, 256);
    if (l < NLAYER - 1) {
      gemm_ln2<0><<<256, 256, 0, stream>>>(ffh, w2T + (size_t)l * 256 * 1024,
          b2 + l * D, x, x, ln1_g + (l + 1) * D, ln1_b + (l + 1) * D, h,
          nullptr, nullptr, nullptr, 1024);
    } else {
      gemm_ln2<1><<<256, 256, 0, stream>>>(ffh, w2T + (size_t)l * 256 * 1024,
          b2 + l * D, x, x, nullptr, nullptr, nullptr,
          Wm, bm, (float*)d_out, 1024);
    }
  }
}

// Round 8
// 805.346 us; speedup vs baseline: 10.6378x; 1.0624x over previous
//
#include <hip/hip_runtime.h>
#include <math.h>

#define B 32
#define T 512
#define D 256
#define H 8
#define DH 32
#define MF 128
#define NLAYER 6
#define FF 1024
#define NM 4
#define BT (B*T)
#define BH (B*H)

#define DN2H 0.08838834764831845f   /* 0.5 * 32^-0.5 (0.5*dn^2) */
#define DNS  0.4204482076268573f    /* 32^-0.25 */
#define RATIO 0.08838834764831845f  /* 128^-0.5 */
#define KEPS 1e-4f

typedef __attribute__((ext_vector_type(8))) short short8;
typedef __attribute__((ext_vector_type(4))) float f32x4;

#define MFMA(a, b, c) __builtin_amdgcn_mfma_f32_16x16x32_bf16(a, b, c, 0, 0, 0)

// swizzled 16B-group (element offset) a staging lane fetches from global
#define SWZG(l) (((((l) & 3) + (((l) >> 3) & 3)) & 3) * 8)
// LDS element offset of logical 16B-group gi for row-in-chunk li (inverse swizzle)
#define RS(li, gi) (((((gi) - ((li) >> 1)) & 3)) * 8)

__device__ __forceinline__ ushort f2b(float x) {
  union { float f; unsigned u; } c; c.f = x;
  unsigned r = (c.u + 0x7FFFu + ((c.u >> 16) & 1u)) >> 16;
  return (ushort)r;
}
__device__ __forceinline__ float bf2f(ushort u) {
  union { unsigned u; float f; } c; c.u = ((unsigned)u) << 16;
  return c.f;
}
__device__ __forceinline__ void gload16(const ushort* g, ushort* l) {
  __builtin_amdgcn_global_load_lds((const __attribute__((address_space(1))) void*)g,
                                   (__attribute__((address_space(3))) void*)l, 16, 0, 0);
}

// ---------------- transpose mel (B,D,T) -> x (B,T,D) fp32 ----------------
__global__ void transpose_mel(const float* __restrict__ mel, float* __restrict__ x) {
  __shared__ float tile[32][33];
  int b = blockIdx.z;
  int d0 = blockIdx.y * 32, t0 = blockIdx.x * 32;
  int tx = threadIdx.x, ty = threadIdx.y;
  #pragma unroll
  for (int i = 0; i < 32; i += 8)
    tile[ty + i][tx] = mel[(b * D + d0 + ty + i) * T + t0 + tx];
  __syncthreads();
  #pragma unroll
  for (int i = 0; i < 32; i += 8)
    x[(b * T + t0 + ty + i) * D + d0 + tx] = tile[tx][ty + i];
}

// ---------------- weight transpose+convert: W[K][N] fp32 -> WT[N][K] bf16 ----------------
__global__ void wtrans(const float* __restrict__ W, ushort* __restrict__ WT,
                       int K, int N, size_t lin, size_t lout) {
  __shared__ float tile[32][33];
  int l = blockIdx.z;
  const float* Wl = W + (size_t)l * lin;
  ushort* WTl = WT + (size_t)l * lout;
  int k0 = blockIdx.y * 32, n0 = blockIdx.x * 32;
  int tx = threadIdx.x, ty = threadIdx.y;
  #pragma unroll
  for (int i = 0; i < 32; i += 8)
    tile[ty + i][tx] = Wl[(size_t)(k0 + ty + i) * N + n0 + tx];
  __syncthreads();
  #pragma unroll
  for (int i = 0; i < 32; i += 8)
    WTl[(size_t)(n0 + ty + i) * K + k0 + tx] = f2b(tile[tx][ty + i]);
}

// ---------------- proj convert (prescaled by DN) ----------------
__global__ void proj_conv(const float* __restrict__ proj, ushort* __restrict__ projd) {
  int e = blockIdx.x * 256 + threadIdx.x;
  if (e < MF * DH) projd[e] = f2b(proj[e] * DNS);
}

// ---------------- layernorm (layer-0 entry only) ----------------
__global__ __launch_bounds__(256) void ln_kernel(const float* __restrict__ x, const float* __restrict__ g,
                          const float* __restrict__ bb, ushort* __restrict__ y) {
  int row = blockIdx.x * 4 + (threadIdx.x >> 6);
  int lane = threadIdx.x & 63;
  const float4 v = ((const float4*)(x + (size_t)row * D))[lane];
  float s = v.x + v.y + v.z + v.w;
  #pragma unroll
  for (int off = 32; off; off >>= 1) s += __shfl_down(s, off);
  s = __shfl(s, 0);
  float mu = s * (1.0f / 256.0f);
  float dx = v.x - mu, dy = v.y - mu, dz = v.z - mu, dw = v.w - mu;
  float q = dx * dx + dy * dy + dz * dz + dw * dw;
  #pragma unroll
  for (int off = 32; off; off >>= 1) q += __shfl_down(q, off);
  q = __shfl(q, 0);
  float rstd = rsqrtf(q * (1.0f / 256.0f) + 1e-5f);
  const float4 gg = ((const float4*)g)[lane];
  const float4 be = ((const float4*)bb)[lane];
  ushort4 o;
  o.x = f2b(dx * rstd * gg.x + be.x);
  o.y = f2b(dy * rstd * gg.y + be.y);
  o.z = f2b(dz * rstd * gg.z + be.z);
  o.w = f2b(dw * rstd * gg.w + be.w);
  ((ushort4*)(y + (size_t)row * D))[lane] = o;
}

// ---------------- bf16 MFMA GEMM, double-buffered swizzled gload_lds staging ----------------
// EPI 0: QKV split (q,k natural bf16; v transposed [bh*32+d][T])
// EPI 2: + bias + fast-gelu -> bf16
template<int EPI, int BM>
__global__ __launch_bounds__(256) void gemm_bf16(
    const ushort* __restrict__ A, const ushort* __restrict__ BTm,
    const float* __restrict__ bias,
    ushort* __restrict__ outB,
    ushort* __restrict__ qo, ushort* __restrict__ ko, ushort* __restrict__ vT,
    int N, int K) {
  constexpr int MFR = BM / 32;
  __shared__ __align__(16) ushort Al[2][BM * 32];
  __shared__ __align__(16) ushort Bl[2][128 * 32];
  int tid = threadIdx.x;
  int wave = tid >> 6, lane = tid & 63;
  int wr = wave >> 1, wc = wave & 1;
  int gi = lane >> 4, li = lane & 15;
  int lrow = lane >> 2, lkb = SWZG(lane);
  int row0 = blockIdx.y * BM, col0 = blockIdx.x * 128;
  f32x4 acc[MFR][4] = {};

  auto stage = [&](int buf, int kk) {
    #pragma unroll
    for (int i = 0; i < BM / 64; i++) {
      int chunk = wave * (BM / 64) + i;
      gload16(&A[(size_t)(row0 + chunk * 16 + lrow) * K + kk + lkb], &Al[buf][chunk * 512]);
    }
    #pragma unroll
    for (int i = 0; i < 2; i++) {
      int chunk = wave * 2 + i;
      gload16(&BTm[(size_t)(col0 + chunk * 16 + lrow) * K + kk + lkb], &Bl[buf][chunk * 512]);
    }
  };

  stage(0, 0);
  __syncthreads();
  int cur = 0;
  for (int k0 = 0; k0 < K; k0 += 32, cur ^= 1) {
    if (k0 + 32 < K) stage(cur ^ 1, k0 + 32);
    short8 a[MFR], b[4];
    #pragma unroll
    for (int m = 0; m < MFR; m++)
      a[m] = *(const short8*)&Al[cur][(wr * (MFR * 16) + m * 16 + li) * 32 + RS(li, gi)];
    #pragma unroll
    for (int n = 0; n < 4; n++)
      b[n] = *(const short8*)&Bl[cur][(wc * 64 + n * 16 + li) * 32 + RS(li, gi)];
    #pragma unroll
    for (int m = 0; m < MFR; m++)
      #pragma unroll
      for (int n = 0; n < 4; n++)
        acc[m][n] = MFMA(a[m], b[n], acc[m][n]);
    __syncthreads();
  }
  #pragma unroll
  for (int m = 0; m < MFR; m++) {
    int rbase = row0 + wr * (MFR * 16) + m * 16 + gi * 4;
    #pragma unroll
    for (int n = 0; n < 4; n++) {
      int col = col0 + wc * 64 + n * 16 + li;
      f32x4 v = acc[m][n];
      if (EPI == 2) {
        float bs = bias[col];
        #pragma unroll
        for (int r = 0; r < 4; r++) {
          float u = v[r] + bs;
          float p = u + 0.044715f * u * u * u;
          float gel = u / (1.0f + __expf(-1.5957691216057308f * p));
          outB[(size_t)(rbase + r) * N + col] = f2b(gel);
        }
      } else {
        if (col < 256) {
          #pragma unroll
          for (int r = 0; r < 4; r++) qo[(size_t)(rbase + r) * 256 + col] = f2b(v[r]);
        } else if (col < 512) {
          #pragma unroll
          for (int r = 0; r < 4; r++) ko[(size_t)(rbase + r) * 256 + col - 256] = f2b(v[r]);
        } else {
          int b_ = rbase >> 9, t = rbase & 511;
          int hh = (col - 512) >> 5, d = (col - 512) & 31;
          ushort4 pk;
          pk.x = f2b(v[0]); pk.y = f2b(v[1]); pk.z = f2b(v[2]); pk.w = f2b(v[3]);
          *(ushort4*)&vT[((size_t)((b_ * 8 + hh) * 32 + d)) * 512 + t] = pk;
        }
      }
    }
  }
}

// ---------------- fused k-features + ctx per (b,h) ----------------
__global__ __launch_bounds__(256) void ctx_fused(
    const ushort* __restrict__ kb, const ushort* __restrict__ projd,
    const ushort* __restrict__ vT, ushort* __restrict__ Bmat) {
  __shared__ __align__(16) ushort Kl[512 * 32];
  __shared__ __align__(16) ushort Pl[128 * 32];
  __shared__ __align__(16) ushort Sl[2][128 * 40];
  __shared__ __align__(16) ushort Bvl[2][32 * 32];
  __shared__ float dg_s[512];
  __shared__ float red_s[256];
  int bh = blockIdx.x;
  int b = bh >> 3, h = bh & 7;
  int tid = threadIdx.x, wave = tid >> 6, lane = tid & 63;
  int gi = lane >> 4, li = lane & 15;
  int lrow = lane >> 2, lkb = (lane & 3) * 8;
  const ushort* Kg = kb + (size_t)(b * 512) * 256 + h * 32;
  const ushort* Vg = vT + (size_t)bh * 32 * 512;
  #pragma unroll
  for (int i = 0; i < 8; i++) {
    int chunk = wave * 8 + i;
    gload16(&Kg[(size_t)(chunk * 16 + lrow) * 256 + lkb], &Kl[chunk * 512]);
  }
  #pragma unroll
  for (int i = 0; i < 2; i++) {
    int chunk = wave * 2 + i;
    gload16(&projd[(chunk * 16 + lrow) * 32 + lkb], &Pl[chunk * 512]);
  }
  __syncthreads();
  #pragma unroll
  for (int i = 0; i < 2; i++) {
    int t = tid * 2 + i;
    const ushort* kr = &Kl[t * 32];
    float s = 0.f;
    #pragma unroll
    for (int j = 0; j < 32; j++) { float v = bf2f(kr[j]); s += v * v; }
    dg_s[t] = DN2H * s;
  }
  short8 bp0 = *(const short8*)&Pl[(wave * 32 + li) * 32 + gi * 8];
  short8 bp1 = *(const short8*)&Pl[(wave * 32 + 16 + li) * 32 + gi * 8];
  float smax = -1e30f;
  for (int c = 0; c < 16; c++) {
    int t0c = c * 32;
    short8 a0 = *(const short8*)&Kl[(t0c + li) * 32 + gi * 8];
    short8 a1 = *(const short8*)&Kl[(t0c + 16 + li) * 32 + gi * 8];
    f32x4 s00 = {}, s01 = {}, s10 = {}, s11 = {};
    s00 = MFMA(a0, bp0, s00); s01 = MFMA(a0, bp1, s01);
    s10 = MFMA(a1, bp0, s10); s11 = MFMA(a1, bp1, s11);
    #pragma unroll
    for (int r = 0; r < 4; r++)
      smax = fmaxf(smax, fmaxf(fmaxf(s00[r], s01[r]), fmaxf(s10[r], s11[r])));
  }
  red_s[tid] = smax;
  __syncthreads();
  for (int s = 128; s; s >>= 1) {
    if (tid < s) red_s[tid] = fmaxf(red_s[tid], red_s[tid + s]);
    __syncthreads();
  }
  float km = red_s[0];
  f32x4 cacc[2][2] = {};
  float ks0 = 0.f, ks1 = 0.f;
  int cur = 0;
  for (int c = 0; c < 16; c++, cur ^= 1) {
    int t0c = c * 32;
    if (wave < 2)
      gload16(&Vg[(size_t)(wave * 16 + lrow) * 512 + t0c + lkb], &Bvl[cur][wave * 512]);
    short8 a0 = *(const short8*)&Kl[(t0c + li) * 32 + gi * 8];
    short8 a1 = *(const short8*)&Kl[(t0c + 16 + li) * 32 + gi * 8];
    f32x4 s00 = {}, s01 = {}, s10 = {}, s11 = {};
    s00 = MFMA(a0, bp0, s00); s01 = MFMA(a0, bp1, s01);
    s10 = MFMA(a1, bp0, s10); s11 = MFMA(a1, bp1, s11);
    ushort4 w00, w01, w10, w11;
    #pragma unroll
    for (int r = 0; r < 4; r++) {
      float d0 = dg_s[t0c + gi * 4 + r];
      float d1 = dg_s[t0c + 16 + gi * 4 + r];
      float k00 = RATIO * (__expf(s00[r] - d0 - km) + KEPS);
      float k01 = RATIO * (__expf(s01[r] - d0 - km) + KEPS);
      float k10 = RATIO * (__expf(s10[r] - d1 - km) + KEPS);
      float k11 = RATIO * (__expf(s11[r] - d1 - km) + KEPS);
      ks0 += k00 + k10; ks1 += k01 + k11;
      ((ushort*)&w00)[r] = f2b(k00); ((ushort*)&w01)[r] = f2b(k01);
      ((ushort*)&w10)[r] = f2b(k10); ((ushort*)&w11)[r] = f2b(k11);
    }
    *(ushort4*)&Sl[cur][(wave * 32 + li) * 40 + gi * 4]           = w00;
    *(ushort4*)&Sl[cur][(wave * 32 + 16 + li) * 40 + gi * 4]      = w01;
    *(ushort4*)&Sl[cur][(wave * 32 + li) * 40 + 16 + gi * 4]      = w10;
    *(ushort4*)&Sl[cur][(wave * 32 + 16 + li) * 40 + 16 + gi * 4] = w11;
    __syncthreads();
    short8 ca0 = *(const short8*)&Sl[cur][(wave * 32 + li) * 40 + gi * 8];
    short8 ca1 = *(const short8*)&Sl[cur][(wave * 32 + 16 + li) * 40 + gi * 8];
    short8 cb0 = *(const short8*)&Bvl[cur][li * 32 + gi * 8];
    short8 cb1 = *(const short8*)&Bvl[cur][(16 + li) * 32 + gi * 8];
    cacc[0][0] = MFMA(ca0, cb0, cacc[0][0]);
    cacc[0][1] = MFMA(ca0, cb1, cacc[0][1]);
    cacc[1][0] = MFMA(ca1, cb0, cacc[1][0]);
    cacc[1][1] = MFMA(ca1, cb1, cacc[1][1]);
  }
  ks0 += __shfl_xor(ks0, 16); ks0 += __shfl_xor(ks0, 32);
  ks1 += __shfl_xor(ks1, 16); ks1 += __shfl_xor(ks1, 32);
  if (gi == 0) {
    Bmat[((size_t)bh * 48 + 32) * 128 + wave * 32 + li] = f2b(ks0);
    Bmat[((size_t)bh * 48 + 32) * 128 + wave * 32 + 16 + li] = f2b(ks1);
  }
  #pragma unroll
  for (int m = 0; m < 2; m++)
    #pragma unroll
    for (int n = 0; n < 2; n++) {
      int dd = n * 16 + li;
      int mg = wave * 32 + m * 16 + gi * 4;
      ushort4 pk;
      pk.x = f2b(cacc[m][n][0]); pk.y = f2b(cacc[m][n][1]);
      pk.z = f2b(cacc[m][n][2]); pk.w = f2b(cacc[m][n][3]);
      *(ushort4*)&Bmat[((size_t)bh * 48 + dd) * 128 + mg] = pk;
    }
  for (int e = tid; e < 15 * 128; e += 256)
    Bmat[((size_t)bh * 48 + 33) * 128 + e] = 0;
}

// ---------------- fused q-features + o per (64 t, bh) ----------------
__global__ __launch_bounds__(256) void favq_o(
    const ushort* __restrict__ qb, const ushort* __restrict__ projd,
    const ushort* __restrict__ Bmat, ushort* __restrict__ ob) {
  __shared__ __align__(16) ushort Ql[64 * 32];
  __shared__ __align__(16) ushort Pl[128 * 32];
  __shared__ __align__(16) ushort Sl[64 * 136];
  __shared__ __align__(16) ushort Bml[48 * 136];
  __shared__ float dgq[64];
  int bh = blockIdx.y;
  int t0 = blockIdx.x * 64;
  int b = bh >> 3, h = bh & 7;
  int tid = threadIdx.x, wave = tid >> 6, lane = tid & 63;
  int gi = lane >> 4, li = lane & 15;
  int lrow = lane >> 2, lkb = (lane & 3) * 8;
  const ushort* Qg = qb + (size_t)(b * 512) * 256 + h * 32;
  gload16(&Qg[(size_t)(t0 + wave * 16 + lrow) * 256 + lkb], &Ql[wave * 512]);
  #pragma unroll
  for (int i = 0; i < 2; i++) {
    int chunk = wave * 2 + i;
    gload16(&projd[(chunk * 16 + lrow) * 32 + lkb], &Pl[chunk * 512]);
  }
  #pragma unroll
  for (int j = 0; j < 3; j++) {
    int c = j * 256 + tid;
    int r = c >> 4, g = c & 15;
    *(uint4*)&Bml[r * 136 + g * 8] = *(const uint4*)&Bmat[(size_t)bh * 48 * 128 + r * 128 + g * 8];
  }
  __syncthreads();
  if (tid < 64) {
    const ushort* qr = &Ql[tid * 32];
    float s = 0.f;
    #pragma unroll
    for (int j = 0; j < 32; j++) { float v = bf2f(qr[j]); s += v * v; }
    dgq[tid] = DN2H * s;
  }
  short8 bq = *(const short8*)&Ql[(wave * 16 + li) * 32 + gi * 8];
  f32x4 sacc[8] = {};
  #pragma unroll
  for (int m = 0; m < 8; m++) {
    short8 a = *(const short8*)&Pl[(m * 16 + li) * 32 + gi * 8];
    sacc[m] = MFMA(a, bq, sacc[m]);
  }
  __syncthreads();
  float mx = -1e30f;
  #pragma unroll
  for (int m = 0; m < 8; m++)
    #pragma unroll
    for (int r = 0; r < 4; r++) mx = fmaxf(mx, sacc[m][r]);
  mx = fmaxf(mx, __shfl_xor(mx, 16));
  mx = fmaxf(mx, __shfl_xor(mx, 32));
  float dg = dgq[wave * 16 + li];
  #pragma unroll
  for (int m = 0; m < 8; m++) {
    ushort4 o4;
    #pragma unroll
    for (int r = 0; r < 4; r++)
      ((ushort*)&o4)[r] = f2b(RATIO * (__expf(sacc[m][r] - dg - mx) + KEPS));
    *(ushort4*)&Sl[(wave * 16 + li) * 136 + m * 16 + gi * 4] = o4;
  }
  __syncthreads();
  f32x4 oacc[3] = {};
  #pragma unroll
  for (int ks = 0; ks < 4; ks++) {
    short8 a = *(const short8*)&Sl[(wave * 16 + li) * 136 + ks * 32 + gi * 8];
    #pragma unroll
    for (int n = 0; n < 3; n++) {
      short8 bb = *(const short8*)&Bml[(n * 16 + li) * 136 + ks * 32 + gi * 8];
      oacc[n] = MFMA(a, bb, oacc[n]);
    }
  }
  int t = t0 + wave * 16 + gi * 4;
  float den[4];
  #pragma unroll
  for (int r = 0; r < 4; r++) den[r] = __shfl(oacc[2][r], lane & 48);
  #pragma unroll
  for (int n = 0; n < 2; n++)
    #pragma unroll
    for (int r = 0; r < 4; r++)
      ob[((size_t)(b * 512) + t + r) * 256 + h * 32 + n * 16 + li] = f2b(oacc[n][r] / den[r]);
}

// ---------------- GEMM 64x256 + bias + residual + {LN -> h | mask -> out} ----------------
// 4 waves side-by-side over N; wave tile 64x64; double-buffered swizzled staging.
template<int MODE>  // 0: write x fp32 + h = LN(x); 1: final masks to mout
__global__ __launch_bounds__(256) void gemm_ln2(
    const ushort* __restrict__ A, const ushort* __restrict__ BTm,
    const float* __restrict__ bias, const float* __restrict__ res,
    float* __restrict__ x, const float* __restrict__ g, const float* __restrict__ bvec,
    ushort* __restrict__ hout,
    const float* __restrict__ Wm, const float* __restrict__ bm, float* __restrict__ mout,
    int K) {
  __shared__ __align__(16) ushort Al[2][64 * 32];
  __shared__ __align__(16) ushort Bl[2][256 * 32];
  __shared__ float rs1[4 * 64];
  __shared__ float rs2[4 * 64];
  __shared__ float pmS[4 * 256];
  int tid = threadIdx.x, wave = tid >> 6, lane = tid & 63;
  int gi = lane >> 4, li = lane & 15;
  int lrow = lane >> 2, lkb = SWZG(lane);
  int row0 = blockIdx.x * 64;
  int wc = wave;
  f32x4 acc[4][4] = {};

  auto stage = [&](int buf, int kk) {
    gload16(&A[(size_t)(row0 + wave * 16 + lrow) * K + kk + lkb], &Al[buf][wave * 512]);
    #pragma unroll
    for (int i = 0; i < 4; i++) {
      int chunk = wave * 4 + i;
      gload16(&BTm[(size_t)(chunk * 16 + lrow) * K + kk + lkb], &Bl[buf][chunk * 512]);
    }
  };

  stage(0, 0);
  __syncthreads();
  int cur = 0;
  for (int k0 = 0; k0 < K; k0 += 32, cur ^= 1) {
    if (k0 + 32 < K) stage(cur ^ 1, k0 + 32);
    short8 a[4], b[4];
    #pragma unroll
    for (int m = 0; m < 4; m++)
      a[m] = *(const short8*)&Al[cur][(m * 16 + li) * 32 + RS(li, gi)];
    #pragma unroll
    for (int n = 0; n < 4; n++)
      b[n] = *(const short8*)&Bl[cur][(wc * 64 + n * 16 + li) * 32 + RS(li, gi)];
    #pragma unroll
    for (int m = 0; m < 4; m++)
      #pragma unroll
      for (int n = 0; n < 4; n++)
        acc[m][n] = MFMA(a[m], b[n], acc[m][n]);
    __syncthreads();
  }
  // phase 1: add bias+res into acc; per-row partial sums -> LDS
  #pragma unroll
  for (int m = 0; m < 4; m++) {
    #pragma unroll
    for (int r = 0; r < 4; r++) {
      int row = row0 + m * 16 + gi * 4 + r;
      int ridx = m * 16 + gi * 4 + r;
      float s1 = 0.f, s2 = 0.f;
      #pragma unroll
      for (int n = 0; n < 4; n++) {
        int col = wc * 64 + n * 16 + li;
        float val = acc[m][n][r] + bias[col] + res[(size_t)row * 256 + col];
        acc[m][n][r] = val;
        s1 += val; s2 += val * val;
      }
      if (MODE == 0) {
        #pragma unroll
        for (int off = 1; off <= 8; off <<= 1) { s1 += __shfl_xor(s1, off); s2 += __shfl_xor(s2, off); }
        if (li == 0) { rs1[wave * 64 + ridx] = s1; rs2[wave * 64 + ridx] = s2; }
      } else {
        #pragma unroll
        for (int msk = 0; msk < NM; msk++) {
          float sm = 0.f;
          #pragma unroll
          for (int n = 0; n < 4; n++) {
            int col = wc * 64 + n * 16 + li;
            sm += acc[m][n][r] * Wm[col * NM + msk];
          }
          #pragma unroll
          for (int off = 1; off <= 8; off <<= 1) sm += __shfl_xor(sm, off);
          if (li == 0) pmS[wave * 256 + ridx * 4 + msk] = sm;
        }
      }
    }
  }
  __syncthreads();
  if (MODE == 0) {
    float g4[4], bv4[4];
    #pragma unroll
    for (int n = 0; n < 4; n++) {
      int col = wc * 64 + n * 16 + li;
      g4[n] = g[col]; bv4[n] = bvec[col];
    }
    #pragma unroll
    for (int m = 0; m < 4; m++) {
      #pragma unroll
      for (int r = 0; r < 4; r++) {
        int row = row0 + m * 16 + gi * 4 + r;
        int ridx = m * 16 + gi * 4 + r;
        float t1 = rs1[ridx] + rs1[64 + ridx] + rs1[128 + ridx] + rs1[192 + ridx];
        float t2 = rs2[ridx] + rs2[64 + ridx] + rs2[128 + ridx] + rs2[192 + ridx];
        float mu = t1 * (1.f / 256.f);
        float rstd = rsqrtf(t2 * (1.f / 256.f) - mu * mu + 1e-5f);
        #pragma unroll
        for (int n = 0; n < 4; n++) {
          int col = wc * 64 + n * 16 + li;
          float val = acc[m][n][r];
          x[(size_t)row * 256 + col] = val;
          hout[(size_t)row * 256 + col] = f2b((val - mu) * rstd * g4[n] + bv4[n]);
        }
      }
    }
  } else {
    int ridx = tid >> 2, msk = tid & 3;
    float tot = pmS[ridx * 4 + msk] + pmS[256 + ridx * 4 + msk] +
                pmS[512 + ridx * 4 + msk] + pmS[768 + ridx * 4 + msk];
    int grow = row0 + ridx;
    int bb_ = grow >> 9, t = grow & 511;
    mout[((size_t)(bb_ * NM) + msk) * 512 + t] = tot + bm[msk];
  }
}

extern "C" void kernel_launch(void* const* d_in, const int* in_sizes, int n_in,
                              void* d_out, int out_size, void* d_ws, size_t ws_size,
                              hipStream_t stream) {
  const float* mel   = (const float*)d_in[0];
  const float* proj  = (const float*)d_in[1];
  const float* ln1_g = (const float*)d_in[2];
  const float* ln1_b = (const float*)d_in[3];
  const float* Wq    = (const float*)d_in[4];
  const float* Wk    = (const float*)d_in[5];
  const float* Wv    = (const float*)d_in[6];
  const float* Wo    = (const float*)d_in[7];
  const float* bo    = (const float*)d_in[8];
  const float* ln2_g = (const float*)d_in[9];
  const float* ln2_b = (const float*)d_in[10];
  const float* W1    = (const float*)d_in[11];
  const float* b1    = (const float*)d_in[12];
  const float* W2    = (const float*)d_in[13];
  const float* b2    = (const float*)d_in[14];
  const float* Wm    = (const float*)d_in[15];
  const float* bm    = (const float*)d_in[16];

  // ---- workspace layout ----
  float* x      = (float*)d_ws;                        // BT*D fp32
  ushort* us    = (ushort*)(x + (size_t)BT * D);
  ushort* h     = us;                   us += (size_t)BT * D;
  ushort* qb    = us;                   us += (size_t)BT * D;
  ushort* kb    = us;                   us += (size_t)BT * D;
  ushort* vT    = us;                   us += (size_t)BH * 32 * T;
  ushort* ob    = us;                   us += (size_t)BT * D;
  ushort* ffh   = us;                   us += (size_t)BT * FF;
  ushort* Bmat  = us;                   us += (size_t)BH * 48 * MF;
  ushort* qkvT  = us;                   us += (size_t)NLAYER * 768 * 256;
  ushort* woT   = us;                   us += (size_t)NLAYER * 256 * 256;
  ushort* w1T   = us;                   us += (size_t)NLAYER * 1024 * 256;
  ushort* w2T   = us;                   us += (size_t)NLAYER * 256 * 1024;
  ushort* projd = us;                   us += (size_t)MF * DH;

  // ---- prep: transposed bf16 weights ----
  wtrans<<<dim3(8, 8, NLAYER), dim3(32, 8), 0, stream>>>(Wq, qkvT, 256, 256, 65536, 768 * 256);
  wtrans<<<dim3(8, 8, NLAYER), dim3(32, 8), 0, stream>>>(Wk, qkvT + 256 * 256, 256, 256, 65536, 768 * 256);
  wtrans<<<dim3(8, 8, NLAYER), dim3(32, 8), 0, stream>>>(Wv, qkvT + 512 * 256, 256, 256, 65536, 768 * 256);
  wtrans<<<dim3(8, 8, NLAYER), dim3(32, 8), 0, stream>>>(Wo, woT, 256, 256, 65536, 65536);
  wtrans<<<dim3(32, 8, NLAYER), dim3(32, 8), 0, stream>>>(W1, w1T, 256, 1024, 262144, 262144);
  wtrans<<<dim3(8, 32, NLAYER), dim3(32, 8), 0, stream>>>(W2, w2T, 1024, 256, 262144, 262144);
  proj_conv<<<16, 256, 0, stream>>>(proj, projd);

  transpose_mel<<<dim3(T / 32, D / 32, B), dim3(32, 8), 0, stream>>>(mel, x);
  ln_kernel<<<BT / 4, 256, 0, stream>>>(x, ln1_g, ln1_b, h);

  for (int l = 0; l < NLAYER; l++) {
    gemm_bf16<0, 128><<<dim3(6, 128), 256, 0, stream>>>(h, qkvT + (size_t)l * 768 * 256,
        nullptr, nullptr, qb, kb, vT, 768, 256);
    ctx_fused<<<BH, 256, 0, stream>>>(kb, projd, vT, Bmat);
    favq_o<<<dim3(8, BH), 256, 0, stream>>>(qb, projd, Bmat, ob);
    gemm_ln2<0><<<256, 256, 0, stream>>>(ob, woT + (size_t)l * 256 * 256,
        bo + l * D, x, x, ln2_g + l * D, ln2_b + l * D, h,
        nullptr, nullptr, nullptr, 256);
    gemm_bf16<2, 128><<<dim3(8, 128), 256, 0, stream>>>(h, w1T + (size_t)l * 1024 * 256,
        b1 + (size_t)l * FF, ffh, nullptr, nullptr, nullptr, 1024, 256);
    if (l < NLAYER - 1) {
      gemm_ln2<0><<<256, 256, 0, stream>>>(ffh, w2T + (size_t)l * 256 * 1024,
          b2 + l * D, x, x, ln1_g + (l + 1) * D, ln1_b + (l + 1) * D, h,
          nullptr, nullptr, nullptr, 1024);
    } else {
      gemm_ln2<1><<<256, 256, 0, stream>>>(ffh, w2T + (size_t)l * 256 * 1024,
          b2 + l * D, x, x, nullptr, nullptr, nullptr,
          Wm, bm, (float*)d_out, 1024);
    }
  }
}

// Round 9
// 749.979 us; speedup vs baseline: 11.4231x; 1.0738x over previous
//
#include <hip/hip_runtime.h>
#include <math.h>

#define B 32
#define T 512
#define D 256
#define H 8
#define DH 32
#define MF 128
#define NLAYER 6
#define FF 1024
#define NM 4
#define BT (B*T)
#define BH (B*H)

#define DN2H 0.08838834764831845f   /* 0.5 * 32^-0.5 (0.5*dn^2) */
#define DNS  0.4204482076268573f    /* 32^-0.25 */
#define RATIO 0.08838834764831845f  /* 128^-0.5 */
#define KEPS 1e-4f

typedef __attribute__((ext_vector_type(8))) short short8;
typedef __attribute__((ext_vector_type(4))) float f32x4;

#define MFMA(a, b, c) __builtin_amdgcn_mfma_f32_16x16x32_bf16(a, b, c, 0, 0, 0)

// swizzled 16B-group (element offset) a staging lane fetches from global
#define SWZG(l) (((((l) & 3) + (((l) >> 3) & 3)) & 3) * 8)
// LDS element offset of logical 16B-group gi for row-in-chunk li (inverse swizzle)
#define RS(li, gi) (((((gi) - ((li) >> 1)) & 3)) * 8)

__device__ __forceinline__ ushort f2b(float x) {
  union { float f; unsigned u; } c; c.f = x;
  unsigned r = (c.u + 0x7FFFu + ((c.u >> 16) & 1u)) >> 16;
  return (ushort)r;
}
__device__ __forceinline__ float bf2f(ushort u) {
  union { unsigned u; float f; } c; c.u = ((unsigned)u) << 16;
  return c.f;
}
__device__ __forceinline__ void gload16(const ushort* g, ushort* l) {
  __builtin_amdgcn_global_load_lds((const __attribute__((address_space(1))) void*)g,
                                   (__attribute__((address_space(3))) void*)l, 16, 0, 0);
}

// ---------------- transpose mel (B,D,T) -> x (B,T,D) fp32 ----------------
__global__ void transpose_mel(const float* __restrict__ mel, float* __restrict__ x) {
  __shared__ float tile[32][33];
  int b = blockIdx.z;
  int d0 = blockIdx.y * 32, t0 = blockIdx.x * 32;
  int tx = threadIdx.x, ty = threadIdx.y;
  #pragma unroll
  for (int i = 0; i < 32; i += 8)
    tile[ty + i][tx] = mel[(b * D + d0 + ty + i) * T + t0 + tx];
  __syncthreads();
  #pragma unroll
  for (int i = 0; i < 32; i += 8)
    x[(b * T + t0 + ty + i) * D + d0 + tx] = tile[tx][ty + i];
}

// ---------------- weight transpose+convert: W[K][N] fp32 -> WT[N][K] bf16 ----------------
__global__ void wtrans(const float* __restrict__ W, ushort* __restrict__ WT,
                       int K, int N, size_t lin, size_t lout) {
  __shared__ float tile[32][33];
  int l = blockIdx.z;
  const float* Wl = W + (size_t)l * lin;
  ushort* WTl = WT + (size_t)l * lout;
  int k0 = blockIdx.y * 32, n0 = blockIdx.x * 32;
  int tx = threadIdx.x, ty = threadIdx.y;
  #pragma unroll
  for (int i = 0; i < 32; i += 8)
    tile[ty + i][tx] = Wl[(size_t)(k0 + ty + i) * N + n0 + tx];
  __syncthreads();
  #pragma unroll
  for (int i = 0; i < 32; i += 8)
    WTl[(size_t)(n0 + ty + i) * K + k0 + tx] = f2b(tile[tx][ty + i]);
}

// ---------------- proj convert (prescaled by DN) ----------------
__global__ void proj_conv(const float* __restrict__ proj, ushort* __restrict__ projd) {
  int e = blockIdx.x * 256 + threadIdx.x;
  if (e < MF * DH) projd[e] = f2b(proj[e] * DNS);
}

// ---------------- layernorm (layer-0 entry only) ----------------
__global__ __launch_bounds__(256) void ln_kernel(const float* __restrict__ x, const float* __restrict__ g,
                          const float* __restrict__ bb, ushort* __restrict__ y) {
  int row = blockIdx.x * 4 + (threadIdx.x >> 6);
  int lane = threadIdx.x & 63;
  const float4 v = ((const float4*)(x + (size_t)row * D))[lane];
  float s = v.x + v.y + v.z + v.w;
  #pragma unroll
  for (int off = 32; off; off >>= 1) s += __shfl_down(s, off);
  s = __shfl(s, 0);
  float mu = s * (1.0f / 256.0f);
  float dx = v.x - mu, dy = v.y - mu, dz = v.z - mu, dw = v.w - mu;
  float q = dx * dx + dy * dy + dz * dz + dw * dw;
  #pragma unroll
  for (int off = 32; off; off >>= 1) q += __shfl_down(q, off);
  q = __shfl(q, 0);
  float rstd = rsqrtf(q * (1.0f / 256.0f) + 1e-5f);
  const float4 gg = ((const float4*)g)[lane];
  const float4 be = ((const float4*)bb)[lane];
  ushort4 o;
  o.x = f2b(dx * rstd * gg.x + be.x);
  o.y = f2b(dy * rstd * gg.y + be.y);
  o.z = f2b(dz * rstd * gg.z + be.z);
  o.w = f2b(dw * rstd * gg.w + be.w);
  ((ushort4*)(y + (size_t)row * D))[lane] = o;
}

// ---------------- bf16 MFMA GEMM, double-buffered swizzled gload_lds staging ----------------
// EPI 0: QKV split (q,k natural bf16; v transposed [bh*32+d][T])
// EPI 2: + bias + fast-gelu -> bf16
template<int EPI, int BM>
__global__ __launch_bounds__(256) void gemm_bf16(
    const ushort* __restrict__ A, const ushort* __restrict__ BTm,
    const float* __restrict__ bias,
    ushort* __restrict__ outB,
    ushort* __restrict__ qo, ushort* __restrict__ ko, ushort* __restrict__ vT,
    int N, int K) {
  constexpr int MFR = BM / 32;
  __shared__ __align__(16) ushort Al[2][BM * 32];
  __shared__ __align__(16) ushort Bl[2][128 * 32];
  int tid = threadIdx.x;
  int wave = tid >> 6, lane = tid & 63;
  int wr = wave >> 1, wc = wave & 1;
  int gi = lane >> 4, li = lane & 15;
  int lrow = lane >> 2, lkb = SWZG(lane);
  int row0 = blockIdx.y * BM, col0 = blockIdx.x * 128;
  f32x4 acc[MFR][4] = {};

  auto stage = [&](int buf, int kk) {
    #pragma unroll
    for (int i = 0; i < BM / 64; i++) {
      int chunk = wave * (BM / 64) + i;
      gload16(&A[(size_t)(row0 + chunk * 16 + lrow) * K + kk + lkb], &Al[buf][chunk * 512]);
    }
    #pragma unroll
    for (int i = 0; i < 2; i++) {
      int chunk = wave * 2 + i;
      gload16(&BTm[(size_t)(col0 + chunk * 16 + lrow) * K + kk + lkb], &Bl[buf][chunk * 512]);
    }
  };

  stage(0, 0);
  __syncthreads();
  int cur = 0;
  for (int k0 = 0; k0 < K; k0 += 32, cur ^= 1) {
    if (k0 + 32 < K) stage(cur ^ 1, k0 + 32);
    short8 a[MFR], b[4];
    #pragma unroll
    for (int m = 0; m < MFR; m++)
      a[m] = *(const short8*)&Al[cur][(wr * (MFR * 16) + m * 16 + li) * 32 + RS(li, gi)];
    #pragma unroll
    for (int n = 0; n < 4; n++)
      b[n] = *(const short8*)&Bl[cur][(wc * 64 + n * 16 + li) * 32 + RS(li, gi)];
    #pragma unroll
    for (int m = 0; m < MFR; m++)
      #pragma unroll
      for (int n = 0; n < 4; n++)
        acc[m][n] = MFMA(a[m], b[n], acc[m][n]);
    __syncthreads();
  }
  #pragma unroll
  for (int m = 0; m < MFR; m++) {
    int rbase = row0 + wr * (MFR * 16) + m * 16 + gi * 4;
    #pragma unroll
    for (int n = 0; n < 4; n++) {
      int col = col0 + wc * 64 + n * 16 + li;
      f32x4 v = acc[m][n];
      if (EPI == 2) {
        float bs = bias[col];
        #pragma unroll
        for (int r = 0; r < 4; r++) {
          float u = v[r] + bs;
          float p = u + 0.044715f * u * u * u;
          float gel = u / (1.0f + __expf(-1.5957691216057308f * p));
          outB[(size_t)(rbase + r) * N + col] = f2b(gel);
        }
      } else {
        if (col < 256) {
          #pragma unroll
          for (int r = 0; r < 4; r++) qo[(size_t)(rbase + r) * 256 + col] = f2b(v[r]);
        } else if (col < 512) {
          #pragma unroll
          for (int r = 0; r < 4; r++) ko[(size_t)(rbase + r) * 256 + col - 256] = f2b(v[r]);
        } else {
          int b_ = rbase >> 9, t = rbase & 511;
          int hh = (col - 512) >> 5, d = (col - 512) & 31;
          ushort4 pk;
          pk.x = f2b(v[0]); pk.y = f2b(v[1]); pk.z = f2b(v[2]); pk.w = f2b(v[3]);
          *(ushort4*)&vT[((size_t)((b_ * 8 + hh) * 32 + d)) * 512 + t] = pk;
        }
      }
    }
  }
}

// ---------------- fused k-features + ctx per (b,h) ----------------
__global__ __launch_bounds__(256) void ctx_fused(
    const ushort* __restrict__ kb, const ushort* __restrict__ projd,
    const ushort* __restrict__ vT, ushort* __restrict__ Bmat) {
  __shared__ __align__(16) ushort Kl[512 * 32];
  __shared__ __align__(16) ushort Pl[128 * 32];
  __shared__ __align__(16) ushort Sl[2][128 * 40];
  __shared__ __align__(16) ushort Bvl[2][32 * 32];
  __shared__ float dg_s[512];
  __shared__ float red_s[256];
  int bh = blockIdx.x;
  int b = bh >> 3, h = bh & 7;
  int tid = threadIdx.x, wave = tid >> 6, lane = tid & 63;
  int gi = lane >> 4, li = lane & 15;
  int lrow = lane >> 2, lkb = (lane & 3) * 8;
  const ushort* Kg = kb + (size_t)(b * 512) * 256 + h * 32;
  const ushort* Vg = vT + (size_t)bh * 32 * 512;
  #pragma unroll
  for (int i = 0; i < 8; i++) {
    int chunk = wave * 8 + i;
    gload16(&Kg[(size_t)(chunk * 16 + lrow) * 256 + lkb], &Kl[chunk * 512]);
  }
  #pragma unroll
  for (int i = 0; i < 2; i++) {
    int chunk = wave * 2 + i;
    gload16(&projd[(chunk * 16 + lrow) * 32 + lkb], &Pl[chunk * 512]);
  }
  __syncthreads();
  #pragma unroll
  for (int i = 0; i < 2; i++) {
    int t = tid * 2 + i;
    const ushort* kr = &Kl[t * 32];
    float s = 0.f;
    #pragma unroll
    for (int j = 0; j < 32; j++) { float v = bf2f(kr[j]); s += v * v; }
    dg_s[t] = DN2H * s;
  }
  short8 bp0 = *(const short8*)&Pl[(wave * 32 + li) * 32 + gi * 8];
  short8 bp1 = *(const short8*)&Pl[(wave * 32 + 16 + li) * 32 + gi * 8];
  float smax = -1e30f;
  for (int c = 0; c < 16; c++) {
    int t0c = c * 32;
    short8 a0 = *(const short8*)&Kl[(t0c + li) * 32 + gi * 8];
    short8 a1 = *(const short8*)&Kl[(t0c + 16 + li) * 32 + gi * 8];
    f32x4 s00 = {}, s01 = {}, s10 = {}, s11 = {};
    s00 = MFMA(a0, bp0, s00); s01 = MFMA(a0, bp1, s01);
    s10 = MFMA(a1, bp0, s10); s11 = MFMA(a1, bp1, s11);
    #pragma unroll
    for (int r = 0; r < 4; r++)
      smax = fmaxf(smax, fmaxf(fmaxf(s00[r], s01[r]), fmaxf(s10[r], s11[r])));
  }
  red_s[tid] = smax;
  __syncthreads();
  for (int s = 128; s; s >>= 1) {
    if (tid < s) red_s[tid] = fmaxf(red_s[tid], red_s[tid + s]);
    __syncthreads();
  }
  float km = red_s[0];
  f32x4 cacc[2][2] = {};
  float ks0 = 0.f, ks1 = 0.f;
  int cur = 0;
  for (int c = 0; c < 16; c++, cur ^= 1) {
    int t0c = c * 32;
    if (wave < 2)
      gload16(&Vg[(size_t)(wave * 16 + lrow) * 512 + t0c + lkb], &Bvl[cur][wave * 512]);
    short8 a0 = *(const short8*)&Kl[(t0c + li) * 32 + gi * 8];
    short8 a1 = *(const short8*)&Kl[(t0c + 16 + li) * 32 + gi * 8];
    f32x4 s00 = {}, s01 = {}, s10 = {}, s11 = {};
    s00 = MFMA(a0, bp0, s00); s01 = MFMA(a0, bp1, s01);
    s10 = MFMA(a1, bp0, s10); s11 = MFMA(a1, bp1, s11);
    ushort4 w00, w01, w10, w11;
    #pragma unroll
    for (int r = 0; r < 4; r++) {
      float d0 = dg_s[t0c + gi * 4 + r];
      float d1 = dg_s[t0c + 16 + gi * 4 + r];
      float k00 = RATIO * (__expf(s00[r] - d0 - km) + KEPS);
      float k01 = RATIO * (__expf(s01[r] - d0 - km) + KEPS);
      float k10 = RATIO * (__expf(s10[r] - d1 - km) + KEPS);
      float k11 = RATIO * (__expf(s11[r] - d1 - km) + KEPS);
      ks0 += k00 + k10; ks1 += k01 + k11;
      ((ushort*)&w00)[r] = f2b(k00); ((ushort*)&w01)[r] = f2b(k01);
      ((ushort*)&w10)[r] = f2b(k10); ((ushort*)&w11)[r] = f2b(k11);
    }
    *(ushort4*)&Sl[cur][(wave * 32 + li) * 40 + gi * 4]           = w00;
    *(ushort4*)&Sl[cur][(wave * 32 + 16 + li) * 40 + gi * 4]      = w01;
    *(ushort4*)&Sl[cur][(wave * 32 + li) * 40 + 16 + gi * 4]      = w10;
    *(ushort4*)&Sl[cur][(wave * 32 + 16 + li) * 40 + 16 + gi * 4] = w11;
    __syncthreads();
    short8 ca0 = *(const short8*)&Sl[cur][(wave * 32 + li) * 40 + gi * 8];
    short8 ca1 = *(const short8*)&Sl[cur][(wave * 32 + 16 + li) * 40 + gi * 8];
    short8 cb0 = *(const short8*)&Bvl[cur][li * 32 + gi * 8];
    short8 cb1 = *(const short8*)&Bvl[cur][(16 + li) * 32 + gi * 8];
    cacc[0][0] = MFMA(ca0, cb0, cacc[0][0]);
    cacc[0][1] = MFMA(ca0, cb1, cacc[0][1]);
    cacc[1][0] = MFMA(ca1, cb0, cacc[1][0]);
    cacc[1][1] = MFMA(ca1, cb1, cacc[1][1]);
  }
  ks0 += __shfl_xor(ks0, 16); ks0 += __shfl_xor(ks0, 32);
  ks1 += __shfl_xor(ks1, 16); ks1 += __shfl_xor(ks1, 32);
  if (gi == 0) {
    Bmat[((size_t)bh * 48 + 32) * 128 + wave * 32 + li] = f2b(ks0);
    Bmat[((size_t)bh * 48 + 32) * 128 + wave * 32 + 16 + li] = f2b(ks1);
  }
  #pragma unroll
  for (int m = 0; m < 2; m++)
    #pragma unroll
    for (int n = 0; n < 2; n++) {
      int dd = n * 16 + li;
      int mg = wave * 32 + m * 16 + gi * 4;
      ushort4 pk;
      pk.x = f2b(cacc[m][n][0]); pk.y = f2b(cacc[m][n][1]);
      pk.z = f2b(cacc[m][n][2]); pk.w = f2b(cacc[m][n][3]);
      *(ushort4*)&Bmat[((size_t)bh * 48 + dd) * 128 + mg] = pk;
    }
  for (int e = tid; e < 15 * 128; e += 256)
    Bmat[((size_t)bh * 48 + 33) * 128 + e] = 0;
}

// ---------------- fused q-features + o per (64 t, bh) ----------------
__global__ __launch_bounds__(256) void favq_o(
    const ushort* __restrict__ qb, const ushort* __restrict__ projd,
    const ushort* __restrict__ Bmat, ushort* __restrict__ ob) {
  __shared__ __align__(16) ushort Ql[64 * 32];
  __shared__ __align__(16) ushort Pl[128 * 32];
  __shared__ __align__(16) ushort Sl[64 * 136];
  __shared__ __align__(16) ushort Bml[48 * 136];
  __shared__ float dgq[64];
  int bh = blockIdx.y;
  int t0 = blockIdx.x * 64;
  int b = bh >> 3, h = bh & 7;
  int tid = threadIdx.x, wave = tid >> 6, lane = tid & 63;
  int gi = lane >> 4, li = lane & 15;
  int lrow = lane >> 2, lkb = (lane & 3) * 8;
  const ushort* Qg = qb + (size_t)(b * 512) * 256 + h * 32;
  gload16(&Qg[(size_t)(t0 + wave * 16 + lrow) * 256 + lkb], &Ql[wave * 512]);
  #pragma unroll
  for (int i = 0; i < 2; i++) {
    int chunk = wave * 2 + i;
    gload16(&projd[(chunk * 16 + lrow) * 32 + lkb], &Pl[chunk * 512]);
  }
  #pragma unroll
  for (int j = 0; j < 3; j++) {
    int c = j * 256 + tid;
    int r = c >> 4, g = c & 15;
    *(uint4*)&Bml[r * 136 + g * 8] = *(const uint4*)&Bmat[(size_t)bh * 48 * 128 + r * 128 + g * 8];
  }
  __syncthreads();
  if (tid < 64) {
    const ushort* qr = &Ql[tid * 32];
    float s = 0.f;
    #pragma unroll
    for (int j = 0; j < 32; j++) { float v = bf2f(qr[j]); s += v * v; }
    dgq[tid] = DN2H * s;
  }
  short8 bq = *(const short8*)&Ql[(wave * 16 + li) * 32 + gi * 8];
  f32x4 sacc[8] = {};
  #pragma unroll
  for (int m = 0; m < 8; m++) {
    short8 a = *(const short8*)&Pl[(m * 16 + li) * 32 + gi * 8];
    sacc[m] = MFMA(a, bq, sacc[m]);
  }
  __syncthreads();
  float mx = -1e30f;
  #pragma unroll
  for (int m = 0; m < 8; m++)
    #pragma unroll
    for (int r = 0; r < 4; r++) mx = fmaxf(mx, sacc[m][r]);
  mx = fmaxf(mx, __shfl_xor(mx, 16));
  mx = fmaxf(mx, __shfl_xor(mx, 32));
  float dg = dgq[wave * 16 + li];
  #pragma unroll
  for (int m = 0; m < 8; m++) {
    ushort4 o4;
    #pragma unroll
    for (int r = 0; r < 4; r++)
      ((ushort*)&o4)[r] = f2b(RATIO * (__expf(sacc[m][r] - dg - mx) + KEPS));
    *(ushort4*)&Sl[(wave * 16 + li) * 136 + m * 16 + gi * 4] = o4;
  }
  __syncthreads();
  f32x4 oacc[3] = {};
  #pragma unroll
  for (int ks = 0; ks < 4; ks++) {
    short8 a = *(const short8*)&Sl[(wave * 16 + li) * 136 + ks * 32 + gi * 8];
    #pragma unroll
    for (int n = 0; n < 3; n++) {
      short8 bb = *(const short8*)&Bml[(n * 16 + li) * 136 + ks * 32 + gi * 8];
      oacc[n] = MFMA(a, bb, oacc[n]);
    }
  }
  int t = t0 + wave * 16 + gi * 4;
  float den[4];
  #pragma unroll
  for (int r = 0; r < 4; r++) den[r] = __shfl(oacc[2][r], lane & 48);
  #pragma unroll
  for (int n = 0; n < 2; n++)
    #pragma unroll
    for (int r = 0; r < 4; r++)
      ob[((size_t)(b * 512) + t + r) * 256 + h * 32 + n * 16 + li] = f2b(oacc[n][r] / den[r]);
}

// ---------------- GEMM 32x256 + bias + residual + {LN -> h | mask -> out} ----------------
// 4 waves side-by-side over N; wave tile 32x64; double-buffered swizzled staging. grid BT/32.
template<int MODE>  // 0: write x fp32 + h = LN(x); 1: final masks to mout
__global__ __launch_bounds__(256) void gemm_ln2(
    const ushort* __restrict__ A, const ushort* __restrict__ BTm,
    const float* __restrict__ bias, const float* __restrict__ res,
    float* __restrict__ x, const float* __restrict__ g, const float* __restrict__ bvec,
    ushort* __restrict__ hout,
    const float* __restrict__ Wm, const float* __restrict__ bm, float* __restrict__ mout,
    int K) {
  __shared__ __align__(16) ushort Al[2][32 * 32];
  __shared__ __align__(16) ushort Bl[2][256 * 32];
  __shared__ float rs1[4 * 32];
  __shared__ float rs2[4 * 32];
  __shared__ float pmS[4 * 128];
  int tid = threadIdx.x, wave = tid >> 6, lane = tid & 63;
  int gi = lane >> 4, li = lane & 15;
  int lrow = lane >> 2, lkb = SWZG(lane);
  int row0 = blockIdx.x * 32;
  int wc = wave;
  f32x4 acc[2][4] = {};

  auto stage = [&](int buf, int kk) {
    if (wave < 2)
      gload16(&A[(size_t)(row0 + wave * 16 + lrow) * K + kk + lkb], &Al[buf][wave * 512]);
    #pragma unroll
    for (int i = 0; i < 4; i++) {
      int chunk = wave * 4 + i;
      gload16(&BTm[(size_t)(chunk * 16 + lrow) * K + kk + lkb], &Bl[buf][chunk * 512]);
    }
  };

  stage(0, 0);
  __syncthreads();
  int cur = 0;
  for (int k0 = 0; k0 < K; k0 += 32, cur ^= 1) {
    if (k0 + 32 < K) stage(cur ^ 1, k0 + 32);
    short8 a[2], b[4];
    #pragma unroll
    for (int m = 0; m < 2; m++)
      a[m] = *(const short8*)&Al[cur][(m * 16 + li) * 32 + RS(li, gi)];
    #pragma unroll
    for (int n = 0; n < 4; n++)
      b[n] = *(const short8*)&Bl[cur][(wc * 64 + n * 16 + li) * 32 + RS(li, gi)];
    #pragma unroll
    for (int m = 0; m < 2; m++)
      #pragma unroll
      for (int n = 0; n < 4; n++)
        acc[m][n] = MFMA(a[m], b[n], acc[m][n]);
    __syncthreads();
  }
  // phase 1: add bias+res into acc; per-row partial sums -> LDS
  #pragma unroll
  for (int m = 0; m < 2; m++) {
    #pragma unroll
    for (int r = 0; r < 4; r++) {
      int row = row0 + m * 16 + gi * 4 + r;
      int ridx = m * 16 + gi * 4 + r;
      float s1 = 0.f, s2 = 0.f;
      #pragma unroll
      for (int n = 0; n < 4; n++) {
        int col = wc * 64 + n * 16 + li;
        float val = acc[m][n][r] + bias[col] + res[(size_t)row * 256 + col];
        acc[m][n][r] = val;
        s1 += val; s2 += val * val;
      }
      if (MODE == 0) {
        #pragma unroll
        for (int off = 1; off <= 8; off <<= 1) { s1 += __shfl_xor(s1, off); s2 += __shfl_xor(s2, off); }
        if (li == 0) { rs1[wave * 32 + ridx] = s1; rs2[wave * 32 + ridx] = s2; }
      } else {
        #pragma unroll
        for (int msk = 0; msk < NM; msk++) {
          float sm = 0.f;
          #pragma unroll
          for (int n = 0; n < 4; n++) {
            int col = wc * 64 + n * 16 + li;
            sm += acc[m][n][r] * Wm[col * NM + msk];
          }
          #pragma unroll
          for (int off = 1; off <= 8; off <<= 1) sm += __shfl_xor(sm, off);
          if (li == 0) pmS[wave * 128 + ridx * 4 + msk] = sm;
        }
      }
    }
  }
  __syncthreads();
  if (MODE == 0) {
    float g4[4], bv4[4];
    #pragma unroll
    for (int n = 0; n < 4; n++) {
      int col = wc * 64 + n * 16 + li;
      g4[n] = g[col]; bv4[n] = bvec[col];
    }
    #pragma unroll
    for (int m = 0; m < 2; m++) {
      #pragma unroll
      for (int r = 0; r < 4; r++) {
        int row = row0 + m * 16 + gi * 4 + r;
        int ridx = m * 16 + gi * 4 + r;
        float t1 = rs1[ridx] + rs1[32 + ridx] + rs1[64 + ridx] + rs1[96 + ridx];
        float t2 = rs2[ridx] + rs2[32 + ridx] + rs2[64 + ridx] + rs2[96 + ridx];
        float mu = t1 * (1.f / 256.f);
        float rstd = rsqrtf(t2 * (1.f / 256.f) - mu * mu + 1e-5f);
        #pragma unroll
        for (int n = 0; n < 4; n++) {
          int col = wc * 64 + n * 16 + li;
          float val = acc[m][n][r];
          x[(size_t)row * 256 + col] = val;
          hout[(size_t)row * 256 + col] = f2b((val - mu) * rstd * g4[n] + bv4[n]);
        }
      }
    }
  } else {
    if (tid < 128) {
      int ridx = tid >> 2, msk = tid & 3;
      float tot = pmS[ridx * 4 + msk] + pmS[128 + ridx * 4 + msk] +
                  pmS[256 + ridx * 4 + msk] + pmS[384 + ridx * 4 + msk];
      int grow = row0 + ridx;
      int bb_ = grow >> 9, t = grow & 511;
      mout[((size_t)(bb_ * NM) + msk) * 512 + t] = tot + bm[msk];
    }
  }
}

extern "C" void kernel_launch(void* const* d_in, const int* in_sizes, int n_in,
                              void* d_out, int out_size, void* d_ws, size_t ws_size,
                              hipStream_t stream) {
  const float* mel   = (const float*)d_in[0];
  const float* proj  = (const float*)d_in[1];
  const float* ln1_g = (const float*)d_in[2];
  const float* ln1_b = (const float*)d_in[3];
  const float* Wq    = (const float*)d_in[4];
  const float* Wk    = (const float*)d_in[5];
  const float* Wv    = (const float*)d_in[6];
  const float* Wo    = (const float*)d_in[7];
  const float* bo    = (const float*)d_in[8];
  const float* ln2_g = (const float*)d_in[9];
  const float* ln2_b = (const float*)d_in[10];
  const float* W1    = (const float*)d_in[11];
  const float* b1    = (const float*)d_in[12];
  const float* W2    = (const float*)d_in[13];
  const float* b2    = (const float*)d_in[14];
  const float* Wm    = (const float*)d_in[15];
  const float* bm    = (const float*)d_in[16];

  // ---- workspace layout ----
  float* x      = (float*)d_ws;                        // BT*D fp32
  ushort* us    = (ushort*)(x + (size_t)BT * D);
  ushort* h     = us;                   us += (size_t)BT * D;
  ushort* qb    = us;                   us += (size_t)BT * D;
  ushort* kb    = us;                   us += (size_t)BT * D;
  ushort* vT    = us;                   us += (size_t)BH * 32 * T;
  ushort* ob    = us;                   us += (size_t)BT * D;
  ushort* ffh   = us;                   us += (size_t)BT * FF;
  ushort* Bmat  = us;                   us += (size_t)BH * 48 * MF;
  ushort* qkvT  = us;                   us += (size_t)NLAYER * 768 * 256;
  ushort* woT   = us;                   us += (size_t)NLAYER * 256 * 256;
  ushort* w1T   = us;                   us += (size_t)NLAYER * 1024 * 256;
  ushort* w2T   = us;                   us += (size_t)NLAYER * 256 * 1024;
  ushort* projd = us;                   us += (size_t)MF * DH;

  // ---- prep: transposed bf16 weights ----
  wtrans<<<dim3(8, 8, NLAYER), dim3(32, 8), 0, stream>>>(Wq, qkvT, 256, 256, 65536, 768 * 256);
  wtrans<<<dim3(8, 8, NLAYER), dim3(32, 8), 0, stream>>>(Wk, qkvT + 256 * 256, 256, 256, 65536, 768 * 256);
  wtrans<<<dim3(8, 8, NLAYER), dim3(32, 8), 0, stream>>>(Wv, qkvT + 512 * 256, 256, 256, 65536, 768 * 256);
  wtrans<<<dim3(8, 8, NLAYER), dim3(32, 8), 0, stream>>>(Wo, woT, 256, 256, 65536, 65536);
  wtrans<<<dim3(32, 8, NLAYER), dim3(32, 8), 0, stream>>>(W1, w1T, 256, 1024, 262144, 262144);
  wtrans<<<dim3(8, 32, NLAYER), dim3(32, 8), 0, stream>>>(W2, w2T, 1024, 256, 262144, 262144);
  proj_conv<<<16, 256, 0, stream>>>(proj, projd);

  transpose_mel<<<dim3(T / 32, D / 32, B), dim3(32, 8), 0, stream>>>(mel, x);
  ln_kernel<<<BT / 4, 256, 0, stream>>>(x, ln1_g, ln1_b, h);

  for (int l = 0; l < NLAYER; l++) {
    gemm_bf16<0, 64><<<dim3(6, 256), 256, 0, stream>>>(h, qkvT + (size_t)l * 768 * 256,
        nullptr, nullptr, qb, kb, vT, 768, 256);
    ctx_fused<<<BH, 256, 0, stream>>>(kb, projd, vT, Bmat);
    favq_o<<<dim3(8, BH), 256, 0, stream>>>(qb, projd, Bmat, ob);
    gemm_ln2<0><<<BT / 32, 256, 0, stream>>>(ob, woT + (size_t)l * 256 * 256,
        bo + l * D, x, x, ln2_g + l * D, ln2_b + l * D, h,
        nullptr, nullptr, nullptr, 256);
    gemm_bf16<2, 64><<<dim3(8, 256), 256, 0, stream>>>(h, w1T + (size_t)l * 1024 * 256,
        b1 + (size_t)l * FF, ffh, nullptr, nullptr, nullptr, 1024, 256);
    if (l < NLAYER - 1) {
      gemm_ln2<0><<<BT / 32, 256, 0, stream>>>(ffh, w2T + (size_t)l * 256 * 1024,
          b2 + l * D, x, x, ln1_g + (l + 1) * D, ln1_b + (l + 1) * D, h,
          nullptr, nullptr, nullptr, 1024);
    } else {
      gemm_ln2<1><<<BT / 32, 256, 0, stream>>>(ffh, w2T + (size_t)l * 256 * 1024,
          b2 + l * D, x, x, nullptr, nullptr, nullptr,
          Wm, bm, (float*)d_out, 1024);
    }
  }
}